// Round 15
// baseline (904.600 us; speedup 1.0000x reference)
//
#include <hip/hip_runtime.h>
#include <math.h>

#define NB 32
#define NT 16
#define NH 768
#define NV 32000

typedef short bf16x8 __attribute__((ext_vector_type(8)));
typedef float floatx4 __attribute__((ext_vector_type(4)));
typedef unsigned short ushort_t;

__device__ __forceinline__ float bf2f(unsigned short h) {
    unsigned u = ((unsigned)h) << 16;
    return __builtin_bit_cast(float, u);
}
__device__ __forceinline__ unsigned short f2bf(float f) {
    unsigned u = __builtin_bit_cast(unsigned, f);
    u += 0x7fffu + ((u >> 16) & 1u);
    return (unsigned short)(u >> 16);
}
__device__ __forceinline__ float sigmoidf_(float x) { return 1.f / (1.f + expf(-x)); }

// XCD-chunk swizzle: grid size N % 8 == 0. Blocks dispatched round-robin over 8 XCDs;
// this gives each XCD a CONTIGUOUS chunk of the flattened work space.
__device__ __forceinline__ int swz8(int bid, int N) {
    return (bid & 7) * (N >> 3) + (bid >> 3);
}

__device__ __forceinline__ bf16x8 cvt8(float4 a, float4 b) {
    bf16x8 t;
    t[0] = (short)f2bf(a.x); t[1] = (short)f2bf(a.y);
    t[2] = (short)f2bf(a.z); t[3] = (short)f2bf(a.w);
    t[4] = (short)f2bf(b.x); t[5] = (short)f2bf(b.y);
    t[6] = (short)f2bf(b.z); t[7] = (short)f2bf(b.w);
    return t;
}

// ---------------- merged BN scale/bias precompute (all 4 layers) ----------------
__global__ __launch_bounds__(256) void bn_prep4(
    const float* __restrict__ g1, const float* __restrict__ b1, const float* __restrict__ m1, const float* __restrict__ v1,
    const float* __restrict__ g2, const float* __restrict__ b2, const float* __restrict__ m2, const float* __restrict__ v2,
    const float* __restrict__ g3, const float* __restrict__ b3, const float* __restrict__ m3, const float* __restrict__ v3,
    const float* __restrict__ g4, const float* __restrict__ b4, const float* __restrict__ m4, const float* __restrict__ v4,
    float* __restrict__ s1, float* __restrict__ o1, float* __restrict__ s2, float* __restrict__ o2,
    float* __restrict__ s3, float* __restrict__ o3, float* __restrict__ s4, float* __restrict__ o4) {
    int i = blockIdx.x * 256 + threadIdx.x;
    const float *g, *b, *m, *v;
    float *s, *o;
    int c;
    if (i < 64)        { g = g1; b = b1; m = m1; v = v1; s = s1; o = o1; c = i; }
    else if (i < 192)  { g = g2; b = b2; m = m2; v = v2; s = s2; o = o2; c = i - 64; }
    else if (i < 448)  { g = g3; b = b3; m = m3; v = v3; s = s3; o = o3; c = i - 192; }
    else if (i < 1216) { g = g4; b = b4; m = m4; v = v4; s = s4; o = o4; c = i - 448; }
    else return;
    float inv = g[c] * rsqrtf(v[c] + 1e-5f);
    s[c] = inv;
    o[c] = b[c] - m[c] * inv;
}

__global__ __launch_bounds__(256) void zfill(unsigned long long* __restrict__ p, long long n) {
    long long i = (long long)blockIdx.x * 256 + threadIdx.x;
    if (i < n) p[i] = 0ULL;
}

// rows of f32 -> bf16, vectorized 8 elems/thread. dst flat [rows][cols8*8].
__global__ __launch_bounds__(256) void cvt_b16rows(const float* __restrict__ src, ushort_t* __restrict__ dst,
                                                   int cols8, int ldsrc, int total8) {
    int i = blockIdx.x * 256 + threadIdx.x;
    if (i >= total8) return;
    int r = i / cols8, g = i % cols8;
    const float4* s = (const float4*)(src + (size_t)r * ldsrc + g * 8);
    float4 a = s[0], b = s[1];
    *(bf16x8*)(dst + (size_t)i * 8) = cvt8(a, b);
}

// conv weights OIHW f32 -> packed per (nt, tap, kq)
__global__ __launch_bounds__(256) void cvt_packW_conv(const float* __restrict__ w, ushort_t* __restrict__ dst,
                                                      int CIN, int total) {
    int idx = blockIdx.x * 256 + threadIdx.x;
    if (idx >= total) return;
    int e = idx & 7, lane = (idx >> 3) & 63, j = (idx >> 9) & 3;
    int r = idx >> 11;
    int KQ = CIN >> 5;
    int kq = r % KQ; r /= KQ;
    int tap = r % 9; int nt = r / 9;
    int co = nt * 64 + j * 16 + (lane & 15);
    int ci = kq * 32 + (lane >> 4) * 8 + e;
    dst[idx] = f2bf(w[((size_t)co * CIN + ci) * 9 + tap]);
}

// wcombP pack
__global__ __launch_bounds__(256) void cvt_wcombP(const float* __restrict__ w_ih, const float* __restrict__ w_hh,
                                                  ushort_t* __restrict__ dst) {
    int idx = blockIdx.x * 256 + threadIdx.x;
    if (idx >= 3072 * 1536) return;
    int e = idx & 7, lane = (idx >> 3) & 63;
    int t = idx >> 9;
    int kq = t % 48, gg = t / 48;
    int g = gg & 3, bx = gg >> 2;
    int j = g * 768 + bx * 16 + (lane & 15);
    int k = kq * 32 + (lane >> 4) * 8 + e;
    float v = (k < NH) ? w_ih[(size_t)j * (2 * NH) + NH + k] : w_hh[(size_t)j * NH + (k - NH)];
    dst[idx] = f2bf(v);
}

// wattnT packed for kmat: fragment holds W^T[n][k] = attn_w[k][n]
__global__ __launch_bounds__(256) void cvt_wattnTP(const float* __restrict__ w, ushort_t* __restrict__ dst) {
    int idx = blockIdx.x * 256 + threadIdx.x;
    if (idx >= 768 * 768) return;
    int e = idx & 7, lane = (idx >> 3) & 63, j = (idx >> 9) & 3;
    int t = idx >> 11;
    int kq = t % 24, nt = t / 24;
    int n = nt * 64 + 16 * j + (lane & 15);
    int k = kq * 32 + (lane >> 4) * 8 + e;
    dst[idx] = f2bf(w[(size_t)k * 768 + n]);
}

// conv1 weights: [64][147] f32 -> [64][160] bf16 (zero pad)
__global__ __launch_bounds__(256) void cvt_pad(const float* __restrict__ src, ushort_t* __restrict__ dst) {
    int idx = blockIdx.x * 256 + threadIdx.x;
    if (idx >= 64 * 160) return;
    int co = idx / 160, k = idx % 160;
    dst[idx] = (k < 147) ? f2bf(src[co * 147 + k]) : (ushort_t)0;
}

// ---------------- conv1 im2col: [121856][160] bf16 ----------------
__global__ __launch_bounds__(256) void im2col1(const float* __restrict__ img, ushort_t* __restrict__ A) {
    int idx = blockIdx.x * 256 + threadIdx.x;
    const int total = 121856 * 160;
    if (idx >= total) return;
    int k = idx % 160;
    int m = idx / 160;
    ushort_t v = 0;
    if (k < 147) {
        int b = m / 3808;
        int rm = m % 3808;
        int y = rm / 112, x = rm % 112;
        int ci = k / 49;
        int r = k % 49;
        int ky = r / 7, kx = r % 7;
        int iy = 2 * y - 3 + ky;
        int ix = 2 * x - 3 + kx;
        if ((unsigned)iy < 224u && (unsigned)ix < 224u)
            v = f2bf(img[((size_t)(b * 3 + ci) * 224 + iy) * 224 + ix]);
    }
    A[idx] = v;
}

// ---------------- conv1 GEMM ----------------
__global__ __launch_bounds__(256) void conv1_gemm(
    const ushort_t* __restrict__ A, const ushort_t* __restrict__ Bw,
    const float* __restrict__ scale, const float* __restrict__ bias,
    ushort_t* __restrict__ out) {
    int lane = threadIdx.x & 63, w = threadIdx.x >> 6;
    int m0 = (blockIdx.x * 4 + w) * 64;
    int lr = lane & 15, kl = (lane >> 4) * 8;
    floatx4 acc[4][4];
    #pragma unroll
    for (int i = 0; i < 4; ++i)
        #pragma unroll
        for (int j = 0; j < 4; ++j) acc[i][j] = 0.f;
    #pragma unroll
    for (int k0 = 0; k0 < 160; k0 += 32) {
        bf16x8 a[4], bb[4];
        #pragma unroll
        for (int i = 0; i < 4; ++i) a[i] = *(const bf16x8*)(A + (size_t)(m0 + 16 * i + lr) * 160 + kl + k0);
        #pragma unroll
        for (int j = 0; j < 4; ++j) bb[j] = *(const bf16x8*)(Bw + (size_t)(16 * j + lr) * 160 + kl + k0);
        #pragma unroll
        for (int i = 0; i < 4; ++i)
            #pragma unroll
            for (int j = 0; j < 4; ++j)
                acc[i][j] = __builtin_amdgcn_mfma_f32_16x16x32_bf16(a[i], bb[j], acc[i][j], 0, 0, 0);
    }
    #pragma unroll
    for (int i = 0; i < 4; ++i) {
        #pragma unroll
        for (int r = 0; r < 4; ++r) {
            int m = m0 + 16 * i + (lane >> 4) * 4 + r;
            int b = m / 3808;
            int rm = m % 3808;
            int y = rm / 112, x = rm % 112;
            #pragma unroll
            for (int j = 0; j < 4; ++j) {
                int n = 16 * j + lr;
                float v = fmaxf(acc[i][j][r] * scale[n] + bias[n], 0.f);
                out[((size_t)(b * 34 + y) * 112 + x) * 64 + n] = f2bf(v);
            }
        }
    }
}

// ---------------- maxpool 3x3 s2 p1 ----------------
__global__ __launch_bounds__(256) void pool_kernel(const ushort_t* __restrict__ in,
                                                   ushort_t* __restrict__ hal2) {
    int idx = blockIdx.x * 256 + threadIdx.x;
    const int total = 32 * 17 * 56 * 8;
    if (idx >= total) return;
    int c8 = idx & 7;
    int rest = idx >> 3;
    int x = rest % 56; rest /= 56;
    int y = rest % 17; int b = rest / 17;
    float mx[8];
    #pragma unroll
    for (int j = 0; j < 8; ++j) mx[j] = -INFINITY;
    for (int dy = -1; dy <= 1; ++dy) {
        int iy = 2 * y + dy;
        if ((unsigned)iy >= 34u) continue;
        for (int dx = -1; dx <= 1; ++dx) {
            int ix = 2 * x + dx;
            if ((unsigned)ix >= 112u) continue;
            bf16x8 v = *(const bf16x8*)(in + (((size_t)(b * 34 + iy)) * 112 + ix) * 64 + c8 * 8);
            #pragma unroll
            for (int j = 0; j < 8; ++j) mx[j] = fmaxf(mx[j], bf2f((unsigned short)v[j]));
        }
    }
    bf16x8 o;
    #pragma unroll
    for (int j = 0; j < 8; ++j) o[j] = (short)f2bf(mx[j]);
    *(bf16x8*)(hal2 + (((size_t)(b * 19 + y + 1)) * 58 + (x + 1)) * 64 + c8 * 8) = o;
}

// ---------------- implicit-GEMM 3x3 conv via MFMA, packed weights ----------------
// 64m x 64n wave tile + k-step register prefetch; 1D grid with XCD-chunk swizzle,
// nt-major flattening so each XCD covers a contiguous nt range (weights stay in its L2).
template <int CIN, int HH, int WH, int STRIDE, int HOUT, int WOUT, int COUT, int MEMOUT, int OH, int OW>
__global__ __launch_bounds__(64) void conv_mfma(
    const ushort_t* __restrict__ in, const ushort_t* __restrict__ wtP,
    const float* __restrict__ scale, const float* __restrict__ bias,
    ushort_t* __restrict__ out) {
    const int KQ = CIN / 32;
    const int NK = 9 * KQ;
    const int MT = (32 * HOUT * WOUT) / 64;
    const int NTL = COUT / 64;
    int id = swz8(blockIdx.x, MT * NTL);
    int mt = id % MT, nt = id / MT;
    int lane = threadIdx.x;
    int lr = lane & 15, kl = (lane >> 4) * 8;
    int rowoff[4];
    #pragma unroll
    for (int i = 0; i < 4; ++i) {
        int m = mt * 64 + 16 * i + lr;
        int b = m / (HOUT * WOUT);
        int rm = m % (HOUT * WOUT);
        int y = rm / WOUT, x = rm % WOUT;
        rowoff[i] = ((b * HH + y * STRIDE) * WH + x * STRIDE) * CIN + kl;
    }
    floatx4 acc[4][4];
    #pragma unroll
    for (int i = 0; i < 4; ++i)
        #pragma unroll
        for (int j = 0; j < 4; ++j) acc[i][j] = 0.f;

    auto ioffOf = [&](int ks) {
        int tap = ks / KQ;
        int k0 = (ks & (KQ - 1)) * 32;
        int ky = tap / 3, kx = tap - ky * 3;
        return (ky * WH + kx) * CIN + k0;
    };
    const ushort_t* bbase = wtP + ((size_t)nt * 9 * KQ * 4 * 64 + lane) * 8;

    bf16x8 aC[4], bC[4], aN[4], bN[4];
    {
        int io = ioffOf(0);
        #pragma unroll
        for (int i = 0; i < 4; ++i) aC[i] = *(const bf16x8*)(in + rowoff[i] + io);
        #pragma unroll
        for (int j = 0; j < 4; ++j) bC[j] = *(const bf16x8*)(bbase + ((size_t)(0 * 4 + j) * 64) * 8);
    }
    for (int ks = 0; ks < NK; ks += 2) {
        {
            int io = ioffOf(ks + 1);
            #pragma unroll
            for (int i = 0; i < 4; ++i) aN[i] = *(const bf16x8*)(in + rowoff[i] + io);
            #pragma unroll
            for (int j = 0; j < 4; ++j) bN[j] = *(const bf16x8*)(bbase + ((size_t)((ks + 1) * 4 + j) * 64) * 8);
        }
        #pragma unroll
        for (int i = 0; i < 4; ++i)
            #pragma unroll
            for (int j = 0; j < 4; ++j)
                acc[i][j] = __builtin_amdgcn_mfma_f32_16x16x32_bf16(aC[i], bC[j], acc[i][j], 0, 0, 0);
        if (ks + 2 < NK) {
            int io = ioffOf(ks + 2);
            #pragma unroll
            for (int i = 0; i < 4; ++i) aC[i] = *(const bf16x8*)(in + rowoff[i] + io);
            #pragma unroll
            for (int j = 0; j < 4; ++j) bC[j] = *(const bf16x8*)(bbase + ((size_t)((ks + 2) * 4 + j) * 64) * 8);
        }
        #pragma unroll
        for (int i = 0; i < 4; ++i)
            #pragma unroll
            for (int j = 0; j < 4; ++j)
                acc[i][j] = __builtin_amdgcn_mfma_f32_16x16x32_bf16(aN[i], bN[j], acc[i][j], 0, 0, 0);
    }
    #pragma unroll
    for (int i = 0; i < 4; ++i) {
        #pragma unroll
        for (int r = 0; r < 4; ++r) {
            int m = mt * 64 + 16 * i + (lane >> 4) * 4 + r;
            int b = m / (HOUT * WOUT);
            int rm = m % (HOUT * WOUT);
            int y = rm / WOUT, x = rm % WOUT;
            #pragma unroll
            for (int j = 0; j < 4; ++j) {
                int n = nt * 64 + 16 * j + lr;
                float v = fmaxf(acc[i][j][r] * scale[n] + bias[n], 0.f);
                ushort_t hv = f2bf(v);
                if (MEMOUT) {
                    out[(size_t)m * COUT + n] = hv;   // memory [b][196][768]
                } else {
                    out[((size_t)(b * OH + y + 1) * OW + (x + 1)) * COUT + n] = hv;
                }
            }
        }
    }
}

// ---------------- kmat: K~[b] = mem[b] @ attn_w -> KT [b][96][196][8]; swizzled grid ----------------
__global__ __launch_bounds__(64) void kmat_gemm(
    const ushort_t* __restrict__ memv, const ushort_t* __restrict__ Bp,
    ushort_t* __restrict__ KT) {
    int id = swz8(blockIdx.x, 98 * 12);
    int mt = id % 98, nt = id / 98;
    int lane = threadIdx.x;
    int lr = lane & 15, kl = (lane >> 4) * 8;
    const ushort_t* arow[4];
    #pragma unroll
    for (int i = 0; i < 4; ++i) arow[i] = memv + (size_t)(mt * 64 + 16 * i + lr) * 768 + kl;
    const ushort_t* bbase = Bp + ((size_t)nt * 24 * 4 * 64 + lane) * 8;
    floatx4 acc[4][4];
    #pragma unroll
    for (int i = 0; i < 4; ++i)
        #pragma unroll
        for (int j = 0; j < 4; ++j) acc[i][j] = 0.f;
    bf16x8 aC[4], bC[4], aN[4], bN[4];
    #pragma unroll
    for (int i = 0; i < 4; ++i) aC[i] = *(const bf16x8*)(arow[i]);
    #pragma unroll
    for (int j = 0; j < 4; ++j) bC[j] = *(const bf16x8*)(bbase + ((size_t)j * 64) * 8);
    for (int ks = 0; ks < 24; ks += 2) {
        #pragma unroll
        for (int i = 0; i < 4; ++i) aN[i] = *(const bf16x8*)(arow[i] + (ks + 1) * 32);
        #pragma unroll
        for (int j = 0; j < 4; ++j) bN[j] = *(const bf16x8*)(bbase + ((size_t)((ks + 1) * 4 + j) * 64) * 8);
        #pragma unroll
        for (int i = 0; i < 4; ++i)
            #pragma unroll
            for (int j = 0; j < 4; ++j)
                acc[i][j] = __builtin_amdgcn_mfma_f32_16x16x32_bf16(aC[i], bC[j], acc[i][j], 0, 0, 0);
        if (ks + 2 < 24) {
            #pragma unroll
            for (int i = 0; i < 4; ++i) aC[i] = *(const bf16x8*)(arow[i] + (ks + 2) * 32);
            #pragma unroll
            for (int j = 0; j < 4; ++j) bC[j] = *(const bf16x8*)(bbase + ((size_t)((ks + 2) * 4 + j) * 64) * 8);
        }
        #pragma unroll
        for (int i = 0; i < 4; ++i)
            #pragma unroll
            for (int j = 0; j < 4; ++j)
                acc[i][j] = __builtin_amdgcn_mfma_f32_16x16x32_bf16(aN[i], bN[j], acc[i][j], 0, 0, 0);
    }
    #pragma unroll
    for (int i = 0; i < 4; ++i) {
        #pragma unroll
        for (int r = 0; r < 4; ++r) {
            int mg = mt * 64 + 16 * i + (lane >> 4) * 4 + r;
            int b = mg / 196, m = mg % 196;
            #pragma unroll
            for (int j = 0; j < 4; ++j) {
                int n = nt * 64 + 16 * j + lr;
                KT[(((size_t)b * 96 + (n >> 3)) * 196 + m) * 8 + (n & 7)] = f2bf(acc[i][j][r]);
            }
        }
    }
}

// ---------------- embedding gather -> PACKED bf16 e512P ----------------
__global__ __launch_bounds__(256) void gather_embP(const int* __restrict__ caps,
                                                   const float* __restrict__ table,
                                                   ushort_t* __restrict__ dst) {
    int idx = blockIdx.x * 256 + threadIdx.x;  // 512*768
    if (idx >= 512 * 768) return;
    int e = idx & 7, lane = (idx >> 3) & 63, i = (idx >> 9) & 3;
    int t2 = idx >> 11;
    int kq = t2 % 24, mt = t2 / 24;
    int r = mt * 64 + i * 16 + (lane & 15);
    int k = kq * 32 + (lane >> 4) * 8 + e;
    int t = r >> 5, b = r & 31;
    dst[idx] = f2bf(table[(size_t)caps[b * NT + t] * NH + k]);
}

// ---------------- occupancy-first GEMM: C[512][N] = Ap . Bb^T + bias; swizzled 1D grid ----------------
template <int REMAP>
__global__ __launch_bounds__(256, 4) void gemm_ldsb(
    const ushort_t* __restrict__ Ap, const ushort_t* __restrict__ Bb,
    const float* __restrict__ bias1, const float* __restrict__ bias2,
    float* __restrict__ C, int N) {
    __shared__ ushort_t bt[2][64 * 72];
    int tid = threadIdx.x;
    int lane = tid & 63, w = tid >> 6;
    int nblk = (N >> 6) * 2;
    int id = swz8(blockIdx.x, nblk);
    int nt = id >> 1, mh = id & 1;
    int n0 = nt * 64;
    int mt = mh * 4 + w;
    int lr = lane & 15, hi = lane >> 4;
    int srow = tid >> 2, sc = tid & 3;
    const ushort_t* gsrc = Bb + (size_t)(n0 + srow) * 768 + sc * 8;
    int woff = srow * 72 + sc * 8;
    floatx4 acc[4][4];
    #pragma unroll
    for (int i = 0; i < 4; ++i)
        #pragma unroll
        for (int j = 0; j < 4; ++j) acc[i][j] = 0.f;
    bf16x8 s0 = *(const bf16x8*)(gsrc);
    bf16x8 s1 = *(const bf16x8*)(gsrc + 32);
    for (int kc = 0; kc < 12; ++kc) {
        ushort_t* bufw = &bt[kc & 1][0];
        *(bf16x8*)(bufw + woff) = s0;
        *(bf16x8*)(bufw + woff + 32) = s1;
        if (kc < 11) {
            const ushort_t* p = gsrc + (size_t)(kc + 1) * 64;
            s0 = *(const bf16x8*)(p);
            s1 = *(const bf16x8*)(p + 32);
        }
        __syncthreads();
        const ushort_t* bufr = &bt[kc & 1][0];
        #pragma unroll
        for (int kk = 0; kk < 2; ++kk) {
            int kq = kc * 2 + kk;
            bf16x8 bfr[4], a[4];
            #pragma unroll
            for (int j = 0; j < 4; ++j)
                bfr[j] = *(const bf16x8*)(bufr + (j * 16 + lr) * 72 + kk * 32 + hi * 8);
            #pragma unroll
            for (int i = 0; i < 4; ++i)
                a[i] = *(const bf16x8*)(Ap + ((((size_t)mt * 24 + kq) * 4 + i) * 64 + lane) * 8);
            #pragma unroll
            for (int i = 0; i < 4; ++i)
                #pragma unroll
                for (int j = 0; j < 4; ++j)
                    acc[i][j] = __builtin_amdgcn_mfma_f32_16x16x32_bf16(a[i], bfr[j], acc[i][j], 0, 0, 0);
        }
    }
    #pragma unroll
    for (int i = 0; i < 4; ++i) {
        #pragma unroll
        for (int rr = 0; rr < 4; ++rr) {
            int m = mt * 64 + 16 * i + hi * 4 + rr;   // m = t*32+b
            #pragma unroll
            for (int j = 0; j < 4; ++j) {
                int n = n0 + 16 * j + lr;
                float vv = acc[i][j][rr];
                if (bias1) vv += bias1[n];
                if (bias2) vv += bias2[n];
                if (REMAP) {
                    int t = m >> 5, b = m & 31;
                    C[(size_t)((b << 4) + t) * NV + n] = vv;
                } else {
                    C[(size_t)m * N + n] = vv;
                }
            }
        }
    }
}

// ---------------- attention step (scores = h . K~[b]) ----------------
__global__ __launch_bounds__(768) void attn2(
    ushort_t* __restrict__ xin, const ushort_t* __restrict__ KT,
    const ushort_t* __restrict__ mem) {
    __shared__ float hq[NH];
    __shared__ float sl[196];
    __shared__ float red[16];
    int b = blockIdx.x, tid = threadIdx.x;
    hq[tid] = bf2f(xin[(size_t)b * 1536 + NH + tid]);
    __syncthreads();
    if (tid < 392) {
        int m = tid >> 1, half = tid & 1;
        const ushort_t* basep = KT + (((size_t)b * 96 + half * 48) * 196 + m) * 8;
        float acc = 0.f;
        #pragma unroll 4
        for (int k8 = 0; k8 < 48; ++k8) {
            bf16x8 v = *(const bf16x8*)(basep + (size_t)k8 * 196 * 8);
            const float* qp = hq + (half * 48 + k8) * 8;
            #pragma unroll
            for (int j = 0; j < 8; ++j)
                acc = fmaf(bf2f((unsigned short)v[j]), qp[j], acc);
        }
        acc += __shfl_xor(acc, 1);
        if (!half) sl[m] = acc;
    }
    __syncthreads();
    float sc = (tid < 196) ? sl[tid] : -INFINITY;
    float v = sc;
    #pragma unroll
    for (int off = 32; off; off >>= 1) v = fmaxf(v, __shfl_down(v, off));
    if ((tid & 63) == 0) red[tid >> 6] = v;
    __syncthreads();
    if (tid == 0) {
        float m = red[0];
        for (int i = 1; i < 12; ++i) m = fmaxf(m, red[i]);
        red[12] = m;
    }
    __syncthreads();
    float mx = red[12];
    float e = (tid < 196) ? expf(sc - mx) : 0.f;
    __syncthreads();
    v = e;
    #pragma unroll
    for (int off = 32; off; off >>= 1) v += __shfl_down(v, off);
    if ((tid & 63) == 0) red[tid >> 6] = v;
    __syncthreads();
    if (tid == 0) {
        float s = red[0];
        for (int i = 1; i < 12; ++i) s += red[i];
        red[12] = 1.f / s;
    }
    __syncthreads();
    if (tid < 196) sl[tid] = e * red[12];
    __syncthreads();
    {
        float acc = 0.f;
        const ushort_t* mb = mem + (size_t)b * 196 * NH + tid;
        #pragma unroll 4
        for (int m = 0; m < 196; ++m) acc = fmaf(sl[m], bf2f(mb[(size_t)m * NH]), acc);
        xin[(size_t)b * 1536 + tid] = f2bf(acc);
    }
}

// ---------------- fused gates GEMM + LSTM cell; writes Hall PACKED ----------------
__global__ __launch_bounds__(256) void step_fused(
    const ushort_t* __restrict__ xin_r, const ushort_t* __restrict__ wcombP,
    const float* __restrict__ eg_t,
    float* __restrict__ cbuf, float* __restrict__ hbuf,
    ushort_t* __restrict__ xin_w, ushort_t* __restrict__ hallP, int tstep) {
    __shared__ float pbuf[4][64][33];
    int lane = threadIdx.x & 63, w = threadIdx.x >> 6;
    int bx = blockIdx.x;
    int lr = lane & 15, kl = (lane >> 4) * 8;
    floatx4 acc[2][4];
    #pragma unroll
    for (int i = 0; i < 2; ++i)
        #pragma unroll
        for (int g = 0; g < 4; ++g) acc[i][g] = 0.f;
    for (int kq = 0; kq < 12; ++kq) {
        int k = w * 384 + kq * 32;
        bf16x8 a[2], bb[4];
        #pragma unroll
        for (int i = 0; i < 2; ++i)
            a[i] = *(const bf16x8*)(xin_r + (size_t)(16 * i + lr) * 1536 + k + kl);
        #pragma unroll
        for (int g = 0; g < 4; ++g)
            bb[g] = *(const bf16x8*)(wcombP + (((size_t)(bx * 4 + g) * 48 + (w * 12 + kq)) * 64 + lane) * 8);
        #pragma unroll
        for (int i = 0; i < 2; ++i)
            #pragma unroll
            for (int g = 0; g < 4; ++g)
                acc[i][g] = __builtin_amdgcn_mfma_f32_16x16x32_bf16(a[i], bb[g], acc[i][g], 0, 0, 0);
    }
    #pragma unroll
    for (int i = 0; i < 2; ++i)
        #pragma unroll
        for (int g = 0; g < 4; ++g)
            #pragma unroll
            for (int r = 0; r < 4; ++r) {
                int m = 16 * i + (lane >> 4) * 4 + r;
                pbuf[w][g * 16 + lr][m] = acc[i][g][r];
            }
    __syncthreads();
    int tid = threadIdx.x;
    #pragma unroll
    for (int o = 0; o < 2; ++o) {
        int pid = tid * 2 + o;          // 0..511
        int m = pid & 31, c = pid >> 5; // m = batch, c = 0..15
        int kcol = bx * 16 + c;
        float gi = 0.f, gf = 0.f, gg = 0.f, go = 0.f;
        #pragma unroll
        for (int ww = 0; ww < 4; ++ww) {
            gi += pbuf[ww][c][m];
            gf += pbuf[ww][16 + c][m];
            gg += pbuf[ww][32 + c][m];
            go += pbuf[ww][48 + c][m];
        }
        const float* eg = eg_t + (size_t)m * 3072;
        gi += eg[kcol];
        gf += eg[768 + kcol];
        gg += eg[1536 + kcol];
        go += eg[2304 + kcol];
        float cst = cbuf[m * 768 + kcol];
        float cn = sigmoidf_(gf) * cst + sigmoidf_(gi) * tanhf(gg);
        float hn = sigmoidf_(go) * tanhf(cn);
        cbuf[m * 768 + kcol] = cn;
        hbuf[m * 768 + kcol] = hn;
        ushort_t hb = f2bf(hn);
        xin_w[(size_t)m * 1536 + NH + kcol] = hb;
        int rrow = tstep * 32 + m;
        int mtp = rrow >> 6, ip = (rrow >> 4) & 3, lrp = rrow & 15;
        int kqp = kcol >> 5, hip = (kcol >> 3) & 3, ep = kcol & 7;
        hallP[((((size_t)mtp * 24 + kqp) * 4 + ip) * 64 + (lrp | (hip << 4))) * 8 + ep] = hb;
    }
}

__global__ __launch_bounds__(256) void zero_state(float* __restrict__ h, float* __restrict__ c,
                                                  ushort_t* __restrict__ xin) {
    int i = blockIdx.x * 256 + threadIdx.x;
    if (i < NB * 1536) xin[i] = 0;
    if (i < NB * NH) { h[i] = 0.f; c[i] = 0.f; }
}

__global__ __launch_bounds__(256) void copy_hc(const float* __restrict__ h, const float* __restrict__ c,
                                               float* __restrict__ out) {
    int i = blockIdx.x * 256 + threadIdx.x;
    if (i < NB * NH) {
        out[(size_t)NB * NT * NV + i] = h[i];
        out[(size_t)NB * NT * NV + NB * NH + i] = c[i];
    }
}

extern "C" void kernel_launch(void* const* d_in, const int* in_sizes, int n_in,
                              void* d_out, int out_size, void* d_ws, size_t ws_size,
                              hipStream_t stream) {
    const float* images   = (const float*)d_in[0];
    const int*   captions = (const int*)d_in[1];
    const float* conv1_w  = (const float*)d_in[2];
    const float* bn1_g = (const float*)d_in[3], *bn1_b = (const float*)d_in[4];
    const float* bn1_m = (const float*)d_in[5], *bn1_v = (const float*)d_in[6];
    const float* conv2_w  = (const float*)d_in[7];
    const float* bn2_g = (const float*)d_in[8], *bn2_b = (const float*)d_in[9];
    const float* bn2_m = (const float*)d_in[10], *bn2_v = (const float*)d_in[11];
    const float* conv3_w  = (const float*)d_in[12];
    const float* bn3_g = (const float*)d_in[13], *bn3_b = (const float*)d_in[14];
    const float* bn3_m = (const float*)d_in[15], *bn3_v = (const float*)d_in[16];
    const float* conv4_w  = (const float*)d_in[17];
    const float* bn4_g = (const float*)d_in[18], *bn4_b = (const float*)d_in[19];
    const float* bn4_m = (const float*)d_in[20], *bn4_v = (const float*)d_in[21];
    const float* emb_table = (const float*)d_in[22];
    const float* attn_w   = (const float*)d_in[23];
    const float* w_ih     = (const float*)d_in[24];
    const float* w_hh     = (const float*)d_in[25];
    const float* b_ih     = (const float*)d_in[26];
    const float* b_hh     = (const float*)d_in[27];
    const float* fc_w     = (const float*)d_in[28];
    const float* fc_b     = (const float*)d_in[29];
    float* out = (float*)d_out;

    // ---- workspace layout ----
    char* base = (char*)d_ws;
    size_t off = 0;
    auto alloc = [&](size_t bytes) { char* p = base + off; off += (bytes + 255) & ~(size_t)255; return p; };
    float* s1 = (float*)alloc(64 * 4);   float* bb1 = (float*)alloc(64 * 4);
    float* s2 = (float*)alloc(128 * 4);  float* bb2 = (float*)alloc(128 * 4);
    float* s3 = (float*)alloc(256 * 4);  float* bb3 = (float*)alloc(256 * 4);
    float* s4 = (float*)alloc(768 * 4);  float* bb4 = (float*)alloc(768 * 4);
    ushort_t* c1out = (ushort_t*)alloc((size_t)32 * 34 * 112 * 64 * 2);
    size_t halo_start = off;
    ushort_t* hal2 = (ushort_t*)alloc((size_t)32 * 19 * 58 * 64 * 2);
    ushort_t* hal3 = (ushort_t*)alloc((size_t)32 * 18 * 58 * 128 * 2);
    ushort_t* hal4 = (ushort_t*)alloc((size_t)32 * 10 * 30 * 256 * 2);
    size_t halo_bytes = off - halo_start;
    ushort_t* memv = (ushort_t*)alloc((size_t)32 * 196 * 768 * 2);
    ushort_t* KT   = (ushort_t*)alloc((size_t)32 * 96 * 196 * 8 * 2);
    ushort_t* wb1 = (ushort_t*)alloc((size_t)64 * 160 * 2);
    ushort_t* wb2 = (ushort_t*)alloc((size_t)128 * 9 * 64 * 2);
    ushort_t* wb3 = (ushort_t*)alloc((size_t)256 * 9 * 128 * 2);
    ushort_t* wb4 = (ushort_t*)alloc((size_t)768 * 9 * 256 * 2);
    ushort_t* wattnTP = (ushort_t*)alloc((size_t)768 * 768 * 2);
    ushort_t* wcombP = (ushort_t*)alloc((size_t)3072 * 1536 * 2);
    ushort_t* wihL = (ushort_t*)alloc((size_t)3072 * 768 * 2);
    ushort_t* e512P = (ushort_t*)alloc((size_t)512 * 768 * 2);
    float* eg   = (float*)alloc((size_t)512 * 3072 * 4);
    ushort_t* HallP = (ushort_t*)alloc((size_t)512 * 768 * 2);
    float* hbuf = (float*)alloc(NB * NH * 4);
    float* cbuf = (float*)alloc(NB * NH * 4);
    ushort_t* xinA = (ushort_t*)alloc((size_t)NB * 1536 * 2);
    ushort_t* xinB = (ushort_t*)alloc((size_t)NB * 1536 * 2);
    // union: im2col (39 MB, dead after conv1_gemm) then fc_w bf16 (49.2 MB)
    char* ubig = alloc((size_t)NV * NH * 2);
    ushort_t* imcol = (ushort_t*)ubig;
    ushort_t* fcwb  = (ushort_t*)ubig;

    // ---- one-time transforms ----
    bn_prep4<<<5, 256, 0, stream>>>(bn1_g, bn1_b, bn1_m, bn1_v,
                                    bn2_g, bn2_b, bn2_m, bn2_v,
                                    bn3_g, bn3_b, bn3_m, bn3_v,
                                    bn4_g, bn4_b, bn4_m, bn4_v,
                                    s1, bb1, s2, bb2, s3, bb3, s4, bb4);
    cvt_pad<<<(64 * 160 + 255) / 256, 256, 0, stream>>>(conv1_w, wb1);
    cvt_packW_conv<<<(128 * 9 * 64 + 255) / 256, 256, 0, stream>>>(conv2_w, wb2, 64, 128 * 9 * 64);
    cvt_packW_conv<<<(256 * 9 * 128 + 255) / 256, 256, 0, stream>>>(conv3_w, wb3, 128, 256 * 9 * 128);
    cvt_packW_conv<<<(768 * 9 * 256 + 255) / 256, 256, 0, stream>>>(conv4_w, wb4, 256, 768 * 9 * 256);
    cvt_wattnTP<<<(768 * 768 + 255) / 256, 256, 0, stream>>>(attn_w, wattnTP);
    cvt_wcombP<<<(3072 * 1536 + 255) / 256, 256, 0, stream>>>(w_ih, w_hh, wcombP);
    cvt_b16rows<<<(3072 * 96 + 255) / 256, 256, 0, stream>>>(w_ih, wihL, 96, 1536, 3072 * 96);
    {
        long long n8 = (long long)(halo_bytes / 8);
        zfill<<<(unsigned)((n8 + 255) / 256), 256, 0, stream>>>((unsigned long long*)hal2, n8);
    }

    // ---- encoder ----
    im2col1<<<(121856 * 160 + 255) / 256, 256, 0, stream>>>(images, imcol);
    conv1_gemm<<<476, 256, 0, stream>>>(imcol, wb1, s1, bb1, c1out);
    // imcol dead -> convert fc_w (f32->bf16 row-major, fully coalesced) into same buffer
    cvt_b16rows<<<(NV * 96 + 255) / 256, 256, 0, stream>>>(fc_w, fcwb, 96, 768, NV * 96);
    pool_kernel<<<(32 * 17 * 56 * 8 + 255) / 256, 256, 0, stream>>>(c1out, hal2);
    conv_mfma<64, 19, 58, 1, 16, 56, 128, 0, 18, 58>
        <<<896, 64, 0, stream>>>(hal2, wb2, s2, bb2, hal3);
    conv_mfma<128, 18, 58, 2, 8, 28, 256, 0, 10, 30>
        <<<448, 64, 0, stream>>>(hal3, wb3, s3, bb3, hal4);
    conv_mfma<256, 10, 30, 1, 7, 28, 768, 1, 1, 1>
        <<<1176, 64, 0, stream>>>(hal4, wb4, s4, bb4, memv);

    // ---- attention K~ precompute: KT = mem @ attn_w ----
    kmat_gemm<<<1176, 64, 0, stream>>>(memv, wattnTP, KT);

    // ---- decoder precompute: eg = e @ w_ih[:, :768]^T + b_ih + b_hh ----
    gather_embP<<<(512 * 768) / 256, 256, 0, stream>>>(captions, emb_table, e512P);
    gemm_ldsb<0><<<96, 256, 0, stream>>>(e512P, wihL, b_ih, b_hh, eg, 3072);
    zero_state<<<(NB * 1536 + 255) / 256, 256, 0, stream>>>(hbuf, cbuf, xinA);

    // ---- sequential decoder (xin double-buffered) ----
    ushort_t* xcur = xinA;
    ushort_t* xnxt = xinB;
    for (int t = 0; t < NT; ++t) {
        attn2<<<NB, NH, 0, stream>>>(xcur, KT, memv);
        step_fused<<<48, 256, 0, stream>>>(
            xcur, wcombP, eg + (size_t)t * NB * 3072, cbuf, hbuf, xnxt, HallP, t);
        ushort_t* tmp = xcur; xcur = xnxt; xnxt = tmp;
    }

    // ---- vocab projection for all 16 steps at once ----
    gemm_ldsb<1><<<1000, 256, 0, stream>>>(HallP, fcwb, fc_b, nullptr, out, NV);

    copy_hc<<<(NB * NH + 255) / 256, 256, 0, stream>>>(hbuf, cbuf, out);
}

// Round 16
// 902.388 us; speedup vs baseline: 1.0025x; 1.0025x over previous
//
#include <hip/hip_runtime.h>
#include <math.h>

#define NB 32
#define NT 16
#define NH 768
#define NV 32000

typedef short bf16x8 __attribute__((ext_vector_type(8)));
typedef float floatx4 __attribute__((ext_vector_type(4)));
typedef unsigned short ushort_t;

__device__ __forceinline__ float bf2f(unsigned short h) {
    unsigned u = ((unsigned)h) << 16;
    return __builtin_bit_cast(float, u);
}
__device__ __forceinline__ unsigned short f2bf(float f) {
    unsigned u = __builtin_bit_cast(unsigned, f);
    u += 0x7fffu + ((u >> 16) & 1u);
    return (unsigned short)(u >> 16);
}
__device__ __forceinline__ float sigmoidf_(float x) { return 1.f / (1.f + expf(-x)); }

// XCD-chunk swizzle: grid size N % 8 == 0.
__device__ __forceinline__ int swz8(int bid, int N) {
    return (bid & 7) * (N >> 3) + (bid >> 3);
}

__device__ __forceinline__ bf16x8 cvt8(float4 a, float4 b) {
    bf16x8 t;
    t[0] = (short)f2bf(a.x); t[1] = (short)f2bf(a.y);
    t[2] = (short)f2bf(a.z); t[3] = (short)f2bf(a.w);
    t[4] = (short)f2bf(b.x); t[5] = (short)f2bf(b.y);
    t[6] = (short)f2bf(b.z); t[7] = (short)f2bf(b.w);
    return t;
}

// ---------------- ONE merged prep kernel: bn, conv1 pad, packW 2/3/4, wattnT, wcomb,
// wihL, emb gather, state zero, halo zfill ----------------
#define SEG0 1216
#define SEG1 (SEG0 + 10240)        // conv1 pad
#define SEG2 (SEG1 + 73728)        // packW conv2 (CIN 64)
#define SEG3 (SEG2 + 294912)       // packW conv3 (CIN 128)
#define SEG4 (SEG3 + 1769472)      // packW conv4 (CIN 256)
#define SEG5 (SEG4 + 589824)       // wattnTP
#define SEG6 (SEG5 + 4718592)      // wcombP
#define SEG7 (SEG6 + 294912)       // wihL (8-col units)
#define SEG8 (SEG7 + 393216)       // gather embP
#define SEG9 (SEG8 + 49152)        // zero xin (+ h/c)
__global__ __launch_bounds__(256) void prep_all(
    const float* __restrict__ g1, const float* __restrict__ b1, const float* __restrict__ m1, const float* __restrict__ v1,
    const float* __restrict__ g2, const float* __restrict__ b2, const float* __restrict__ m2, const float* __restrict__ v2,
    const float* __restrict__ g3, const float* __restrict__ b3, const float* __restrict__ m3, const float* __restrict__ v3,
    const float* __restrict__ g4, const float* __restrict__ b4, const float* __restrict__ m4, const float* __restrict__ v4,
    float* __restrict__ s1, float* __restrict__ o1, float* __restrict__ s2, float* __restrict__ o2,
    float* __restrict__ s3, float* __restrict__ o3, float* __restrict__ s4, float* __restrict__ o4,
    const float* __restrict__ conv1_w, ushort_t* __restrict__ wb1,
    const float* __restrict__ conv2_w, ushort_t* __restrict__ wb2,
    const float* __restrict__ conv3_w, ushort_t* __restrict__ wb3,
    const float* __restrict__ conv4_w, ushort_t* __restrict__ wb4,
    const float* __restrict__ attn_w, ushort_t* __restrict__ wattnTP,
    const float* __restrict__ w_ih, const float* __restrict__ w_hh, ushort_t* __restrict__ wcombP,
    ushort_t* __restrict__ wihL,
    const int* __restrict__ caps, const float* __restrict__ table, ushort_t* __restrict__ e512P,
    float* __restrict__ hbuf, float* __restrict__ cbuf, ushort_t* __restrict__ xinA,
    unsigned long long* __restrict__ halo, long long n8) {
    long long gi = (long long)blockIdx.x * 256 + threadIdx.x;
    if (gi < SEG0) {
        int i = (int)gi;
        const float *g, *b, *m, *v;
        float *s, *o;
        int c;
        if (i < 64)        { g = g1; b = b1; m = m1; v = v1; s = s1; o = o1; c = i; }
        else if (i < 192)  { g = g2; b = b2; m = m2; v = v2; s = s2; o = o2; c = i - 64; }
        else if (i < 448)  { g = g3; b = b3; m = m3; v = v3; s = s3; o = o3; c = i - 192; }
        else               { g = g4; b = b4; m = m4; v = v4; s = s4; o = o4; c = i - 448; }
        float inv = g[c] * rsqrtf(v[c] + 1e-5f);
        s[c] = inv;
        o[c] = b[c] - m[c] * inv;
    } else if (gi < SEG1) {
        int idx = (int)(gi - SEG0);
        int co = idx / 160, k = idx % 160;
        wb1[idx] = (k < 147) ? f2bf(conv1_w[co * 147 + k]) : (ushort_t)0;
    } else if (gi < SEG4) {
        // packW conv 2/3/4
        const float* w;
        ushort_t* dst;
        int CIN, idx;
        if (gi < SEG2)      { w = conv2_w; dst = wb2; CIN = 64;  idx = (int)(gi - SEG1); }
        else if (gi < SEG3) { w = conv3_w; dst = wb3; CIN = 128; idx = (int)(gi - SEG2); }
        else                { w = conv4_w; dst = wb4; CIN = 256; idx = (int)(gi - SEG3); }
        int e = idx & 7, lane = (idx >> 3) & 63, j = (idx >> 9) & 3;
        int r = idx >> 11;
        int KQ = CIN >> 5;
        int kq = r % KQ; r /= KQ;
        int tap = r % 9; int nt = r / 9;
        int co = nt * 64 + j * 16 + (lane & 15);
        int ci = kq * 32 + (lane >> 4) * 8 + e;
        dst[idx] = f2bf(w[((size_t)co * CIN + ci) * 9 + tap]);
    } else if (gi < SEG5) {
        int idx = (int)(gi - SEG4);
        int e = idx & 7, lane = (idx >> 3) & 63, j = (idx >> 9) & 3;
        int t = idx >> 11;
        int kq = t % 24, nt = t / 24;
        int n = nt * 64 + 16 * j + (lane & 15);
        int k = kq * 32 + (lane >> 4) * 8 + e;
        wattnTP[idx] = f2bf(attn_w[(size_t)k * 768 + n]);
    } else if (gi < SEG6) {
        int idx = (int)(gi - SEG5);
        int e = idx & 7, lane = (idx >> 3) & 63;
        int t = idx >> 9;
        int kq = t % 48, gg = t / 48;
        int g = gg & 3, bx = gg >> 2;
        int j = g * 768 + bx * 16 + (lane & 15);
        int k = kq * 32 + (lane >> 4) * 8 + e;
        float v = (k < NH) ? w_ih[(size_t)j * (2 * NH) + NH + k] : w_hh[(size_t)j * NH + (k - NH)];
        wcombP[idx] = f2bf(v);
    } else if (gi < SEG7) {
        int idx = (int)(gi - SEG6);
        int r = idx / 96, g = idx % 96;
        const float4* s = (const float4*)(w_ih + (size_t)r * 1536 + g * 8);
        *(bf16x8*)(wihL + (size_t)idx * 8) = cvt8(s[0], s[1]);
    } else if (gi < SEG8) {
        int idx = (int)(gi - SEG7);
        int e = idx & 7, lane = (idx >> 3) & 63, i = (idx >> 9) & 3;
        int t2 = idx >> 11;
        int kq = t2 % 24, mt = t2 / 24;
        int r = mt * 64 + i * 16 + (lane & 15);
        int k = kq * 32 + (lane >> 4) * 8 + e;
        int t = r >> 5, b = r & 31;
        e512P[idx] = f2bf(table[(size_t)caps[b * NT + t] * NH + k]);
    } else if (gi < SEG9) {
        int i = (int)(gi - SEG8);
        xinA[i] = 0;
        if (i < NB * NH) { hbuf[i] = 0.f; cbuf[i] = 0.f; }
    } else {
        long long j = gi - SEG9;
        if (j < n8) halo[j] = 0ULL;
    }
}

// ---------------- conv1 im2col: [121856][160] bf16 ----------------
__global__ __launch_bounds__(256) void im2col1(const float* __restrict__ img, ushort_t* __restrict__ A) {
    int idx = blockIdx.x * 256 + threadIdx.x;
    const int total = 121856 * 160;
    if (idx >= total) return;
    int k = idx % 160;
    int m = idx / 160;
    ushort_t v = 0;
    if (k < 147) {
        int b = m / 3808;
        int rm = m % 3808;
        int y = rm / 112, x = rm % 112;
        int ci = k / 49;
        int r = k % 49;
        int ky = r / 7, kx = r % 7;
        int iy = 2 * y - 3 + ky;
        int ix = 2 * x - 3 + kx;
        if ((unsigned)iy < 224u && (unsigned)ix < 224u)
            v = f2bf(img[((size_t)(b * 3 + ci) * 224 + iy) * 224 + ix]);
    }
    A[idx] = v;
}

// rows of f32 -> bf16 (fc weights)
__global__ __launch_bounds__(256) void cvt_b16rows(const float* __restrict__ src, ushort_t* __restrict__ dst,
                                                   int cols8, int ldsrc, int total8) {
    int i = blockIdx.x * 256 + threadIdx.x;
    if (i >= total8) return;
    int r = i / cols8, g = i % cols8;
    const float4* s = (const float4*)(src + (size_t)r * ldsrc + g * 8);
    *(bf16x8*)(dst + (size_t)i * 8) = cvt8(s[0], s[1]);
}

// ---------------- conv1 GEMM ----------------
__global__ __launch_bounds__(256) void conv1_gemm(
    const ushort_t* __restrict__ A, const ushort_t* __restrict__ Bw,
    const float* __restrict__ scale, const float* __restrict__ bias,
    ushort_t* __restrict__ out) {
    int lane = threadIdx.x & 63, w = threadIdx.x >> 6;
    int m0 = (blockIdx.x * 4 + w) * 64;
    int lr = lane & 15, kl = (lane >> 4) * 8;
    floatx4 acc[4][4];
    #pragma unroll
    for (int i = 0; i < 4; ++i)
        #pragma unroll
        for (int j = 0; j < 4; ++j) acc[i][j] = 0.f;
    #pragma unroll
    for (int k0 = 0; k0 < 160; k0 += 32) {
        bf16x8 a[4], bb[4];
        #pragma unroll
        for (int i = 0; i < 4; ++i) a[i] = *(const bf16x8*)(A + (size_t)(m0 + 16 * i + lr) * 160 + kl + k0);
        #pragma unroll
        for (int j = 0; j < 4; ++j) bb[j] = *(const bf16x8*)(Bw + (size_t)(16 * j + lr) * 160 + kl + k0);
        #pragma unroll
        for (int i = 0; i < 4; ++i)
            #pragma unroll
            for (int j = 0; j < 4; ++j)
                acc[i][j] = __builtin_amdgcn_mfma_f32_16x16x32_bf16(a[i], bb[j], acc[i][j], 0, 0, 0);
    }
    #pragma unroll
    for (int i = 0; i < 4; ++i) {
        #pragma unroll
        for (int r = 0; r < 4; ++r) {
            int m = m0 + 16 * i + (lane >> 4) * 4 + r;
            int b = m / 3808;
            int rm = m % 3808;
            int y = rm / 112, x = rm % 112;
            #pragma unroll
            for (int j = 0; j < 4; ++j) {
                int n = 16 * j + lr;
                float v = fmaxf(acc[i][j][r] * scale[n] + bias[n], 0.f);
                out[((size_t)(b * 34 + y) * 112 + x) * 64 + n] = f2bf(v);
            }
        }
    }
}

// ---------------- maxpool 3x3 s2 p1 ----------------
__global__ __launch_bounds__(256) void pool_kernel(const ushort_t* __restrict__ in,
                                                   ushort_t* __restrict__ hal2) {
    int idx = blockIdx.x * 256 + threadIdx.x;
    const int total = 32 * 17 * 56 * 8;
    if (idx >= total) return;
    int c8 = idx & 7;
    int rest = idx >> 3;
    int x = rest % 56; rest /= 56;
    int y = rest % 17; int b = rest / 17;
    float mx[8];
    #pragma unroll
    for (int j = 0; j < 8; ++j) mx[j] = -INFINITY;
    for (int dy = -1; dy <= 1; ++dy) {
        int iy = 2 * y + dy;
        if ((unsigned)iy >= 34u) continue;
        for (int dx = -1; dx <= 1; ++dx) {
            int ix = 2 * x + dx;
            if ((unsigned)ix >= 112u) continue;
            bf16x8 v = *(const bf16x8*)(in + (((size_t)(b * 34 + iy)) * 112 + ix) * 64 + c8 * 8);
            #pragma unroll
            for (int j = 0; j < 8; ++j) mx[j] = fmaxf(mx[j], bf2f((unsigned short)v[j]));
        }
    }
    bf16x8 o;
    #pragma unroll
    for (int j = 0; j < 8; ++j) o[j] = (short)f2bf(mx[j]);
    *(bf16x8*)(hal2 + (((size_t)(b * 19 + y + 1)) * 58 + (x + 1)) * 64 + c8 * 8) = o;
}

// ---------------- implicit-GEMM 3x3 conv via MFMA (conv2/conv3), prefetch + swizzle ----------------
template <int CIN, int HH, int WH, int STRIDE, int HOUT, int WOUT, int COUT, int OH, int OW>
__global__ __launch_bounds__(64) void conv_mfma(
    const ushort_t* __restrict__ in, const ushort_t* __restrict__ wtP,
    const float* __restrict__ scale, const float* __restrict__ bias,
    ushort_t* __restrict__ out) {
    const int KQ = CIN / 32;
    const int NK = 9 * KQ;
    const int MT = (32 * HOUT * WOUT) / 64;
    const int NTL = COUT / 64;
    int id = swz8(blockIdx.x, MT * NTL);
    int mt = id % MT, nt = id / MT;
    int lane = threadIdx.x;
    int lr = lane & 15, kl = (lane >> 4) * 8;
    int rowoff[4];
    #pragma unroll
    for (int i = 0; i < 4; ++i) {
        int m = mt * 64 + 16 * i + lr;
        int b = m / (HOUT * WOUT);
        int rm = m % (HOUT * WOUT);
        int y = rm / WOUT, x = rm % WOUT;
        rowoff[i] = ((b * HH + y * STRIDE) * WH + x * STRIDE) * CIN + kl;
    }
    floatx4 acc[4][4];
    #pragma unroll
    for (int i = 0; i < 4; ++i)
        #pragma unroll
        for (int j = 0; j < 4; ++j) acc[i][j] = 0.f;

    auto ioffOf = [&](int ks) {
        int tap = ks / KQ;
        int k0 = (ks & (KQ - 1)) * 32;
        int ky = tap / 3, kx = tap - ky * 3;
        return (ky * WH + kx) * CIN + k0;
    };
    const ushort_t* bbase = wtP + ((size_t)nt * 9 * KQ * 4 * 64 + lane) * 8;

    bf16x8 aC[4], bC[4], aN[4], bN[4];
    {
        int io = ioffOf(0);
        #pragma unroll
        for (int i = 0; i < 4; ++i) aC[i] = *(const bf16x8*)(in + rowoff[i] + io);
        #pragma unroll
        for (int j = 0; j < 4; ++j) bC[j] = *(const bf16x8*)(bbase + ((size_t)j * 64) * 8);
    }
    for (int ks = 0; ks < NK; ks += 2) {
        {
            int io = ioffOf(ks + 1);
            #pragma unroll
            for (int i = 0; i < 4; ++i) aN[i] = *(const bf16x8*)(in + rowoff[i] + io);
            #pragma unroll
            for (int j = 0; j < 4; ++j) bN[j] = *(const bf16x8*)(bbase + ((size_t)((ks + 1) * 4 + j) * 64) * 8);
        }
        #pragma unroll
        for (int i = 0; i < 4; ++i)
            #pragma unroll
            for (int j = 0; j < 4; ++j)
                acc[i][j] = __builtin_amdgcn_mfma_f32_16x16x32_bf16(aC[i], bC[j], acc[i][j], 0, 0, 0);
        if (ks + 2 < NK) {
            int io = ioffOf(ks + 2);
            #pragma unroll
            for (int i = 0; i < 4; ++i) aC[i] = *(const bf16x8*)(in + rowoff[i] + io);
            #pragma unroll
            for (int j = 0; j < 4; ++j) bC[j] = *(const bf16x8*)(bbase + ((size_t)((ks + 2) * 4 + j) * 64) * 8);
        }
        #pragma unroll
        for (int i = 0; i < 4; ++i)
            #pragma unroll
            for (int j = 0; j < 4; ++j)
                acc[i][j] = __builtin_amdgcn_mfma_f32_16x16x32_bf16(aN[i], bN[j], acc[i][j], 0, 0, 0);
    }
    #pragma unroll
    for (int i = 0; i < 4; ++i) {
        #pragma unroll
        for (int r = 0; r < 4; ++r) {
            int m = mt * 64 + 16 * i + (lane >> 4) * 4 + r;
            int b = m / (HOUT * WOUT);
            int rm = m % (HOUT * WOUT);
            int y = rm / WOUT, x = rm % WOUT;
            #pragma unroll
            for (int j = 0; j < 4; ++j) {
                int n = nt * 64 + 16 * j + lr;
                float v = fmaxf(acc[i][j][r] * scale[n] + bias[n], 0.f);
                out[((size_t)(b * OH + y + 1) * OW + (x + 1)) * COUT + n] = f2bf(v);
            }
        }
    }
}

// ---------------- conv4 split-K (3 tap-groups): partials f32 [3][6272][768] ----------------
__global__ __launch_bounds__(64) void conv4_split(
    const ushort_t* __restrict__ in, const ushort_t* __restrict__ wtP,
    float* __restrict__ part) {
    const int CIN = 256, HH = 10, WH = 30, HOUT = 7, WOUT = 28;
    int id = swz8(blockIdx.x, 98 * 12 * 3);
    int s = id / (98 * 12);
    int rem = id % (98 * 12);
    int nt = rem / 98, mt = rem % 98;
    int lane = threadIdx.x;
    int lr = lane & 15, kl = (lane >> 4) * 8;
    int rowoff[4];
    #pragma unroll
    for (int i = 0; i < 4; ++i) {
        int m = mt * 64 + 16 * i + lr;
        int b = m / (HOUT * WOUT);
        int rm = m % (HOUT * WOUT);
        int y = rm / WOUT, x = rm % WOUT;
        rowoff[i] = ((b * HH + y) * WH + x) * CIN + kl;
    }
    floatx4 acc[4][4];
    #pragma unroll
    for (int i = 0; i < 4; ++i)
        #pragma unroll
        for (int j = 0; j < 4; ++j) acc[i][j] = 0.f;

    auto ioffOf = [&](int ks) {   // local ks 0..23, global tap = s*3 + ks/8
        int tap = s * 3 + (ks >> 3);
        int k0 = (ks & 7) * 32;
        int ky = tap / 3, kx = tap - ky * 3;
        return (ky * WH + kx) * CIN + k0;
    };
    const ushort_t* bbase = wtP + ((size_t)nt * 9 * 8 * 4 * 64 + lane) * 8;
    auto bOf = [&](int ks, int j) {   // global kstep g = s*24 + ks
        return (const bf16x8*)(bbase + ((size_t)((s * 24 + ks) * 4 + j) * 64) * 8);
    };

    bf16x8 aC[4], bC[4], aN[4], bN[4];
    {
        int io = ioffOf(0);
        #pragma unroll
        for (int i = 0; i < 4; ++i) aC[i] = *(const bf16x8*)(in + rowoff[i] + io);
        #pragma unroll
        for (int j = 0; j < 4; ++j) bC[j] = *bOf(0, j);
    }
    for (int ks = 0; ks < 24; ks += 2) {
        {
            int io = ioffOf(ks + 1);
            #pragma unroll
            for (int i = 0; i < 4; ++i) aN[i] = *(const bf16x8*)(in + rowoff[i] + io);
            #pragma unroll
            for (int j = 0; j < 4; ++j) bN[j] = *bOf(ks + 1, j);
        }
        #pragma unroll
        for (int i = 0; i < 4; ++i)
            #pragma unroll
            for (int j = 0; j < 4; ++j)
                acc[i][j] = __builtin_amdgcn_mfma_f32_16x16x32_bf16(aC[i], bC[j], acc[i][j], 0, 0, 0);
        if (ks + 2 < 24) {
            int io = ioffOf(ks + 2);
            #pragma unroll
            for (int i = 0; i < 4; ++i) aC[i] = *(const bf16x8*)(in + rowoff[i] + io);
            #pragma unroll
            for (int j = 0; j < 4; ++j) bC[j] = *bOf(ks + 2, j);
        }
        #pragma unroll
        for (int i = 0; i < 4; ++i)
            #pragma unroll
            for (int j = 0; j < 4; ++j)
                acc[i][j] = __builtin_amdgcn_mfma_f32_16x16x32_bf16(aN[i], bN[j], acc[i][j], 0, 0, 0);
    }
    float* pbase = part + (size_t)s * 6272 * 768;
    #pragma unroll
    for (int i = 0; i < 4; ++i) {
        #pragma unroll
        for (int r = 0; r < 4; ++r) {
            int m = mt * 64 + 16 * i + (lane >> 4) * 4 + r;
            #pragma unroll
            for (int j = 0; j < 4; ++j) {
                int n = nt * 64 + 16 * j + lr;
                pbase[(size_t)m * 768 + n] = acc[i][j][r];
            }
        }
    }
}

// ---------------- conv4 combine: memv = ReLU(scale*(p0+p1+p2)+bias) ----------------
__global__ __launch_bounds__(256) void comb4(
    const float* __restrict__ part, const float* __restrict__ scale, const float* __restrict__ bias,
    ushort_t* __restrict__ memv) {
    int idx = blockIdx.x * 256 + threadIdx.x;   // 6272*192 quads
    if (idx >= 6272 * 192) return;
    int m = idx / 192, nq = idx % 192;
    int n = nq * 4;
    size_t off = (size_t)m * 768 + n;
    const float4 a = *(const float4*)(part + off);
    const float4 b = *(const float4*)(part + (size_t)6272 * 768 + off);
    const float4 c = *(const float4*)(part + (size_t)2 * 6272 * 768 + off);
    ushort_t o[4];
    o[0] = f2bf(fmaxf((a.x + b.x + c.x) * scale[n]     + bias[n],     0.f));
    o[1] = f2bf(fmaxf((a.y + b.y + c.y) * scale[n + 1] + bias[n + 1], 0.f));
    o[2] = f2bf(fmaxf((a.z + b.z + c.z) * scale[n + 2] + bias[n + 2], 0.f));
    o[3] = f2bf(fmaxf((a.w + b.w + c.w) * scale[n + 3] + bias[n + 3], 0.f));
    *(unsigned long long*)(memv + off) = *(unsigned long long*)o;
}

// ---------------- kmat: K~[b] = mem[b] @ attn_w -> KT [b][96][196][8]; swizzled + prefetch ----------------
__global__ __launch_bounds__(64) void kmat_gemm(
    const ushort_t* __restrict__ memv, const ushort_t* __restrict__ Bp,
    ushort_t* __restrict__ KT) {
    int id = swz8(blockIdx.x, 98 * 12);
    int mt = id % 98, nt = id / 98;
    int lane = threadIdx.x;
    int lr = lane & 15, kl = (lane >> 4) * 8;
    const ushort_t* arow[4];
    #pragma unroll
    for (int i = 0; i < 4; ++i) arow[i] = memv + (size_t)(mt * 64 + 16 * i + lr) * 768 + kl;
    const ushort_t* bbase = Bp + ((size_t)nt * 24 * 4 * 64 + lane) * 8;
    floatx4 acc[4][4];
    #pragma unroll
    for (int i = 0; i < 4; ++i)
        #pragma unroll
        for (int j = 0; j < 4; ++j) acc[i][j] = 0.f;
    bf16x8 aC[4], bC[4], aN[4], bN[4];
    #pragma unroll
    for (int i = 0; i < 4; ++i) aC[i] = *(const bf16x8*)(arow[i]);
    #pragma unroll
    for (int j = 0; j < 4; ++j) bC[j] = *(const bf16x8*)(bbase + ((size_t)j * 64) * 8);
    for (int ks = 0; ks < 24; ks += 2) {
        #pragma unroll
        for (int i = 0; i < 4; ++i) aN[i] = *(const bf16x8*)(arow[i] + (ks + 1) * 32);
        #pragma unroll
        for (int j = 0; j < 4; ++j) bN[j] = *(const bf16x8*)(bbase + ((size_t)((ks + 1) * 4 + j) * 64) * 8);
        #pragma unroll
        for (int i = 0; i < 4; ++i)
            #pragma unroll
            for (int j = 0; j < 4; ++j)
                acc[i][j] = __builtin_amdgcn_mfma_f32_16x16x32_bf16(aC[i], bC[j], acc[i][j], 0, 0, 0);
        if (ks + 2 < 24) {
            #pragma unroll
            for (int i = 0; i < 4; ++i) aC[i] = *(const bf16x8*)(arow[i] + (ks + 2) * 32);
            #pragma unroll
            for (int j = 0; j < 4; ++j) bC[j] = *(const bf16x8*)(bbase + ((size_t)((ks + 2) * 4 + j) * 64) * 8);
        }
        #pragma unroll
        for (int i = 0; i < 4; ++i)
            #pragma unroll
            for (int j = 0; j < 4; ++j)
                acc[i][j] = __builtin_amdgcn_mfma_f32_16x16x32_bf16(aN[i], bN[j], acc[i][j], 0, 0, 0);
    }
    #pragma unroll
    for (int i = 0; i < 4; ++i) {
        #pragma unroll
        for (int r = 0; r < 4; ++r) {
            int mg = mt * 64 + 16 * i + (lane >> 4) * 4 + r;
            int b = mg / 196, m = mg % 196;
            #pragma unroll
            for (int j = 0; j < 4; ++j) {
                int n = nt * 64 + 16 * j + lr;
                KT[(((size_t)b * 96 + (n >> 3)) * 196 + m) * 8 + (n & 7)] = f2bf(acc[i][j][r]);
            }
        }
    }
}

// ---------------- occupancy-first GEMM: C[512][N] = Ap . Bb^T + bias; swizzled 1D grid ----------------
template <int REMAP>
__global__ __launch_bounds__(256, 4) void gemm_ldsb(
    const ushort_t* __restrict__ Ap, const ushort_t* __restrict__ Bb,
    const float* __restrict__ bias1, const float* __restrict__ bias2,
    float* __restrict__ C, int N) {
    __shared__ ushort_t bt[2][64 * 72];
    int tid = threadIdx.x;
    int lane = tid & 63, w = tid >> 6;
    int nblk = (N >> 6) * 2;
    int id = swz8(blockIdx.x, nblk);
    int nt = id >> 1, mh = id & 1;
    int n0 = nt * 64;
    int mt = mh * 4 + w;
    int lr = lane & 15, hi = lane >> 4;
    int srow = tid >> 2, sc = tid & 3;
    const ushort_t* gsrc = Bb + (size_t)(n0 + srow) * 768 + sc * 8;
    int woff = srow * 72 + sc * 8;
    floatx4 acc[4][4];
    #pragma unroll
    for (int i = 0; i < 4; ++i)
        #pragma unroll
        for (int j = 0; j < 4; ++j) acc[i][j] = 0.f;
    bf16x8 s0 = *(const bf16x8*)(gsrc);
    bf16x8 s1 = *(const bf16x8*)(gsrc + 32);
    for (int kc = 0; kc < 12; ++kc) {
        ushort_t* bufw = &bt[kc & 1][0];
        *(bf16x8*)(bufw + woff) = s0;
        *(bf16x8*)(bufw + woff + 32) = s1;
        if (kc < 11) {
            const ushort_t* p = gsrc + (size_t)(kc + 1) * 64;
            s0 = *(const bf16x8*)(p);
            s1 = *(const bf16x8*)(p + 32);
        }
        __syncthreads();
        const ushort_t* bufr = &bt[kc & 1][0];
        #pragma unroll
        for (int kk = 0; kk < 2; ++kk) {
            int kq = kc * 2 + kk;
            bf16x8 bfr[4], a[4];
            #pragma unroll
            for (int j = 0; j < 4; ++j)
                bfr[j] = *(const bf16x8*)(bufr + (j * 16 + lr) * 72 + kk * 32 + hi * 8);
            #pragma unroll
            for (int i = 0; i < 4; ++i)
                a[i] = *(const bf16x8*)(Ap + ((((size_t)mt * 24 + kq) * 4 + i) * 64 + lane) * 8);
            #pragma unroll
            for (int i = 0; i < 4; ++i)
                #pragma unroll
                for (int j = 0; j < 4; ++j)
                    acc[i][j] = __builtin_amdgcn_mfma_f32_16x16x32_bf16(a[i], bfr[j], acc[i][j], 0, 0, 0);
        }
    }
    #pragma unroll
    for (int i = 0; i < 4; ++i) {
        #pragma unroll
        for (int rr = 0; rr < 4; ++rr) {
            int m = mt * 64 + 16 * i + hi * 4 + rr;   // m = t*32+b
            #pragma unroll
            for (int j = 0; j < 4; ++j) {
                int n = n0 + 16 * j + lr;
                float vv = acc[i][j][rr];
                if (bias1) vv += bias1[n];
                if (bias2) vv += bias2[n];
                if (REMAP) {
                    int t = m >> 5, b = m & 31;
                    C[(size_t)((b << 4) + t) * NV + n] = vv;
                } else {
                    C[(size_t)m * N + n] = vv;
                }
            }
        }
    }
}

// ---------------- attention step (scores = h . K~[b]) ----------------
__global__ __launch_bounds__(768) void attn2(
    ushort_t* __restrict__ xin, const ushort_t* __restrict__ KT,
    const ushort_t* __restrict__ mem) {
    __shared__ float hq[NH];
    __shared__ float sl[196];
    __shared__ float red[16];
    int b = blockIdx.x, tid = threadIdx.x;
    hq[tid] = bf2f(xin[(size_t)b * 1536 + NH + tid]);
    __syncthreads();
    if (tid < 392) {
        int m = tid >> 1, half = tid & 1;
        const ushort_t* basep = KT + (((size_t)b * 96 + half * 48) * 196 + m) * 8;
        float acc = 0.f;
        #pragma unroll 4
        for (int k8 = 0; k8 < 48; ++k8) {
            bf16x8 v = *(const bf16x8*)(basep + (size_t)k8 * 196 * 8);
            const float* qp = hq + (half * 48 + k8) * 8;
            #pragma unroll
            for (int j = 0; j < 8; ++j)
                acc = fmaf(bf2f((unsigned short)v[j]), qp[j], acc);
        }
        acc += __shfl_xor(acc, 1);
        if (!half) sl[m] = acc;
    }
    __syncthreads();
    float sc = (tid < 196) ? sl[tid] : -INFINITY;
    float v = sc;
    #pragma unroll
    for (int off = 32; off; off >>= 1) v = fmaxf(v, __shfl_down(v, off));
    if ((tid & 63) == 0) red[tid >> 6] = v;
    __syncthreads();
    if (tid == 0) {
        float m = red[0];
        for (int i = 1; i < 12; ++i) m = fmaxf(m, red[i]);
        red[12] = m;
    }
    __syncthreads();
    float mx = red[12];
    float e = (tid < 196) ? expf(sc - mx) : 0.f;
    __syncthreads();
    v = e;
    #pragma unroll
    for (int off = 32; off; off >>= 1) v += __shfl_down(v, off);
    if ((tid & 63) == 0) red[tid >> 6] = v;
    __syncthreads();
    if (tid == 0) {
        float s = red[0];
        for (int i = 1; i < 12; ++i) s += red[i];
        red[12] = 1.f / s;
    }
    __syncthreads();
    if (tid < 196) sl[tid] = e * red[12];
    __syncthreads();
    {
        float acc = 0.f;
        const ushort_t* mb = mem + (size_t)b * 196 * NH + tid;
        #pragma unroll 4
        for (int m = 0; m < 196; ++m) acc = fmaf(sl[m], bf2f(mb[(size_t)m * NH]), acc);
        xin[(size_t)b * 1536 + tid] = f2bf(acc);
    }
}

// ---------------- fused gates GEMM + LSTM cell; writes Hall PACKED ----------------
__global__ __launch_bounds__(256) void step_fused(
    const ushort_t* __restrict__ xin_r, const ushort_t* __restrict__ wcombP,
    const float* __restrict__ eg_t,
    float* __restrict__ cbuf, float* __restrict__ hbuf,
    ushort_t* __restrict__ xin_w, ushort_t* __restrict__ hallP, int tstep) {
    __shared__ float pbuf[4][64][33];
    int lane = threadIdx.x & 63, w = threadIdx.x >> 6;
    int bx = blockIdx.x;
    int lr = lane & 15, kl = (lane >> 4) * 8;
    floatx4 acc[2][4];
    #pragma unroll
    for (int i = 0; i < 2; ++i)
        #pragma unroll
        for (int g = 0; g < 4; ++g) acc[i][g] = 0.f;
    for (int kq = 0; kq < 12; ++kq) {
        int k = w * 384 + kq * 32;
        bf16x8 a[2], bb[4];
        #pragma unroll
        for (int i = 0; i < 2; ++i)
            a[i] = *(const bf16x8*)(xin_r + (size_t)(16 * i + lr) * 1536 + k + kl);
        #pragma unroll
        for (int g = 0; g < 4; ++g)
            bb[g] = *(const bf16x8*)(wcombP + (((size_t)(bx * 4 + g) * 48 + (w * 12 + kq)) * 64 + lane) * 8);
        #pragma unroll
        for (int i = 0; i < 2; ++i)
            #pragma unroll
            for (int g = 0; g < 4; ++g)
                acc[i][g] = __builtin_amdgcn_mfma_f32_16x16x32_bf16(a[i], bb[g], acc[i][g], 0, 0, 0);
    }
    #pragma unroll
    for (int i = 0; i < 2; ++i)
        #pragma unroll
        for (int g = 0; g < 4; ++g)
            #pragma unroll
            for (int r = 0; r < 4; ++r) {
                int m = 16 * i + (lane >> 4) * 4 + r;
                pbuf[w][g * 16 + lr][m] = acc[i][g][r];
            }
    __syncthreads();
    int tid = threadIdx.x;
    #pragma unroll
    for (int o = 0; o < 2; ++o) {
        int pid = tid * 2 + o;          // 0..511
        int m = pid & 31, c = pid >> 5; // m = batch, c = 0..15
        int kcol = bx * 16 + c;
        float gi = 0.f, gf = 0.f, gg = 0.f, go = 0.f;
        #pragma unroll
        for (int ww = 0; ww < 4; ++ww) {
            gi += pbuf[ww][c][m];
            gf += pbuf[ww][16 + c][m];
            gg += pbuf[ww][32 + c][m];
            go += pbuf[ww][48 + c][m];
        }
        const float* eg = eg_t + (size_t)m * 3072;
        gi += eg[kcol];
        gf += eg[768 + kcol];
        gg += eg[1536 + kcol];
        go += eg[2304 + kcol];
        float cst = cbuf[m * 768 + kcol];
        float cn = sigmoidf_(gf) * cst + sigmoidf_(gi) * tanhf(gg);
        float hn = sigmoidf_(go) * tanhf(cn);
        cbuf[m * 768 + kcol] = cn;
        hbuf[m * 768 + kcol] = hn;
        ushort_t hb = f2bf(hn);
        xin_w[(size_t)m * 1536 + NH + kcol] = hb;
        int rrow = tstep * 32 + m;
        int mtp = rrow >> 6, ip = (rrow >> 4) & 3, lrp = rrow & 15;
        int kqp = kcol >> 5, hip = (kcol >> 3) & 3, ep = kcol & 7;
        hallP[((((size_t)mtp * 24 + kqp) * 4 + ip) * 64 + (lrp | (hip << 4))) * 8 + ep] = hb;
    }
}

__global__ __launch_bounds__(256) void copy_hc(const float* __restrict__ h, const float* __restrict__ c,
                                               float* __restrict__ out) {
    int i = blockIdx.x * 256 + threadIdx.x;
    if (i < NB * NH) {
        out[(size_t)NB * NT * NV + i] = h[i];
        out[(size_t)NB * NT * NV + NB * NH + i] = c[i];
    }
}

extern "C" void kernel_launch(void* const* d_in, const int* in_sizes, int n_in,
                              void* d_out, int out_size, void* d_ws, size_t ws_size,
                              hipStream_t stream) {
    const float* images   = (const float*)d_in[0];
    const int*   captions = (const int*)d_in[1];
    const float* conv1_w  = (const float*)d_in[2];
    const float* bn1_g = (const float*)d_in[3], *bn1_b = (const float*)d_in[4];
    const float* bn1_m = (const float*)d_in[5], *bn1_v = (const float*)d_in[6];
    const float* conv2_w  = (const float*)d_in[7];
    const float* bn2_g = (const float*)d_in[8], *bn2_b = (const float*)d_in[9];
    const float* bn2_m = (const float*)d_in[10], *bn2_v = (const float*)d_in[11];
    const float* conv3_w  = (const float*)d_in[12];
    const float* bn3_g = (const float*)d_in[13], *bn3_b = (const float*)d_in[14];
    const float* bn3_m = (const float*)d_in[15], *bn3_v = (const float*)d_in[16];
    const float* conv4_w  = (const float*)d_in[17];
    const float* bn4_g = (const float*)d_in[18], *bn4_b = (const float*)d_in[19];
    const float* bn4_m = (const float*)d_in[20], *bn4_v = (const float*)d_in[21];
    const float* emb_table = (const float*)d_in[22];
    const float* attn_w   = (const float*)d_in[23];
    const float* w_ih     = (const float*)d_in[24];
    const float* w_hh     = (const float*)d_in[25];
    const float* b_ih     = (const float*)d_in[26];
    const float* b_hh     = (const float*)d_in[27];
    const float* fc_w     = (const float*)d_in[28];
    const float* fc_b     = (const float*)d_in[29];
    float* out = (float*)d_out;

    // ---- workspace layout ----
    char* base = (char*)d_ws;
    size_t off = 0;
    auto alloc = [&](size_t bytes) { char* p = base + off; off += (bytes + 255) & ~(size_t)255; return p; };
    float* s1 = (float*)alloc(64 * 4);   float* bb1 = (float*)alloc(64 * 4);
    float* s2 = (float*)alloc(128 * 4);  float* bb2 = (float*)alloc(128 * 4);
    float* s3 = (float*)alloc(256 * 4);  float* bb3 = (float*)alloc(256 * 4);
    float* s4 = (float*)alloc(768 * 4);  float* bb4 = (float*)alloc(768 * 4);
    ushort_t* c1out = (ushort_t*)alloc((size_t)32 * 34 * 112 * 64 * 2);
    size_t halo_start = off;
    ushort_t* hal2 = (ushort_t*)alloc((size_t)32 * 19 * 58 * 64 * 2);
    ushort_t* hal3 = (ushort_t*)alloc((size_t)32 * 18 * 58 * 128 * 2);
    ushort_t* hal4 = (ushort_t*)alloc((size_t)32 * 10 * 30 * 256 * 2);
    size_t halo_bytes = off - halo_start;
    ushort_t* memv = (ushort_t*)alloc((size_t)32 * 196 * 768 * 2);
    ushort_t* KT   = (ushort_t*)alloc((size_t)32 * 96 * 196 * 8 * 2);
    ushort_t* wb1 = (ushort_t*)alloc((size_t)64 * 160 * 2);
    ushort_t* wb2 = (ushort_t*)alloc((size_t)128 * 9 * 64 * 2);
    ushort_t* wb3 = (ushort_t*)alloc((size_t)256 * 9 * 128 * 2);
    ushort_t* wb4 = (ushort_t*)alloc((size_t)768 * 9 * 256 * 2);
    ushort_t* wattnTP = (ushort_t*)alloc((size_t)768 * 768 * 2);
    ushort_t* wcombP = (ushort_t*)alloc((size_t)3072 * 1536 * 2);
    ushort_t* wihL = (ushort_t*)alloc((size_t)3072 * 768 * 2);
    ushort_t* e512P = (ushort_t*)alloc((size_t)512 * 768 * 2);
    float* eg   = (float*)alloc((size_t)512 * 3072 * 4);
    ushort_t* HallP = (ushort_t*)alloc((size_t)512 * 768 * 2);
    float* hbuf = (float*)alloc(NB * NH * 4);
    float* cbuf = (float*)alloc(NB * NH * 4);
    ushort_t* xinA = (ushort_t*)alloc((size_t)NB * 1536 * 2);
    ushort_t* xinB = (ushort_t*)alloc((size_t)NB * 1536 * 2);
    float* part = (float*)alloc((size_t)3 * 6272 * 768 * 4);   // conv4 split partials
    // union: im2col (39 MB, dead after conv1_gemm) then fc_w bf16 (49.2 MB)
    char* ubig = alloc((size_t)NV * NH * 2);
    ushort_t* imcol = (ushort_t*)ubig;
    ushort_t* fcwb  = (ushort_t*)ubig;

    // ---- merged one-time transforms (1 launch) ----
    long long n8 = (long long)(halo_bytes / 8);
    long long prep_total = (long long)SEG9 + n8;
    prep_all<<<(unsigned)((prep_total + 255) / 256), 256, 0, stream>>>(
        bn1_g, bn1_b, bn1_m, bn1_v, bn2_g, bn2_b, bn2_m, bn2_v,
        bn3_g, bn3_b, bn3_m, bn3_v, bn4_g, bn4_b, bn4_m, bn4_v,
        s1, bb1, s2, bb2, s3, bb3, s4, bb4,
        conv1_w, wb1, conv2_w, wb2, conv3_w, wb3, conv4_w, wb4,
        attn_w, wattnTP, w_ih, w_hh, wcombP, wihL,
        captions, emb_table, e512P,
        hbuf, cbuf, xinA,
        (unsigned long long*)hal2, n8);

    // ---- decoder precompute GEMM (independent of encoder) ----
    gemm_ldsb<0><<<96, 256, 0, stream>>>(e512P, wihL, b_ih, b_hh, eg, 3072);

    // ---- encoder ----
    im2col1<<<(121856 * 160 + 255) / 256, 256, 0, stream>>>(images, imcol);
    conv1_gemm<<<476, 256, 0, stream>>>(imcol, wb1, s1, bb1, c1out);
    // imcol dead -> convert fc_w (f32->bf16 row-major) into same buffer
    cvt_b16rows<<<(NV * 96 + 255) / 256, 256, 0, stream>>>(fc_w, fcwb, 96, 768, NV * 96);
    pool_kernel<<<(32 * 17 * 56 * 8 + 255) / 256, 256, 0, stream>>>(c1out, hal2);
    conv_mfma<64, 19, 58, 1, 16, 56, 128, 18, 58>
        <<<896, 64, 0, stream>>>(hal2, wb2, s2, bb2, hal3);
    conv_mfma<128, 18, 58, 2, 8, 28, 256, 10, 30>
        <<<448, 64, 0, stream>>>(hal3, wb3, s3, bb3, hal4);
    conv4_split<<<3528, 64, 0, stream>>>(hal4, wb4, part);
    comb4<<<(6272 * 192 + 255) / 256, 256, 0, stream>>>(part, s4, bb4, memv);

    // ---- attention K~ precompute: KT = mem @ attn_w ----
    kmat_gemm<<<1176, 64, 0, stream>>>(memv, wattnTP, KT);

    // ---- sequential decoder (xin double-buffered) ----
    ushort_t* xcur = xinA;
    ushort_t* xnxt = xinB;
    for (int t = 0; t < NT; ++t) {
        attn2<<<NB, NH, 0, stream>>>(xcur, KT, memv);
        step_fused<<<48, 256, 0, stream>>>(
            xcur, wcombP, eg + (size_t)t * NB * 3072, cbuf, hbuf, xnxt, HallP, t);
        ushort_t* tmp = xcur; xcur = xnxt; xnxt = tmp;
    }

    // ---- vocab projection for all 16 steps at once ----
    gemm_ldsb<1><<<1000, 256, 0, stream>>>(HallP, fcwb, fc_b, nullptr, out, NV);

    copy_hc<<<(NB * NH + 255) / 256, 256, 0, stream>>>(hbuf, cbuf, out);
}

// Round 17
// 879.981 us; speedup vs baseline: 1.0280x; 1.0255x over previous
//
#include <hip/hip_runtime.h>
#include <math.h>

#define NB 32
#define NT 16
#define NH 768
#define NV 32000

typedef short bf16x8 __attribute__((ext_vector_type(8)));
typedef float floatx4 __attribute__((ext_vector_type(4)));
typedef unsigned short ushort_t;

__device__ __forceinline__ float bf2f(unsigned short h) {
    unsigned u = ((unsigned)h) << 16;
    return __builtin_bit_cast(float, u);
}
__device__ __forceinline__ unsigned short f2bf(float f) {
    unsigned u = __builtin_bit_cast(unsigned, f);
    u += 0x7fffu + ((u >> 16) & 1u);
    return (unsigned short)(u >> 16);
}
__device__ __forceinline__ float sigmoidf_(float x) { return 1.f / (1.f + expf(-x)); }

// XCD-chunk swizzle: grid size N % 8 == 0.
__device__ __forceinline__ int swz8(int bid, int N) {
    return (bid & 7) * (N >> 3) + (bid >> 3);
}

__device__ __forceinline__ bf16x8 cvt8(float4 a, float4 b) {
    bf16x8 t;
    t[0] = (short)f2bf(a.x); t[1] = (short)f2bf(a.y);
    t[2] = (short)f2bf(a.z); t[3] = (short)f2bf(a.w);
    t[4] = (short)f2bf(b.x); t[5] = (short)f2bf(b.y);
    t[6] = (short)f2bf(b.z); t[7] = (short)f2bf(b.w);
    return t;
}

// ---------------- ONE merged prep kernel ----------------
#define SEG0 1216
#define SEG1 (SEG0 + 10240)
#define SEG2 (SEG1 + 73728)
#define SEG3 (SEG2 + 294912)
#define SEG4 (SEG3 + 1769472)
#define SEG5 (SEG4 + 589824)
#define SEG6 (SEG5 + 4718592)
#define SEG7 (SEG6 + 294912)
#define SEG8 (SEG7 + 393216)
#define SEG9 (SEG8 + 49152)
__global__ __launch_bounds__(256) void prep_all(
    const float* __restrict__ g1, const float* __restrict__ b1, const float* __restrict__ m1, const float* __restrict__ v1,
    const float* __restrict__ g2, const float* __restrict__ b2, const float* __restrict__ m2, const float* __restrict__ v2,
    const float* __restrict__ g3, const float* __restrict__ b3, const float* __restrict__ m3, const float* __restrict__ v3,
    const float* __restrict__ g4, const float* __restrict__ b4, const float* __restrict__ m4, const float* __restrict__ v4,
    float* __restrict__ s1, float* __restrict__ o1, float* __restrict__ s2, float* __restrict__ o2,
    float* __restrict__ s3, float* __restrict__ o3, float* __restrict__ s4, float* __restrict__ o4,
    const float* __restrict__ conv1_w, ushort_t* __restrict__ wb1,
    const float* __restrict__ conv2_w, ushort_t* __restrict__ wb2,
    const float* __restrict__ conv3_w, ushort_t* __restrict__ wb3,
    const float* __restrict__ conv4_w, ushort_t* __restrict__ wb4,
    const float* __restrict__ attn_w, ushort_t* __restrict__ wattnTP,
    const float* __restrict__ w_ih, const float* __restrict__ w_hh, ushort_t* __restrict__ wcombP,
    ushort_t* __restrict__ wihL,
    const int* __restrict__ caps, const float* __restrict__ table, ushort_t* __restrict__ e512P,
    float* __restrict__ hbuf, float* __restrict__ cbuf, ushort_t* __restrict__ xinA,
    unsigned long long* __restrict__ halo, long long n8) {
    long long gi = (long long)blockIdx.x * 256 + threadIdx.x;
    if (gi < SEG0) {
        int i = (int)gi;
        const float *g, *b, *m, *v;
        float *s, *o;
        int c;
        if (i < 64)        { g = g1; b = b1; m = m1; v = v1; s = s1; o = o1; c = i; }
        else if (i < 192)  { g = g2; b = b2; m = m2; v = v2; s = s2; o = o2; c = i - 64; }
        else if (i < 448)  { g = g3; b = b3; m = m3; v = v3; s = s3; o = o3; c = i - 192; }
        else               { g = g4; b = b4; m = m4; v = v4; s = s4; o = o4; c = i - 448; }
        float inv = g[c] * rsqrtf(v[c] + 1e-5f);
        s[c] = inv;
        o[c] = b[c] - m[c] * inv;
    } else if (gi < SEG1) {
        int idx = (int)(gi - SEG0);
        int co = idx / 160, k = idx % 160;
        wb1[idx] = (k < 147) ? f2bf(conv1_w[co * 147 + k]) : (ushort_t)0;
    } else if (gi < SEG4) {
        const float* w;
        ushort_t* dst;
        int CIN, idx;
        if (gi < SEG2)      { w = conv2_w; dst = wb2; CIN = 64;  idx = (int)(gi - SEG1); }
        else if (gi < SEG3) { w = conv3_w; dst = wb3; CIN = 128; idx = (int)(gi - SEG2); }
        else                { w = conv4_w; dst = wb4; CIN = 256; idx = (int)(gi - SEG3); }
        int e = idx & 7, lane = (idx >> 3) & 63, j = (idx >> 9) & 3;
        int r = idx >> 11;
        int KQ = CIN >> 5;
        int kq = r % KQ; r /= KQ;
        int tap = r % 9; int nt = r / 9;
        int co = nt * 64 + j * 16 + (lane & 15);
        int ci = kq * 32 + (lane >> 4) * 8 + e;
        dst[idx] = f2bf(w[((size_t)co * CIN + ci) * 9 + tap]);
    } else if (gi < SEG5) {
        int idx = (int)(gi - SEG4);
        int e = idx & 7, lane = (idx >> 3) & 63, j = (idx >> 9) & 3;
        int t = idx >> 11;
        int kq = t % 24, nt = t / 24;
        int n = nt * 64 + 16 * j + (lane & 15);
        int k = kq * 32 + (lane >> 4) * 8 + e;
        wattnTP[idx] = f2bf(attn_w[(size_t)k * 768 + n]);
    } else if (gi < SEG6) {
        int idx = (int)(gi - SEG5);
        int e = idx & 7, lane = (idx >> 3) & 63;
        int t = idx >> 9;
        int kq = t % 48, gg = t / 48;
        int g = gg & 3, bx = gg >> 2;
        int j = g * 768 + bx * 16 + (lane & 15);
        int k = kq * 32 + (lane >> 4) * 8 + e;
        float v = (k < NH) ? w_ih[(size_t)j * (2 * NH) + NH + k] : w_hh[(size_t)j * NH + (k - NH)];
        wcombP[idx] = f2bf(v);
    } else if (gi < SEG7) {
        int idx = (int)(gi - SEG6);
        int r = idx / 96, g = idx % 96;
        const float4* s = (const float4*)(w_ih + (size_t)r * 1536 + g * 8);
        *(bf16x8*)(wihL + (size_t)idx * 8) = cvt8(s[0], s[1]);
    } else if (gi < SEG8) {
        int idx = (int)(gi - SEG7);
        int e = idx & 7, lane = (idx >> 3) & 63, i = (idx >> 9) & 3;
        int t2 = idx >> 11;
        int kq = t2 % 24, mt = t2 / 24;
        int r = mt * 64 + i * 16 + (lane & 15);
        int k = kq * 32 + (lane >> 4) * 8 + e;
        int t = r >> 5, b = r & 31;
        e512P[idx] = f2bf(table[(size_t)caps[b * NT + t] * NH + k]);
    } else if (gi < SEG9) {
        int i = (int)(gi - SEG8);
        xinA[i] = 0;
        if (i < NB * NH) { hbuf[i] = 0.f; cbuf[i] = 0.f; }
    } else {
        long long j = gi - SEG9;
        if (j < n8) halo[j] = 0ULL;
    }
}

// ---------------- conv1 im2col ----------------
__global__ __launch_bounds__(256) void im2col1(const float* __restrict__ img, ushort_t* __restrict__ A) {
    int idx = blockIdx.x * 256 + threadIdx.x;
    const int total = 121856 * 160;
    if (idx >= total) return;
    int k = idx % 160;
    int m = idx / 160;
    ushort_t v = 0;
    if (k < 147) {
        int b = m / 3808;
        int rm = m % 3808;
        int y = rm / 112, x = rm % 112;
        int ci = k / 49;
        int r = k % 49;
        int ky = r / 7, kx = r % 7;
        int iy = 2 * y - 3 + ky;
        int ix = 2 * x - 3 + kx;
        if ((unsigned)iy < 224u && (unsigned)ix < 224u)
            v = f2bf(img[((size_t)(b * 3 + ci) * 224 + iy) * 224 + ix]);
    }
    A[idx] = v;
}

// rows of f32 -> bf16 (fc weights)
__global__ __launch_bounds__(256) void cvt_b16rows(const float* __restrict__ src, ushort_t* __restrict__ dst,
                                                   int cols8, int ldsrc, int total8) {
    int i = blockIdx.x * 256 + threadIdx.x;
    if (i >= total8) return;
    int r = i / cols8, g = i % cols8;
    const float4* s = (const float4*)(src + (size_t)r * ldsrc + g * 8);
    *(bf16x8*)(dst + (size_t)i * 8) = cvt8(s[0], s[1]);
}

// ---------------- conv1 GEMM ----------------
__global__ __launch_bounds__(256) void conv1_gemm(
    const ushort_t* __restrict__ A, const ushort_t* __restrict__ Bw,
    const float* __restrict__ scale, const float* __restrict__ bias,
    ushort_t* __restrict__ out) {
    int lane = threadIdx.x & 63, w = threadIdx.x >> 6;
    int m0 = (blockIdx.x * 4 + w) * 64;
    int lr = lane & 15, kl = (lane >> 4) * 8;
    floatx4 acc[4][4];
    #pragma unroll
    for (int i = 0; i < 4; ++i)
        #pragma unroll
        for (int j = 0; j < 4; ++j) acc[i][j] = 0.f;
    #pragma unroll
    for (int k0 = 0; k0 < 160; k0 += 32) {
        bf16x8 a[4], bb[4];
        #pragma unroll
        for (int i = 0; i < 4; ++i) a[i] = *(const bf16x8*)(A + (size_t)(m0 + 16 * i + lr) * 160 + kl + k0);
        #pragma unroll
        for (int j = 0; j < 4; ++j) bb[j] = *(const bf16x8*)(Bw + (size_t)(16 * j + lr) * 160 + kl + k0);
        #pragma unroll
        for (int i = 0; i < 4; ++i)
            #pragma unroll
            for (int j = 0; j < 4; ++j)
                acc[i][j] = __builtin_amdgcn_mfma_f32_16x16x32_bf16(a[i], bb[j], acc[i][j], 0, 0, 0);
    }
    #pragma unroll
    for (int i = 0; i < 4; ++i) {
        #pragma unroll
        for (int r = 0; r < 4; ++r) {
            int m = m0 + 16 * i + (lane >> 4) * 4 + r;
            int b = m / 3808;
            int rm = m % 3808;
            int y = rm / 112, x = rm % 112;
            #pragma unroll
            for (int j = 0; j < 4; ++j) {
                int n = 16 * j + lr;
                float v = fmaxf(acc[i][j][r] * scale[n] + bias[n], 0.f);
                out[((size_t)(b * 34 + y) * 112 + x) * 64 + n] = f2bf(v);
            }
        }
    }
}

// ---------------- maxpool 3x3 s2 p1 ----------------
__global__ __launch_bounds__(256) void pool_kernel(const ushort_t* __restrict__ in,
                                                   ushort_t* __restrict__ hal2) {
    int idx = blockIdx.x * 256 + threadIdx.x;
    const int total = 32 * 17 * 56 * 8;
    if (idx >= total) return;
    int c8 = idx & 7;
    int rest = idx >> 3;
    int x = rest % 56; rest /= 56;
    int y = rest % 17; int b = rest / 17;
    float mx[8];
    #pragma unroll
    for (int j = 0; j < 8; ++j) mx[j] = -INFINITY;
    for (int dy = -1; dy <= 1; ++dy) {
        int iy = 2 * y + dy;
        if ((unsigned)iy >= 34u) continue;
        for (int dx = -1; dx <= 1; ++dx) {
            int ix = 2 * x + dx;
            if ((unsigned)ix >= 112u) continue;
            bf16x8 v = *(const bf16x8*)(in + (((size_t)(b * 34 + iy)) * 112 + ix) * 64 + c8 * 8);
            #pragma unroll
            for (int j = 0; j < 8; ++j) mx[j] = fmaxf(mx[j], bf2f((unsigned short)v[j]));
        }
    }
    bf16x8 o;
    #pragma unroll
    for (int j = 0; j < 8; ++j) o[j] = (short)f2bf(mx[j]);
    *(bf16x8*)(hal2 + (((size_t)(b * 19 + y + 1)) * 58 + (x + 1)) * 64 + c8 * 8) = o;
}

// ---------------- implicit-GEMM 3x3 conv via MFMA (conv2/conv3), prefetch + swizzle ----------------
template <int CIN, int HH, int WH, int STRIDE, int HOUT, int WOUT, int COUT, int OH, int OW>
__global__ __launch_bounds__(64) void conv_mfma(
    const ushort_t* __restrict__ in, const ushort_t* __restrict__ wtP,
    const float* __restrict__ scale, const float* __restrict__ bias,
    ushort_t* __restrict__ out) {
    const int KQ = CIN / 32;
    const int NK = 9 * KQ;
    const int MT = (32 * HOUT * WOUT) / 64;
    const int NTL = COUT / 64;
    int id = swz8(blockIdx.x, MT * NTL);
    int mt = id % MT, nt = id / MT;
    int lane = threadIdx.x;
    int lr = lane & 15, kl = (lane >> 4) * 8;
    int rowoff[4];
    #pragma unroll
    for (int i = 0; i < 4; ++i) {
        int m = mt * 64 + 16 * i + lr;
        int b = m / (HOUT * WOUT);
        int rm = m % (HOUT * WOUT);
        int y = rm / WOUT, x = rm % WOUT;
        rowoff[i] = ((b * HH + y * STRIDE) * WH + x * STRIDE) * CIN + kl;
    }
    floatx4 acc[4][4];
    #pragma unroll
    for (int i = 0; i < 4; ++i)
        #pragma unroll
        for (int j = 0; j < 4; ++j) acc[i][j] = 0.f;

    auto ioffOf = [&](int ks) {
        int tap = ks / KQ;
        int k0 = (ks & (KQ - 1)) * 32;
        int ky = tap / 3, kx = tap - ky * 3;
        return (ky * WH + kx) * CIN + k0;
    };
    const ushort_t* bbase = wtP + ((size_t)nt * 9 * KQ * 4 * 64 + lane) * 8;

    bf16x8 aC[4], bC[4], aN[4], bN[4];
    {
        int io = ioffOf(0);
        #pragma unroll
        for (int i = 0; i < 4; ++i) aC[i] = *(const bf16x8*)(in + rowoff[i] + io);
        #pragma unroll
        for (int j = 0; j < 4; ++j) bC[j] = *(const bf16x8*)(bbase + ((size_t)j * 64) * 8);
    }
    for (int ks = 0; ks < NK; ks += 2) {
        {
            int io = ioffOf(ks + 1);
            #pragma unroll
            for (int i = 0; i < 4; ++i) aN[i] = *(const bf16x8*)(in + rowoff[i] + io);
            #pragma unroll
            for (int j = 0; j < 4; ++j) bN[j] = *(const bf16x8*)(bbase + ((size_t)((ks + 1) * 4 + j) * 64) * 8);
        }
        #pragma unroll
        for (int i = 0; i < 4; ++i)
            #pragma unroll
            for (int j = 0; j < 4; ++j)
                acc[i][j] = __builtin_amdgcn_mfma_f32_16x16x32_bf16(aC[i], bC[j], acc[i][j], 0, 0, 0);
        if (ks + 2 < NK) {
            int io = ioffOf(ks + 2);
            #pragma unroll
            for (int i = 0; i < 4; ++i) aC[i] = *(const bf16x8*)(in + rowoff[i] + io);
            #pragma unroll
            for (int j = 0; j < 4; ++j) bC[j] = *(const bf16x8*)(bbase + ((size_t)((ks + 2) * 4 + j) * 64) * 8);
        }
        #pragma unroll
        for (int i = 0; i < 4; ++i)
            #pragma unroll
            for (int j = 0; j < 4; ++j)
                acc[i][j] = __builtin_amdgcn_mfma_f32_16x16x32_bf16(aN[i], bN[j], acc[i][j], 0, 0, 0);
    }
    #pragma unroll
    for (int i = 0; i < 4; ++i) {
        #pragma unroll
        for (int r = 0; r < 4; ++r) {
            int m = mt * 64 + 16 * i + (lane >> 4) * 4 + r;
            int b = m / (HOUT * WOUT);
            int rm = m % (HOUT * WOUT);
            int y = rm / WOUT, x = rm % WOUT;
            #pragma unroll
            for (int j = 0; j < 4; ++j) {
                int n = nt * 64 + 16 * j + lr;
                float v = fmaxf(acc[i][j][r] * scale[n] + bias[n], 0.f);
                out[((size_t)(b * OH + y + 1) * OW + (x + 1)) * COUT + n] = f2bf(v);
            }
        }
    }
}

// ---------------- conv4: 4-wave LDS-staged-A implicit GEMM ----------------
// grid (98, 3), block 256. Wave w -> nt = by*4+w. Per k-step the block stages the
// 64x32 A-chunk coalesced into padded LDS [64][40] (double-buffered), then waves
// ds_read fragments + packed-B global loads + 16 MFMA. Kills the 16-way scattered
// per-lane A loads (VMEM request-rate bound) and shares A across 4 waves.
__global__ __launch_bounds__(256) void conv4_lds(
    const ushort_t* __restrict__ in, const ushort_t* __restrict__ wtP,
    const float* __restrict__ scale, const float* __restrict__ bias,
    ushort_t* __restrict__ memv) {
    const int CIN = 256, WH = 30, HOUT = 7, WOUT = 28;
    __shared__ ushort_t at[2][64 * 40];
    int tid = threadIdx.x;
    int lane = tid & 63, w = tid >> 6;
    int mt = blockIdx.x;
    int nt = blockIdx.y * 4 + w;
    int lr = lane & 15, kl = (lane >> 4) * 8;
    // staging coords: thread -> row srow (0..63), 16B chunk sc (0..3)
    int srow = tid >> 2, sc = tid & 3;
    int m_s = mt * 64 + srow;
    int b_s = m_s / 196, rm_s = m_s % 196;
    int y_s = rm_s / 28, x_s = rm_s % 28;
    const ushort_t* arow = in + ((size_t)(b_s * 10 + y_s) * 30 + x_s) * CIN + sc * 8;
    ushort_t* wslot = &at[0][0];  // indexed per-iter
    int woff = srow * 40 + sc * 8;

    floatx4 acc[4][4];
    #pragma unroll
    for (int i = 0; i < 4; ++i)
        #pragma unroll
        for (int j = 0; j < 4; ++j) acc[i][j] = 0.f;

    auto ioffOf = [&](int ks) {
        int tap = ks >> 3;
        int k0 = (ks & 7) * 32;
        int ky = tap / 3, kx = tap - ky * 3;
        return (ky * WH + kx) * CIN + k0;
    };
    const ushort_t* bbase = wtP + ((size_t)nt * 72 * 4 * 64 + lane) * 8;

    bf16x8 sreg = *(const bf16x8*)(arow + ioffOf(0));
    for (int ks = 0; ks < 72; ++ks) {
        *(bf16x8*)(&at[ks & 1][0] + woff) = sreg;
        if (ks + 1 < 72) sreg = *(const bf16x8*)(arow + ioffOf(ks + 1));
        __syncthreads();
        bf16x8 a[4], bb[4];
        #pragma unroll
        for (int j = 0; j < 4; ++j)
            bb[j] = *(const bf16x8*)(bbase + ((size_t)(ks * 4 + j) * 64) * 8);
        #pragma unroll
        for (int i = 0; i < 4; ++i)
            a[i] = *(const bf16x8*)(&at[ks & 1][0] + (16 * i + lr) * 40 + kl);
        #pragma unroll
        for (int i = 0; i < 4; ++i)
            #pragma unroll
            for (int j = 0; j < 4; ++j)
                acc[i][j] = __builtin_amdgcn_mfma_f32_16x16x32_bf16(a[i], bb[j], acc[i][j], 0, 0, 0);
        __syncthreads();
    }
    #pragma unroll
    for (int i = 0; i < 4; ++i) {
        #pragma unroll
        for (int r = 0; r < 4; ++r) {
            int m = mt * 64 + 16 * i + (lane >> 4) * 4 + r;
            #pragma unroll
            for (int j = 0; j < 4; ++j) {
                int n = nt * 64 + 16 * j + lr;
                float v = fmaxf(acc[i][j][r] * scale[n] + bias[n], 0.f);
                memv[(size_t)m * 768 + n] = f2bf(v);
            }
        }
    }
}

// ---------------- kmat: 4-wave LDS-staged-A; KT [b][96][196][8] ----------------
__global__ __launch_bounds__(256) void kmat_lds(
    const ushort_t* __restrict__ memv, const ushort_t* __restrict__ Bp,
    ushort_t* __restrict__ KT) {
    __shared__ ushort_t at[2][64 * 40];
    int tid = threadIdx.x;
    int lane = tid & 63, w = tid >> 6;
    int mt = blockIdx.x;
    int nt = blockIdx.y * 4 + w;
    int lr = lane & 15, kl = (lane >> 4) * 8;
    int srow = tid >> 2, sc = tid & 3;
    const ushort_t* arow = memv + (size_t)(mt * 64 + srow) * 768 + sc * 8;
    int woff = srow * 40 + sc * 8;
    const ushort_t* bbase = Bp + ((size_t)nt * 24 * 4 * 64 + lane) * 8;

    floatx4 acc[4][4];
    #pragma unroll
    for (int i = 0; i < 4; ++i)
        #pragma unroll
        for (int j = 0; j < 4; ++j) acc[i][j] = 0.f;

    bf16x8 sreg = *(const bf16x8*)(arow);
    for (int ks = 0; ks < 24; ++ks) {
        *(bf16x8*)(&at[ks & 1][0] + woff) = sreg;
        if (ks + 1 < 24) sreg = *(const bf16x8*)(arow + (ks + 1) * 32);
        __syncthreads();
        bf16x8 a[4], bb[4];
        #pragma unroll
        for (int j = 0; j < 4; ++j)
            bb[j] = *(const bf16x8*)(bbase + ((size_t)(ks * 4 + j) * 64) * 8);
        #pragma unroll
        for (int i = 0; i < 4; ++i)
            a[i] = *(const bf16x8*)(&at[ks & 1][0] + (16 * i + lr) * 40 + kl);
        #pragma unroll
        for (int i = 0; i < 4; ++i)
            #pragma unroll
            for (int j = 0; j < 4; ++j)
                acc[i][j] = __builtin_amdgcn_mfma_f32_16x16x32_bf16(a[i], bb[j], acc[i][j], 0, 0, 0);
        __syncthreads();
    }
    #pragma unroll
    for (int i = 0; i < 4; ++i) {
        #pragma unroll
        for (int r = 0; r < 4; ++r) {
            int mg = mt * 64 + 16 * i + (lane >> 4) * 4 + r;
            int b = mg / 196, m = mg % 196;
            #pragma unroll
            for (int j = 0; j < 4; ++j) {
                int n = nt * 64 + 16 * j + lr;
                KT[(((size_t)b * 96 + (n >> 3)) * 196 + m) * 8 + (n & 7)] = f2bf(acc[i][j][r]);
            }
        }
    }
}

// ---------------- occupancy-first GEMM: C[512][N] = Ap . Bb^T + bias; swizzled 1D grid ----------------
template <int REMAP>
__global__ __launch_bounds__(256, 4) void gemm_ldsb(
    const ushort_t* __restrict__ Ap, const ushort_t* __restrict__ Bb,
    const float* __restrict__ bias1, const float* __restrict__ bias2,
    float* __restrict__ C, int N) {
    __shared__ ushort_t bt[2][64 * 72];
    int tid = threadIdx.x;
    int lane = tid & 63, w = tid >> 6;
    int nblk = (N >> 6) * 2;
    int id = swz8(blockIdx.x, nblk);
    int nt = id >> 1, mh = id & 1;
    int n0 = nt * 64;
    int mt = mh * 4 + w;
    int lr = lane & 15, hi = lane >> 4;
    int srow = tid >> 2, sc = tid & 3;
    const ushort_t* gsrc = Bb + (size_t)(n0 + srow) * 768 + sc * 8;
    int woff = srow * 72 + sc * 8;
    floatx4 acc[4][4];
    #pragma unroll
    for (int i = 0; i < 4; ++i)
        #pragma unroll
        for (int j = 0; j < 4; ++j) acc[i][j] = 0.f;
    bf16x8 s0 = *(const bf16x8*)(gsrc);
    bf16x8 s1 = *(const bf16x8*)(gsrc + 32);
    for (int kc = 0; kc < 12; ++kc) {
        ushort_t* bufw = &bt[kc & 1][0];
        *(bf16x8*)(bufw + woff) = s0;
        *(bf16x8*)(bufw + woff + 32) = s1;
        if (kc < 11) {
            const ushort_t* p = gsrc + (size_t)(kc + 1) * 64;
            s0 = *(const bf16x8*)(p);
            s1 = *(const bf16x8*)(p + 32);
        }
        __syncthreads();
        const ushort_t* bufr = &bt[kc & 1][0];
        #pragma unroll
        for (int kk = 0; kk < 2; ++kk) {
            int kq = kc * 2 + kk;
            bf16x8 bfr[4], a[4];
            #pragma unroll
            for (int j = 0; j < 4; ++j)
                bfr[j] = *(const bf16x8*)(bufr + (j * 16 + lr) * 72 + kk * 32 + hi * 8);
            #pragma unroll
            for (int i = 0; i < 4; ++i)
                a[i] = *(const bf16x8*)(Ap + ((((size_t)mt * 24 + kq) * 4 + i) * 64 + lane) * 8);
            #pragma unroll
            for (int i = 0; i < 4; ++i)
                #pragma unroll
                for (int j = 0; j < 4; ++j)
                    acc[i][j] = __builtin_amdgcn_mfma_f32_16x16x32_bf16(a[i], bfr[j], acc[i][j], 0, 0, 0);
        }
    }
    #pragma unroll
    for (int i = 0; i < 4; ++i) {
        #pragma unroll
        for (int rr = 0; rr < 4; ++rr) {
            int m = mt * 64 + 16 * i + hi * 4 + rr;   // m = t*32+b
            #pragma unroll
            for (int j = 0; j < 4; ++j) {
                int n = n0 + 16 * j + lr;
                float vv = acc[i][j][rr];
                if (bias1) vv += bias1[n];
                if (bias2) vv += bias2[n];
                if (REMAP) {
                    int t = m >> 5, b = m & 31;
                    C[(size_t)((b << 4) + t) * NV + n] = vv;
                } else {
                    C[(size_t)m * N + n] = vv;
                }
            }
        }
    }
}

// ---------------- attention step (scores = h . K~[b]) ----------------
__global__ __launch_bounds__(768) void attn2(
    ushort_t* __restrict__ xin, const ushort_t* __restrict__ KT,
    const ushort_t* __restrict__ mem) {
    __shared__ float hq[NH];
    __shared__ float sl[196];
    __shared__ float red[16];
    int b = blockIdx.x, tid = threadIdx.x;
    hq[tid] = bf2f(xin[(size_t)b * 1536 + NH + tid]);
    __syncthreads();
    if (tid < 392) {
        int m = tid >> 1, half = tid & 1;
        const ushort_t* basep = KT + (((size_t)b * 96 + half * 48) * 196 + m) * 8;
        float acc = 0.f;
        #pragma unroll 4
        for (int k8 = 0; k8 < 48; ++k8) {
            bf16x8 v = *(const bf16x8*)(basep + (size_t)k8 * 196 * 8);
            const float* qp = hq + (half * 48 + k8) * 8;
            #pragma unroll
            for (int j = 0; j < 8; ++j)
                acc = fmaf(bf2f((unsigned short)v[j]), qp[j], acc);
        }
        acc += __shfl_xor(acc, 1);
        if (!half) sl[m] = acc;
    }
    __syncthreads();
    float sc = (tid < 196) ? sl[tid] : -INFINITY;
    float v = sc;
    #pragma unroll
    for (int off = 32; off; off >>= 1) v = fmaxf(v, __shfl_down(v, off));
    if ((tid & 63) == 0) red[tid >> 6] = v;
    __syncthreads();
    if (tid == 0) {
        float m = red[0];
        for (int i = 1; i < 12; ++i) m = fmaxf(m, red[i]);
        red[12] = m;
    }
    __syncthreads();
    float mx = red[12];
    float e = (tid < 196) ? expf(sc - mx) : 0.f;
    __syncthreads();
    v = e;
    #pragma unroll
    for (int off = 32; off; off >>= 1) v += __shfl_down(v, off);
    if ((tid & 63) == 0) red[tid >> 6] = v;
    __syncthreads();
    if (tid == 0) {
        float s = red[0];
        for (int i = 1; i < 12; ++i) s += red[i];
        red[12] = 1.f / s;
    }
    __syncthreads();
    if (tid < 196) sl[tid] = e * red[12];
    __syncthreads();
    {
        float acc = 0.f;
        const ushort_t* mb = mem + (size_t)b * 196 * NH + tid;
        #pragma unroll 4
        for (int m = 0; m < 196; ++m) acc = fmaf(sl[m], bf2f(mb[(size_t)m * NH]), acc);
        xin[(size_t)b * 1536 + tid] = f2bf(acc);
    }
}

// ---------------- fused gates GEMM + LSTM cell; writes Hall PACKED ----------------
__global__ __launch_bounds__(256) void step_fused(
    const ushort_t* __restrict__ xin_r, const ushort_t* __restrict__ wcombP,
    const float* __restrict__ eg_t,
    float* __restrict__ cbuf, float* __restrict__ hbuf,
    ushort_t* __restrict__ xin_w, ushort_t* __restrict__ hallP, int tstep) {
    __shared__ float pbuf[4][64][33];
    int lane = threadIdx.x & 63, w = threadIdx.x >> 6;
    int bx = blockIdx.x;
    int lr = lane & 15, kl = (lane >> 4) * 8;
    floatx4 acc[2][4];
    #pragma unroll
    for (int i = 0; i < 2; ++i)
        #pragma unroll
        for (int g = 0; g < 4; ++g) acc[i][g] = 0.f;
    for (int kq = 0; kq < 12; ++kq) {
        int k = w * 384 + kq * 32;
        bf16x8 a[2], bb[4];
        #pragma unroll
        for (int i = 0; i < 2; ++i)
            a[i] = *(const bf16x8*)(xin_r + (size_t)(16 * i + lr) * 1536 + k + kl);
        #pragma unroll
        for (int g = 0; g < 4; ++g)
            bb[g] = *(const bf16x8*)(wcombP + (((size_t)(bx * 4 + g) * 48 + (w * 12 + kq)) * 64 + lane) * 8);
        #pragma unroll
        for (int i = 0; i < 2; ++i)
            #pragma unroll
            for (int g = 0; g < 4; ++g)
                acc[i][g] = __builtin_amdgcn_mfma_f32_16x16x32_bf16(a[i], bb[g], acc[i][g], 0, 0, 0);
    }
    #pragma unroll
    for (int i = 0; i < 2; ++i)
        #pragma unroll
        for (int g = 0; g < 4; ++g)
            #pragma unroll
            for (int r = 0; r < 4; ++r) {
                int m = 16 * i + (lane >> 4) * 4 + r;
                pbuf[w][g * 16 + lr][m] = acc[i][g][r];
            }
    __syncthreads();
    int tid = threadIdx.x;
    #pragma unroll
    for (int o = 0; o < 2; ++o) {
        int pid = tid * 2 + o;          // 0..511
        int m = pid & 31, c = pid >> 5; // m = batch, c = 0..15
        int kcol = bx * 16 + c;
        float gi = 0.f, gf = 0.f, gg = 0.f, go = 0.f;
        #pragma unroll
        for (int ww = 0; ww < 4; ++ww) {
            gi += pbuf[ww][c][m];
            gf += pbuf[ww][16 + c][m];
            gg += pbuf[ww][32 + c][m];
            go += pbuf[ww][48 + c][m];
        }
        const float* eg = eg_t + (size_t)m * 3072;
        gi += eg[kcol];
        gf += eg[768 + kcol];
        gg += eg[1536 + kcol];
        go += eg[2304 + kcol];
        float cst = cbuf[m * 768 + kcol];
        float cn = sigmoidf_(gf) * cst + sigmoidf_(gi) * tanhf(gg);
        float hn = sigmoidf_(go) * tanhf(cn);
        cbuf[m * 768 + kcol] = cn;
        hbuf[m * 768 + kcol] = hn;
        ushort_t hb = f2bf(hn);
        xin_w[(size_t)m * 1536 + NH + kcol] = hb;
        int rrow = tstep * 32 + m;
        int mtp = rrow >> 6, ip = (rrow >> 4) & 3, lrp = rrow & 15;
        int kqp = kcol >> 5, hip = (kcol >> 3) & 3, ep = kcol & 7;
        hallP[((((size_t)mtp * 24 + kqp) * 4 + ip) * 64 + (lrp | (hip << 4))) * 8 + ep] = hb;
    }
}

__global__ __launch_bounds__(256) void copy_hc(const float* __restrict__ h, const float* __restrict__ c,
                                               float* __restrict__ out) {
    int i = blockIdx.x * 256 + threadIdx.x;
    if (i < NB * NH) {
        out[(size_t)NB * NT * NV + i] = h[i];
        out[(size_t)NB * NT * NV + NB * NH + i] = c[i];
    }
}

extern "C" void kernel_launch(void* const* d_in, const int* in_sizes, int n_in,
                              void* d_out, int out_size, void* d_ws, size_t ws_size,
                              hipStream_t stream) {
    const float* images   = (const float*)d_in[0];
    const int*   captions = (const int*)d_in[1];
    const float* conv1_w  = (const float*)d_in[2];
    const float* bn1_g = (const float*)d_in[3], *bn1_b = (const float*)d_in[4];
    const float* bn1_m = (const float*)d_in[5], *bn1_v = (const float*)d_in[6];
    const float* conv2_w  = (const float*)d_in[7];
    const float* bn2_g = (const float*)d_in[8], *bn2_b = (const float*)d_in[9];
    const float* bn2_m = (const float*)d_in[10], *bn2_v = (const float*)d_in[11];
    const float* conv3_w  = (const float*)d_in[12];
    const float* bn3_g = (const float*)d_in[13], *bn3_b = (const float*)d_in[14];
    const float* bn3_m = (const float*)d_in[15], *bn3_v = (const float*)d_in[16];
    const float* conv4_w  = (const float*)d_in[17];
    const float* bn4_g = (const float*)d_in[18], *bn4_b = (const float*)d_in[19];
    const float* bn4_m = (const float*)d_in[20], *bn4_v = (const float*)d_in[21];
    const float* emb_table = (const float*)d_in[22];
    const float* attn_w   = (const float*)d_in[23];
    const float* w_ih     = (const float*)d_in[24];
    const float* w_hh     = (const float*)d_in[25];
    const float* b_ih     = (const float*)d_in[26];
    const float* b_hh     = (const float*)d_in[27];
    const float* fc_w     = (const float*)d_in[28];
    const float* fc_b     = (const float*)d_in[29];
    float* out = (float*)d_out;

    // ---- workspace layout ----
    char* base = (char*)d_ws;
    size_t off = 0;
    auto alloc = [&](size_t bytes) { char* p = base + off; off += (bytes + 255) & ~(size_t)255; return p; };
    float* s1 = (float*)alloc(64 * 4);   float* bb1 = (float*)alloc(64 * 4);
    float* s2 = (float*)alloc(128 * 4);  float* bb2 = (float*)alloc(128 * 4);
    float* s3 = (float*)alloc(256 * 4);  float* bb3 = (float*)alloc(256 * 4);
    float* s4 = (float*)alloc(768 * 4);  float* bb4 = (float*)alloc(768 * 4);
    ushort_t* c1out = (ushort_t*)alloc((size_t)32 * 34 * 112 * 64 * 2);
    size_t halo_start = off;
    ushort_t* hal2 = (ushort_t*)alloc((size_t)32 * 19 * 58 * 64 * 2);
    ushort_t* hal3 = (ushort_t*)alloc((size_t)32 * 18 * 58 * 128 * 2);
    ushort_t* hal4 = (ushort_t*)alloc((size_t)32 * 10 * 30 * 256 * 2);
    size_t halo_bytes = off - halo_start;
    ushort_t* memv = (ushort_t*)alloc((size_t)32 * 196 * 768 * 2);
    ushort_t* KT   = (ushort_t*)alloc((size_t)32 * 96 * 196 * 8 * 2);
    ushort_t* wb1 = (ushort_t*)alloc((size_t)64 * 160 * 2);
    ushort_t* wb2 = (ushort_t*)alloc((size_t)128 * 9 * 64 * 2);
    ushort_t* wb3 = (ushort_t*)alloc((size_t)256 * 9 * 128 * 2);
    ushort_t* wb4 = (ushort_t*)alloc((size_t)768 * 9 * 256 * 2);
    ushort_t* wattnTP = (ushort_t*)alloc((size_t)768 * 768 * 2);
    ushort_t* wcombP = (ushort_t*)alloc((size_t)3072 * 1536 * 2);
    ushort_t* wihL = (ushort_t*)alloc((size_t)3072 * 768 * 2);
    ushort_t* e512P = (ushort_t*)alloc((size_t)512 * 768 * 2);
    float* eg   = (float*)alloc((size_t)512 * 3072 * 4);
    ushort_t* HallP = (ushort_t*)alloc((size_t)512 * 768 * 2);
    float* hbuf = (float*)alloc(NB * NH * 4);
    float* cbuf = (float*)alloc(NB * NH * 4);
    ushort_t* xinA = (ushort_t*)alloc((size_t)NB * 1536 * 2);
    ushort_t* xinB = (ushort_t*)alloc((size_t)NB * 1536 * 2);
    // union: im2col (39 MB, dead after conv1_gemm) then fc_w bf16 (49.2 MB)
    char* ubig = alloc((size_t)NV * NH * 2);
    ushort_t* imcol = (ushort_t*)ubig;
    ushort_t* fcwb  = (ushort_t*)ubig;

    // ---- merged one-time transforms (1 launch) ----
    long long n8 = (long long)(halo_bytes / 8);
    long long prep_total = (long long)SEG9 + n8;
    prep_all<<<(unsigned)((prep_total + 255) / 256), 256, 0, stream>>>(
        bn1_g, bn1_b, bn1_m, bn1_v, bn2_g, bn2_b, bn2_m, bn2_v,
        bn3_g, bn3_b, bn3_m, bn3_v, bn4_g, bn4_b, bn4_m, bn4_v,
        s1, bb1, s2, bb2, s3, bb3, s4, bb4,
        conv1_w, wb1, conv2_w, wb2, conv3_w, wb3, conv4_w, wb4,
        attn_w, wattnTP, w_ih, w_hh, wcombP, wihL,
        captions, emb_table, e512P,
        hbuf, cbuf, xinA,
        (unsigned long long*)hal2, n8);

    // ---- decoder precompute GEMM (independent of encoder) ----
    gemm_ldsb<0><<<96, 256, 0, stream>>>(e512P, wihL, b_ih, b_hh, eg, 3072);

    // ---- encoder ----
    im2col1<<<(121856 * 160 + 255) / 256, 256, 0, stream>>>(images, imcol);
    conv1_gemm<<<476, 256, 0, stream>>>(imcol, wb1, s1, bb1, c1out);
    // imcol dead -> convert fc_w (f32->bf16 row-major) into same buffer
    cvt_b16rows<<<(NV * 96 + 255) / 256, 256, 0, stream>>>(fc_w, fcwb, 96, 768, NV * 96);
    pool_kernel<<<(32 * 17 * 56 * 8 + 255) / 256, 256, 0, stream>>>(c1out, hal2);
    conv_mfma<64, 19, 58, 1, 16, 56, 128, 18, 58>
        <<<896, 64, 0, stream>>>(hal2, wb2, s2, bb2, hal3);
    conv_mfma<128, 18, 58, 2, 8, 28, 256, 10, 30>
        <<<448, 64, 0, stream>>>(hal3, wb3, s3, bb3, hal4);
    conv4_lds<<<dim3(98, 3), 256, 0, stream>>>(hal4, wb4, s4, bb4, memv);

    // ---- attention K~ precompute: KT = mem @ attn_w ----
    kmat_lds<<<dim3(98, 3), 256, 0, stream>>>(memv, wattnTP, KT);

    // ---- sequential decoder (xin double-buffered) ----
    ushort_t* xcur = xinA;
    ushort_t* xnxt = xinB;
    for (int t = 0; t < NT; ++t) {
        attn2<<<NB, NH, 0, stream>>>(xcur, KT, memv);
        step_fused<<<48, 256, 0, stream>>>(
            xcur, wcombP, eg + (size_t)t * NB * 3072, cbuf, hbuf, xnxt, HallP, t);
        ushort_t* tmp = xcur; xcur = xnxt; xnxt = tmp;
    }

    // ---- vocab projection for all 16 steps at once ----
    gemm_ldsb<1><<<1000, 256, 0, stream>>>(HallP, fcwb, fc_b, nullptr, out, NV);

    copy_hc<<<(NB * NH + 255) / 256, 256, 0, stream>>>(hbuf, cbuf, out);
}

// Round 18
// 857.861 us; speedup vs baseline: 1.0545x; 1.0258x over previous
//
#include <hip/hip_runtime.h>
#include <math.h>

#define NB 32
#define NT 16
#define NH 768
#define NV 32000

typedef short bf16x8 __attribute__((ext_vector_type(8)));
typedef float floatx4 __attribute__((ext_vector_type(4)));
typedef unsigned short ushort_t;

__device__ __forceinline__ float bf2f(unsigned short h) {
    unsigned u = ((unsigned)h) << 16;
    return __builtin_bit_cast(float, u);
}
__device__ __forceinline__ unsigned short f2bf(float f) {
    unsigned u = __builtin_bit_cast(unsigned, f);
    u += 0x7fffu + ((u >> 16) & 1u);
    return (unsigned short)(u >> 16);
}
__device__ __forceinline__ float sigmoidf_(float x) { return 1.f / (1.f + expf(-x)); }

// XCD-chunk swizzle: grid size N % 8 == 0.
__device__ __forceinline__ int swz8(int bid, int N) {
    return (bid & 7) * (N >> 3) + (bid >> 3);
}

__device__ __forceinline__ bf16x8 cvt8(float4 a, float4 b) {
    bf16x8 t;
    t[0] = (short)f2bf(a.x); t[1] = (short)f2bf(a.y);
    t[2] = (short)f2bf(a.z); t[3] = (short)f2bf(a.w);
    t[4] = (short)f2bf(b.x); t[5] = (short)f2bf(b.y);
    t[6] = (short)f2bf(b.z); t[7] = (short)f2bf(b.w);
    return t;
}

// ---------------- ONE merged prep kernel ----------------
#define SEG0 1216
#define SEG1 (SEG0 + 10240)
#define SEG2 (SEG1 + 73728)
#define SEG3 (SEG2 + 294912)
#define SEG4 (SEG3 + 1769472)
#define SEG5 (SEG4 + 589824)
#define SEG6 (SEG5 + 4718592)
#define SEG7 (SEG6 + 294912)
#define SEG8 (SEG7 + 393216)
#define SEG9 (SEG8 + 49152)
__global__ __launch_bounds__(256) void prep_all(
    const float* __restrict__ g1, const float* __restrict__ b1, const float* __restrict__ m1, const float* __restrict__ v1,
    const float* __restrict__ g2, const float* __restrict__ b2, const float* __restrict__ m2, const float* __restrict__ v2,
    const float* __restrict__ g3, const float* __restrict__ b3, const float* __restrict__ m3, const float* __restrict__ v3,
    const float* __restrict__ g4, const float* __restrict__ b4, const float* __restrict__ m4, const float* __restrict__ v4,
    float* __restrict__ s1, float* __restrict__ o1, float* __restrict__ s2, float* __restrict__ o2,
    float* __restrict__ s3, float* __restrict__ o3, float* __restrict__ s4, float* __restrict__ o4,
    const float* __restrict__ conv1_w, ushort_t* __restrict__ wb1,
    const float* __restrict__ conv2_w, ushort_t* __restrict__ wb2,
    const float* __restrict__ conv3_w, ushort_t* __restrict__ wb3,
    const float* __restrict__ conv4_w, ushort_t* __restrict__ wb4,
    const float* __restrict__ attn_w, ushort_t* __restrict__ wattnTP,
    const float* __restrict__ w_ih, const float* __restrict__ w_hh, ushort_t* __restrict__ wcombP,
    ushort_t* __restrict__ wihL,
    const int* __restrict__ caps, const float* __restrict__ table, ushort_t* __restrict__ e512P,
    float* __restrict__ hbuf, float* __restrict__ cbuf, ushort_t* __restrict__ xinA,
    unsigned long long* __restrict__ halo, long long n8) {
    long long gi = (long long)blockIdx.x * 256 + threadIdx.x;
    if (gi < SEG0) {
        int i = (int)gi;
        const float *g, *b, *m, *v;
        float *s, *o;
        int c;
        if (i < 64)        { g = g1; b = b1; m = m1; v = v1; s = s1; o = o1; c = i; }
        else if (i < 192)  { g = g2; b = b2; m = m2; v = v2; s = s2; o = o2; c = i - 64; }
        else if (i < 448)  { g = g3; b = b3; m = m3; v = v3; s = s3; o = o3; c = i - 192; }
        else               { g = g4; b = b4; m = m4; v = v4; s = s4; o = o4; c = i - 448; }
        float inv = g[c] * rsqrtf(v[c] + 1e-5f);
        s[c] = inv;
        o[c] = b[c] - m[c] * inv;
    } else if (gi < SEG1) {
        int idx = (int)(gi - SEG0);
        int co = idx / 160, k = idx % 160;
        wb1[idx] = (k < 147) ? f2bf(conv1_w[co * 147 + k]) : (ushort_t)0;
    } else if (gi < SEG4) {
        const float* w;
        ushort_t* dst;
        int CIN, idx;
        if (gi < SEG2)      { w = conv2_w; dst = wb2; CIN = 64;  idx = (int)(gi - SEG1); }
        else if (gi < SEG3) { w = conv3_w; dst = wb3; CIN = 128; idx = (int)(gi - SEG2); }
        else                { w = conv4_w; dst = wb4; CIN = 256; idx = (int)(gi - SEG3); }
        int e = idx & 7, lane = (idx >> 3) & 63, j = (idx >> 9) & 3;
        int r = idx >> 11;
        int KQ = CIN >> 5;
        int kq = r % KQ; r /= KQ;
        int tap = r % 9; int nt = r / 9;
        int co = nt * 64 + j * 16 + (lane & 15);
        int ci = kq * 32 + (lane >> 4) * 8 + e;
        dst[idx] = f2bf(w[((size_t)co * CIN + ci) * 9 + tap]);
    } else if (gi < SEG5) {
        int idx = (int)(gi - SEG4);
        int e = idx & 7, lane = (idx >> 3) & 63, j = (idx >> 9) & 3;
        int t = idx >> 11;
        int kq = t % 24, nt = t / 24;
        int n = nt * 64 + 16 * j + (lane & 15);
        int k = kq * 32 + (lane >> 4) * 8 + e;
        wattnTP[idx] = f2bf(attn_w[(size_t)k * 768 + n]);
    } else if (gi < SEG6) {
        int idx = (int)(gi - SEG5);
        int e = idx & 7, lane = (idx >> 3) & 63;
        int t = idx >> 9;
        int kq = t % 48, gg = t / 48;
        int g = gg & 3, bx = gg >> 2;
        int j = g * 768 + bx * 16 + (lane & 15);
        int k = kq * 32 + (lane >> 4) * 8 + e;
        float v = (k < NH) ? w_ih[(size_t)j * (2 * NH) + NH + k] : w_hh[(size_t)j * NH + (k - NH)];
        wcombP[idx] = f2bf(v);
    } else if (gi < SEG7) {
        int idx = (int)(gi - SEG6);
        int r = idx / 96, g = idx % 96;
        const float4* s = (const float4*)(w_ih + (size_t)r * 1536 + g * 8);
        *(bf16x8*)(wihL + (size_t)idx * 8) = cvt8(s[0], s[1]);
    } else if (gi < SEG8) {
        int idx = (int)(gi - SEG7);
        int e = idx & 7, lane = (idx >> 3) & 63, i = (idx >> 9) & 3;
        int t2 = idx >> 11;
        int kq = t2 % 24, mt = t2 / 24;
        int r = mt * 64 + i * 16 + (lane & 15);
        int k = kq * 32 + (lane >> 4) * 8 + e;
        int t = r >> 5, b = r & 31;
        e512P[idx] = f2bf(table[(size_t)caps[b * NT + t] * NH + k]);
    } else if (gi < SEG9) {
        int i = (int)(gi - SEG8);
        xinA[i] = 0;
        if (i < NB * NH) { hbuf[i] = 0.f; cbuf[i] = 0.f; }
    } else {
        long long j = gi - SEG9;
        if (j < n8) halo[j] = 0ULL;
    }
}

// ---------------- conv1 im2col ----------------
__global__ __launch_bounds__(256) void im2col1(const float* __restrict__ img, ushort_t* __restrict__ A) {
    int idx = blockIdx.x * 256 + threadIdx.x;
    const int total = 121856 * 160;
    if (idx >= total) return;
    int k = idx % 160;
    int m = idx / 160;
    ushort_t v = 0;
    if (k < 147) {
        int b = m / 3808;
        int rm = m % 3808;
        int y = rm / 112, x = rm % 112;
        int ci = k / 49;
        int r = k % 49;
        int ky = r / 7, kx = r % 7;
        int iy = 2 * y - 3 + ky;
        int ix = 2 * x - 3 + kx;
        if ((unsigned)iy < 224u && (unsigned)ix < 224u)
            v = f2bf(img[((size_t)(b * 3 + ci) * 224 + iy) * 224 + ix]);
    }
    A[idx] = v;
}

// rows of f32 -> bf16 (fc weights)
__global__ __launch_bounds__(256) void cvt_b16rows(const float* __restrict__ src, ushort_t* __restrict__ dst,
                                                   int cols8, int ldsrc, int total8) {
    int i = blockIdx.x * 256 + threadIdx.x;
    if (i >= total8) return;
    int r = i / cols8, g = i % cols8;
    const float4* s = (const float4*)(src + (size_t)r * ldsrc + g * 8);
    *(bf16x8*)(dst + (size_t)i * 8) = cvt8(s[0], s[1]);
}

// ---------------- conv1 GEMM ----------------
__global__ __launch_bounds__(256) void conv1_gemm(
    const ushort_t* __restrict__ A, const ushort_t* __restrict__ Bw,
    const float* __restrict__ scale, const float* __restrict__ bias,
    ushort_t* __restrict__ out) {
    int lane = threadIdx.x & 63, w = threadIdx.x >> 6;
    int m0 = (blockIdx.x * 4 + w) * 64;
    int lr = lane & 15, kl = (lane >> 4) * 8;
    floatx4 acc[4][4];
    #pragma unroll
    for (int i = 0; i < 4; ++i)
        #pragma unroll
        for (int j = 0; j < 4; ++j) acc[i][j] = 0.f;
    #pragma unroll
    for (int k0 = 0; k0 < 160; k0 += 32) {
        bf16x8 a[4], bb[4];
        #pragma unroll
        for (int i = 0; i < 4; ++i) a[i] = *(const bf16x8*)(A + (size_t)(m0 + 16 * i + lr) * 160 + kl + k0);
        #pragma unroll
        for (int j = 0; j < 4; ++j) bb[j] = *(const bf16x8*)(Bw + (size_t)(16 * j + lr) * 160 + kl + k0);
        #pragma unroll
        for (int i = 0; i < 4; ++i)
            #pragma unroll
            for (int j = 0; j < 4; ++j)
                acc[i][j] = __builtin_amdgcn_mfma_f32_16x16x32_bf16(a[i], bb[j], acc[i][j], 0, 0, 0);
    }
    #pragma unroll
    for (int i = 0; i < 4; ++i) {
        #pragma unroll
        for (int r = 0; r < 4; ++r) {
            int m = m0 + 16 * i + (lane >> 4) * 4 + r;
            int b = m / 3808;
            int rm = m % 3808;
            int y = rm / 112, x = rm % 112;
            #pragma unroll
            for (int j = 0; j < 4; ++j) {
                int n = 16 * j + lr;
                float v = fmaxf(acc[i][j][r] * scale[n] + bias[n], 0.f);
                out[((size_t)(b * 34 + y) * 112 + x) * 64 + n] = f2bf(v);
            }
        }
    }
}

// ---------------- maxpool 3x3 s2 p1 ----------------
__global__ __launch_bounds__(256) void pool_kernel(const ushort_t* __restrict__ in,
                                                   ushort_t* __restrict__ hal2) {
    int idx = blockIdx.x * 256 + threadIdx.x;
    const int total = 32 * 17 * 56 * 8;
    if (idx >= total) return;
    int c8 = idx & 7;
    int rest = idx >> 3;
    int x = rest % 56; rest /= 56;
    int y = rest % 17; int b = rest / 17;
    float mx[8];
    #pragma unroll
    for (int j = 0; j < 8; ++j) mx[j] = -INFINITY;
    for (int dy = -1; dy <= 1; ++dy) {
        int iy = 2 * y + dy;
        if ((unsigned)iy >= 34u) continue;
        for (int dx = -1; dx <= 1; ++dx) {
            int ix = 2 * x + dx;
            if ((unsigned)ix >= 112u) continue;
            bf16x8 v = *(const bf16x8*)(in + (((size_t)(b * 34 + iy)) * 112 + ix) * 64 + c8 * 8);
            #pragma unroll
            for (int j = 0; j < 8; ++j) mx[j] = fmaxf(mx[j], bf2f((unsigned short)v[j]));
        }
    }
    bf16x8 o;
    #pragma unroll
    for (int j = 0; j < 8; ++j) o[j] = (short)f2bf(mx[j]);
    *(bf16x8*)(hal2 + (((size_t)(b * 19 + y + 1)) * 58 + (x + 1)) * 64 + c8 * 8) = o;
}

// ---------------- implicit-GEMM 3x3 conv via MFMA (conv2/conv3), prefetch + swizzle ----------------
template <int CIN, int HH, int WH, int STRIDE, int HOUT, int WOUT, int COUT, int OH, int OW>
__global__ __launch_bounds__(64) void conv_mfma(
    const ushort_t* __restrict__ in, const ushort_t* __restrict__ wtP,
    const float* __restrict__ scale, const float* __restrict__ bias,
    ushort_t* __restrict__ out) {
    const int KQ = CIN / 32;
    const int NK = 9 * KQ;
    const int MT = (32 * HOUT * WOUT) / 64;
    const int NTL = COUT / 64;
    int id = swz8(blockIdx.x, MT * NTL);
    int mt = id % MT, nt = id / MT;
    int lane = threadIdx.x;
    int lr = lane & 15, kl = (lane >> 4) * 8;
    int rowoff[4];
    #pragma unroll
    for (int i = 0; i < 4; ++i) {
        int m = mt * 64 + 16 * i + lr;
        int b = m / (HOUT * WOUT);
        int rm = m % (HOUT * WOUT);
        int y = rm / WOUT, x = rm % WOUT;
        rowoff[i] = ((b * HH + y * STRIDE) * WH + x * STRIDE) * CIN + kl;
    }
    floatx4 acc[4][4];
    #pragma unroll
    for (int i = 0; i < 4; ++i)
        #pragma unroll
        for (int j = 0; j < 4; ++j) acc[i][j] = 0.f;

    auto ioffOf = [&](int ks) {
        int tap = ks / KQ;
        int k0 = (ks & (KQ - 1)) * 32;
        int ky = tap / 3, kx = tap - ky * 3;
        return (ky * WH + kx) * CIN + k0;
    };
    const ushort_t* bbase = wtP + ((size_t)nt * 9 * KQ * 4 * 64 + lane) * 8;

    bf16x8 aC[4], bC[4], aN[4], bN[4];
    {
        int io = ioffOf(0);
        #pragma unroll
        for (int i = 0; i < 4; ++i) aC[i] = *(const bf16x8*)(in + rowoff[i] + io);
        #pragma unroll
        for (int j = 0; j < 4; ++j) bC[j] = *(const bf16x8*)(bbase + ((size_t)j * 64) * 8);
    }
    for (int ks = 0; ks < NK; ks += 2) {
        {
            int io = ioffOf(ks + 1);
            #pragma unroll
            for (int i = 0; i < 4; ++i) aN[i] = *(const bf16x8*)(in + rowoff[i] + io);
            #pragma unroll
            for (int j = 0; j < 4; ++j) bN[j] = *(const bf16x8*)(bbase + ((size_t)((ks + 1) * 4 + j) * 64) * 8);
        }
        #pragma unroll
        for (int i = 0; i < 4; ++i)
            #pragma unroll
            for (int j = 0; j < 4; ++j)
                acc[i][j] = __builtin_amdgcn_mfma_f32_16x16x32_bf16(aC[i], bC[j], acc[i][j], 0, 0, 0);
        if (ks + 2 < NK) {
            int io = ioffOf(ks + 2);
            #pragma unroll
            for (int i = 0; i < 4; ++i) aC[i] = *(const bf16x8*)(in + rowoff[i] + io);
            #pragma unroll
            for (int j = 0; j < 4; ++j) bC[j] = *(const bf16x8*)(bbase + ((size_t)((ks + 2) * 4 + j) * 64) * 8);
        }
        #pragma unroll
        for (int i = 0; i < 4; ++i)
            #pragma unroll
            for (int j = 0; j < 4; ++j)
                acc[i][j] = __builtin_amdgcn_mfma_f32_16x16x32_bf16(aN[i], bN[j], acc[i][j], 0, 0, 0);
    }
    #pragma unroll
    for (int i = 0; i < 4; ++i) {
        #pragma unroll
        for (int r = 0; r < 4; ++r) {
            int m = mt * 64 + 16 * i + (lane >> 4) * 4 + r;
            int b = m / (HOUT * WOUT);
            int rm = m % (HOUT * WOUT);
            int y = rm / WOUT, x = rm % WOUT;
            #pragma unroll
            for (int j = 0; j < 4; ++j) {
                int n = nt * 64 + 16 * j + lr;
                float v = fmaxf(acc[i][j][r] * scale[n] + bias[n], 0.f);
                out[((size_t)(b * OH + y + 1) * OW + (x + 1)) * COUT + n] = f2bf(v);
            }
        }
    }
}

// ---------------- conv4: 4-wave LDS-staged-A, PHASE=4 k-steps per barrier pair ----------------
// grid (98, 3), block 256. Per phase: 4 reg loads -> ds_write x4 -> prefetch next phase
// -> barrier -> 4 k-steps of {4 B-loads + 4 ds_read + 16 MFMA} per wave -> barrier.
// 36 barriers/block (vs 144), staged loads fly across a full compute phase.
__global__ __launch_bounds__(256) void conv4_lds(
    const ushort_t* __restrict__ in, const ushort_t* __restrict__ wtP,
    const float* __restrict__ scale, const float* __restrict__ bias,
    ushort_t* __restrict__ memv) {
    const int CIN = 256, WH = 30;
    __shared__ ushort_t at[2][4 * 64 * 40];   // [buf][ks-in-phase][row][40]
    int tid = threadIdx.x;
    int lane = tid & 63, w = tid >> 6;
    int mt = blockIdx.x;
    int nt = blockIdx.y * 4 + w;
    int lr = lane & 15, kl = (lane >> 4) * 8;
    int srow = tid >> 2, sc = tid & 3;
    int m_s = mt * 64 + srow;
    int b_s = m_s / 196, rm_s = m_s % 196;
    int y_s = rm_s / 28, x_s = rm_s % 28;
    const ushort_t* arow = in + ((size_t)(b_s * 10 + y_s) * 30 + x_s) * CIN + sc * 8;
    int woff = srow * 40 + sc * 8;

    floatx4 acc[4][4];
    #pragma unroll
    for (int i = 0; i < 4; ++i)
        #pragma unroll
        for (int j = 0; j < 4; ++j) acc[i][j] = 0.f;

    auto ioffOf = [&](int ks) {
        int tap = ks >> 3;
        int k0 = (ks & 7) * 32;
        int ky = tap / 3, kx = tap - ky * 3;
        return (ky * WH + kx) * CIN + k0;
    };
    const ushort_t* bbase = wtP + ((size_t)nt * 72 * 4 * 64 + lane) * 8;

    bf16x8 st[4];
    #pragma unroll
    for (int j = 0; j < 4; ++j) st[j] = *(const bf16x8*)(arow + ioffOf(j));
    for (int p = 0; p < 18; ++p) {
        ushort_t* buf = &at[p & 1][0];
        #pragma unroll
        for (int j = 0; j < 4; ++j)
            *(bf16x8*)(buf + j * 2560 + woff) = st[j];
        if (p < 17) {
            #pragma unroll
            for (int j = 0; j < 4; ++j)
                st[j] = *(const bf16x8*)(arow + ioffOf((p + 1) * 4 + j));
        }
        __syncthreads();
        #pragma unroll
        for (int kk = 0; kk < 4; ++kk) {
            int ks = p * 4 + kk;
            bf16x8 a[4], bb[4];
            #pragma unroll
            for (int j = 0; j < 4; ++j)
                bb[j] = *(const bf16x8*)(bbase + ((size_t)(ks * 4 + j) * 64) * 8);
            #pragma unroll
            for (int i = 0; i < 4; ++i)
                a[i] = *(const bf16x8*)(buf + kk * 2560 + (16 * i + lr) * 40 + kl);
            #pragma unroll
            for (int i = 0; i < 4; ++i)
                #pragma unroll
                for (int j = 0; j < 4; ++j)
                    acc[i][j] = __builtin_amdgcn_mfma_f32_16x16x32_bf16(a[i], bb[j], acc[i][j], 0, 0, 0);
        }
        __syncthreads();
    }
    #pragma unroll
    for (int i = 0; i < 4; ++i) {
        #pragma unroll
        for (int r = 0; r < 4; ++r) {
            int m = mt * 64 + 16 * i + (lane >> 4) * 4 + r;
            #pragma unroll
            for (int j = 0; j < 4; ++j) {
                int n = nt * 64 + 16 * j + lr;
                float v = fmaxf(acc[i][j][r] * scale[n] + bias[n], 0.f);
                memv[(size_t)m * 768 + n] = f2bf(v);
            }
        }
    }
}

// ---------------- kmat: 4-wave LDS-staged-A; KT [b][96][196][8] ----------------
__global__ __launch_bounds__(256) void kmat_lds(
    const ushort_t* __restrict__ memv, const ushort_t* __restrict__ Bp,
    ushort_t* __restrict__ KT) {
    __shared__ ushort_t at[2][4 * 64 * 40];
    int tid = threadIdx.x;
    int lane = tid & 63, w = tid >> 6;
    int mt = blockIdx.x;
    int nt = blockIdx.y * 4 + w;
    int lr = lane & 15, kl = (lane >> 4) * 8;
    int srow = tid >> 2, sc = tid & 3;
    const ushort_t* arow = memv + (size_t)(mt * 64 + srow) * 768 + sc * 8;
    int woff = srow * 40 + sc * 8;
    const ushort_t* bbase = Bp + ((size_t)nt * 24 * 4 * 64 + lane) * 8;

    floatx4 acc[4][4];
    #pragma unroll
    for (int i = 0; i < 4; ++i)
        #pragma unroll
        for (int j = 0; j < 4; ++j) acc[i][j] = 0.f;

    bf16x8 st[4];
    #pragma unroll
    for (int j = 0; j < 4; ++j) st[j] = *(const bf16x8*)(arow + j * 32);
    for (int p = 0; p < 6; ++p) {
        ushort_t* buf = &at[p & 1][0];
        #pragma unroll
        for (int j = 0; j < 4; ++j)
            *(bf16x8*)(buf + j * 2560 + woff) = st[j];
        if (p < 5) {
            #pragma unroll
            for (int j = 0; j < 4; ++j)
                st[j] = *(const bf16x8*)(arow + ((p + 1) * 4 + j) * 32);
        }
        __syncthreads();
        #pragma unroll
        for (int kk = 0; kk < 4; ++kk) {
            int ks = p * 4 + kk;
            bf16x8 a[4], bb[4];
            #pragma unroll
            for (int j = 0; j < 4; ++j)
                bb[j] = *(const bf16x8*)(bbase + ((size_t)(ks * 4 + j) * 64) * 8);
            #pragma unroll
            for (int i = 0; i < 4; ++i)
                a[i] = *(const bf16x8*)(buf + kk * 2560 + (16 * i + lr) * 40 + kl);
            #pragma unroll
            for (int i = 0; i < 4; ++i)
                #pragma unroll
                for (int j = 0; j < 4; ++j)
                    acc[i][j] = __builtin_amdgcn_mfma_f32_16x16x32_bf16(a[i], bb[j], acc[i][j], 0, 0, 0);
        }
        __syncthreads();
    }
    #pragma unroll
    for (int i = 0; i < 4; ++i) {
        #pragma unroll
        for (int r = 0; r < 4; ++r) {
            int mg = mt * 64 + 16 * i + (lane >> 4) * 4 + r;
            int b = mg / 196, m = mg % 196;
            #pragma unroll
            for (int j = 0; j < 4; ++j) {
                int n = nt * 64 + 16 * j + lr;
                KT[(((size_t)b * 96 + (n >> 3)) * 196 + m) * 8 + (n & 7)] = f2bf(acc[i][j][r]);
            }
        }
    }
}

// ---------------- occupancy-first GEMM: C[512][N] = Ap . Bb^T + bias; swizzled 1D grid ----------------
template <int REMAP>
__global__ __launch_bounds__(256, 4) void gemm_ldsb(
    const ushort_t* __restrict__ Ap, const ushort_t* __restrict__ Bb,
    const float* __restrict__ bias1, const float* __restrict__ bias2,
    float* __restrict__ C, int N) {
    __shared__ ushort_t bt[2][64 * 72];
    int tid = threadIdx.x;
    int lane = tid & 63, w = tid >> 6;
    int nblk = (N >> 6) * 2;
    int id = swz8(blockIdx.x, nblk);
    int nt = id >> 1, mh = id & 1;
    int n0 = nt * 64;
    int mt = mh * 4 + w;
    int lr = lane & 15, hi = lane >> 4;
    int srow = tid >> 2, sc = tid & 3;
    const ushort_t* gsrc = Bb + (size_t)(n0 + srow) * 768 + sc * 8;
    int woff = srow * 72 + sc * 8;
    floatx4 acc[4][4];
    #pragma unroll
    for (int i = 0; i < 4; ++i)
        #pragma unroll
        for (int j = 0; j < 4; ++j) acc[i][j] = 0.f;
    bf16x8 s0 = *(const bf16x8*)(gsrc);
    bf16x8 s1 = *(const bf16x8*)(gsrc + 32);
    for (int kc = 0; kc < 12; ++kc) {
        ushort_t* bufw = &bt[kc & 1][0];
        *(bf16x8*)(bufw + woff) = s0;
        *(bf16x8*)(bufw + woff + 32) = s1;
        if (kc < 11) {
            const ushort_t* p = gsrc + (size_t)(kc + 1) * 64;
            s0 = *(const bf16x8*)(p);
            s1 = *(const bf16x8*)(p + 32);
        }
        __syncthreads();
        const ushort_t* bufr = &bt[kc & 1][0];
        #pragma unroll
        for (int kk = 0; kk < 2; ++kk) {
            int kq = kc * 2 + kk;
            bf16x8 bfr[4], a[4];
            #pragma unroll
            for (int j = 0; j < 4; ++j)
                bfr[j] = *(const bf16x8*)(bufr + (j * 16 + lr) * 72 + kk * 32 + hi * 8);
            #pragma unroll
            for (int i = 0; i < 4; ++i)
                a[i] = *(const bf16x8*)(Ap + ((((size_t)mt * 24 + kq) * 4 + i) * 64 + lane) * 8);
            #pragma unroll
            for (int i = 0; i < 4; ++i)
                #pragma unroll
                for (int j = 0; j < 4; ++j)
                    acc[i][j] = __builtin_amdgcn_mfma_f32_16x16x32_bf16(a[i], bfr[j], acc[i][j], 0, 0, 0);
        }
    }
    #pragma unroll
    for (int i = 0; i < 4; ++i) {
        #pragma unroll
        for (int rr = 0; rr < 4; ++rr) {
            int m = mt * 64 + 16 * i + hi * 4 + rr;   // m = t*32+b
            #pragma unroll
            for (int j = 0; j < 4; ++j) {
                int n = n0 + 16 * j + lr;
                float vv = acc[i][j][rr];
                if (bias1) vv += bias1[n];
                if (bias2) vv += bias2[n];
                if (REMAP) {
                    int t = m >> 5, b = m & 31;
                    C[(size_t)((b << 4) + t) * NV + n] = vv;
                } else {
                    C[(size_t)m * N + n] = vv;
                }
            }
        }
    }
}

// ---------------- attention step (scores = h . K~[b]) ----------------
__global__ __launch_bounds__(768) void attn2(
    ushort_t* __restrict__ xin, const ushort_t* __restrict__ KT,
    const ushort_t* __restrict__ mem) {
    __shared__ float hq[NH];
    __shared__ float sl[196];
    __shared__ float red[16];
    int b = blockIdx.x, tid = threadIdx.x;
    hq[tid] = bf2f(xin[(size_t)b * 1536 + NH + tid]);
    __syncthreads();
    if (tid < 392) {
        int m = tid >> 1, half = tid & 1;
        const ushort_t* basep = KT + (((size_t)b * 96 + half * 48) * 196 + m) * 8;
        float acc = 0.f;
        #pragma unroll 4
        for (int k8 = 0; k8 < 48; ++k8) {
            bf16x8 v = *(const bf16x8*)(basep + (size_t)k8 * 196 * 8);
            const float* qp = hq + (half * 48 + k8) * 8;
            #pragma unroll
            for (int j = 0; j < 8; ++j)
                acc = fmaf(bf2f((unsigned short)v[j]), qp[j], acc);
        }
        acc += __shfl_xor(acc, 1);
        if (!half) sl[m] = acc;
    }
    __syncthreads();
    float sc = (tid < 196) ? sl[tid] : -INFINITY;
    float v = sc;
    #pragma unroll
    for (int off = 32; off; off >>= 1) v = fmaxf(v, __shfl_down(v, off));
    if ((tid & 63) == 0) red[tid >> 6] = v;
    __syncthreads();
    if (tid == 0) {
        float m = red[0];
        for (int i = 1; i < 12; ++i) m = fmaxf(m, red[i]);
        red[12] = m;
    }
    __syncthreads();
    float mx = red[12];
    float e = (tid < 196) ? expf(sc - mx) : 0.f;
    __syncthreads();
    v = e;
    #pragma unroll
    for (int off = 32; off; off >>= 1) v += __shfl_down(v, off);
    if ((tid & 63) == 0) red[tid >> 6] = v;
    __syncthreads();
    if (tid == 0) {
        float s = red[0];
        for (int i = 1; i < 12; ++i) s += red[i];
        red[12] = 1.f / s;
    }
    __syncthreads();
    if (tid < 196) sl[tid] = e * red[12];
    __syncthreads();
    {
        float acc = 0.f;
        const ushort_t* mb = mem + (size_t)b * 196 * NH + tid;
        #pragma unroll 4
        for (int m = 0; m < 196; ++m) acc = fmaf(sl[m], bf2f(mb[(size_t)m * NH]), acc);
        xin[(size_t)b * 1536 + tid] = f2bf(acc);
    }
}

// ---------------- fused gates GEMM + LSTM cell; writes Hall PACKED ----------------
__global__ __launch_bounds__(256) void step_fused(
    const ushort_t* __restrict__ xin_r, const ushort_t* __restrict__ wcombP,
    const float* __restrict__ eg_t,
    float* __restrict__ cbuf, float* __restrict__ hbuf,
    ushort_t* __restrict__ xin_w, ushort_t* __restrict__ hallP, int tstep) {
    __shared__ float pbuf[4][64][33];
    int lane = threadIdx.x & 63, w = threadIdx.x >> 6;
    int bx = blockIdx.x;
    int lr = lane & 15, kl = (lane >> 4) * 8;
    floatx4 acc[2][4];
    #pragma unroll
    for (int i = 0; i < 2; ++i)
        #pragma unroll
        for (int g = 0; g < 4; ++g) acc[i][g] = 0.f;
    for (int kq = 0; kq < 12; ++kq) {
        int k = w * 384 + kq * 32;
        bf16x8 a[2], bb[4];
        #pragma unroll
        for (int i = 0; i < 2; ++i)
            a[i] = *(const bf16x8*)(xin_r + (size_t)(16 * i + lr) * 1536 + k + kl);
        #pragma unroll
        for (int g = 0; g < 4; ++g)
            bb[g] = *(const bf16x8*)(wcombP + (((size_t)(bx * 4 + g) * 48 + (w * 12 + kq)) * 64 + lane) * 8);
        #pragma unroll
        for (int i = 0; i < 2; ++i)
            #pragma unroll
            for (int g = 0; g < 4; ++g)
                acc[i][g] = __builtin_amdgcn_mfma_f32_16x16x32_bf16(a[i], bb[g], acc[i][g], 0, 0, 0);
    }
    #pragma unroll
    for (int i = 0; i < 2; ++i)
        #pragma unroll
        for (int g = 0; g < 4; ++g)
            #pragma unroll
            for (int r = 0; r < 4; ++r) {
                int m = 16 * i + (lane >> 4) * 4 + r;
                pbuf[w][g * 16 + lr][m] = acc[i][g][r];
            }
    __syncthreads();
    int tid = threadIdx.x;
    #pragma unroll
    for (int o = 0; o < 2; ++o) {
        int pid = tid * 2 + o;          // 0..511
        int m = pid & 31, c = pid >> 5; // m = batch, c = 0..15
        int kcol = bx * 16 + c;
        float gi = 0.f, gf = 0.f, gg = 0.f, go = 0.f;
        #pragma unroll
        for (int ww = 0; ww < 4; ++ww) {
            gi += pbuf[ww][c][m];
            gf += pbuf[ww][16 + c][m];
            gg += pbuf[ww][32 + c][m];
            go += pbuf[ww][48 + c][m];
        }
        const float* eg = eg_t + (size_t)m * 3072;
        gi += eg[kcol];
        gf += eg[768 + kcol];
        gg += eg[1536 + kcol];
        go += eg[2304 + kcol];
        float cst = cbuf[m * 768 + kcol];
        float cn = sigmoidf_(gf) * cst + sigmoidf_(gi) * tanhf(gg);
        float hn = sigmoidf_(go) * tanhf(cn);
        cbuf[m * 768 + kcol] = cn;
        hbuf[m * 768 + kcol] = hn;
        ushort_t hb = f2bf(hn);
        xin_w[(size_t)m * 1536 + NH + kcol] = hb;
        int rrow = tstep * 32 + m;
        int mtp = rrow >> 6, ip = (rrow >> 4) & 3, lrp = rrow & 15;
        int kqp = kcol >> 5, hip = (kcol >> 3) & 3, ep = kcol & 7;
        hallP[((((size_t)mtp * 24 + kqp) * 4 + ip) * 64 + (lrp | (hip << 4))) * 8 + ep] = hb;
    }
}

__global__ __launch_bounds__(256) void copy_hc(const float* __restrict__ h, const float* __restrict__ c,
                                               float* __restrict__ out) {
    int i = blockIdx.x * 256 + threadIdx.x;
    if (i < NB * NH) {
        out[(size_t)NB * NT * NV + i] = h[i];
        out[(size_t)NB * NT * NV + NB * NH + i] = c[i];
    }
}

extern "C" void kernel_launch(void* const* d_in, const int* in_sizes, int n_in,
                              void* d_out, int out_size, void* d_ws, size_t ws_size,
                              hipStream_t stream) {
    const float* images   = (const float*)d_in[0];
    const int*   captions = (const int*)d_in[1];
    const float* conv1_w  = (const float*)d_in[2];
    const float* bn1_g = (const float*)d_in[3], *bn1_b = (const float*)d_in[4];
    const float* bn1_m = (const float*)d_in[5], *bn1_v = (const float*)d_in[6];
    const float* conv2_w  = (const float*)d_in[7];
    const float* bn2_g = (const float*)d_in[8], *bn2_b = (const float*)d_in[9];
    const float* bn2_m = (const float*)d_in[10], *bn2_v = (const float*)d_in[11];
    const float* conv3_w  = (const float*)d_in[12];
    const float* bn3_g = (const float*)d_in[13], *bn3_b = (const float*)d_in[14];
    const float* bn3_m = (const float*)d_in[15], *bn3_v = (const float*)d_in[16];
    const float* conv4_w  = (const float*)d_in[17];
    const float* bn4_g = (const float*)d_in[18], *bn4_b = (const float*)d_in[19];
    const float* bn4_m = (const float*)d_in[20], *bn4_v = (const float*)d_in[21];
    const float* emb_table = (const float*)d_in[22];
    const float* attn_w   = (const float*)d_in[23];
    const float* w_ih     = (const float*)d_in[24];
    const float* w_hh     = (const float*)d_in[25];
    const float* b_ih     = (const float*)d_in[26];
    const float* b_hh     = (const float*)d_in[27];
    const float* fc_w     = (const float*)d_in[28];
    const float* fc_b     = (const float*)d_in[29];
    float* out = (float*)d_out;

    // ---- workspace layout ----
    char* base = (char*)d_ws;
    size_t off = 0;
    auto alloc = [&](size_t bytes) { char* p = base + off; off += (bytes + 255) & ~(size_t)255; return p; };
    float* s1 = (float*)alloc(64 * 4);   float* bb1 = (float*)alloc(64 * 4);
    float* s2 = (float*)alloc(128 * 4);  float* bb2 = (float*)alloc(128 * 4);
    float* s3 = (float*)alloc(256 * 4);  float* bb3 = (float*)alloc(256 * 4);
    float* s4 = (float*)alloc(768 * 4);  float* bb4 = (float*)alloc(768 * 4);
    ushort_t* c1out = (ushort_t*)alloc((size_t)32 * 34 * 112 * 64 * 2);
    size_t halo_start = off;
    ushort_t* hal2 = (ushort_t*)alloc((size_t)32 * 19 * 58 * 64 * 2);
    ushort_t* hal3 = (ushort_t*)alloc((size_t)32 * 18 * 58 * 128 * 2);
    ushort_t* hal4 = (ushort_t*)alloc((size_t)32 * 10 * 30 * 256 * 2);
    size_t halo_bytes = off - halo_start;
    ushort_t* memv = (ushort_t*)alloc((size_t)32 * 196 * 768 * 2);
    ushort_t* KT   = (ushort_t*)alloc((size_t)32 * 96 * 196 * 8 * 2);
    ushort_t* wb1 = (ushort_t*)alloc((size_t)64 * 160 * 2);
    ushort_t* wb2 = (ushort_t*)alloc((size_t)128 * 9 * 64 * 2);
    ushort_t* wb3 = (ushort_t*)alloc((size_t)256 * 9 * 128 * 2);
    ushort_t* wb4 = (ushort_t*)alloc((size_t)768 * 9 * 256 * 2);
    ushort_t* wattnTP = (ushort_t*)alloc((size_t)768 * 768 * 2);
    ushort_t* wcombP = (ushort_t*)alloc((size_t)3072 * 1536 * 2);
    ushort_t* wihL = (ushort_t*)alloc((size_t)3072 * 768 * 2);
    ushort_t* e512P = (ushort_t*)alloc((size_t)512 * 768 * 2);
    float* eg   = (float*)alloc((size_t)512 * 3072 * 4);
    ushort_t* HallP = (ushort_t*)alloc((size_t)512 * 768 * 2);
    float* hbuf = (float*)alloc(NB * NH * 4);
    float* cbuf = (float*)alloc(NB * NH * 4);
    ushort_t* xinA = (ushort_t*)alloc((size_t)NB * 1536 * 2);
    ushort_t* xinB = (ushort_t*)alloc((size_t)NB * 1536 * 2);
    // union: im2col (39 MB, dead after conv1_gemm) then fc_w bf16 (49.2 MB)
    char* ubig = alloc((size_t)NV * NH * 2);
    ushort_t* imcol = (ushort_t*)ubig;
    ushort_t* fcwb  = (ushort_t*)ubig;

    // ---- merged one-time transforms (1 launch) ----
    long long n8 = (long long)(halo_bytes / 8);
    long long prep_total = (long long)SEG9 + n8;
    prep_all<<<(unsigned)((prep_total + 255) / 256), 256, 0, stream>>>(
        bn1_g, bn1_b, bn1_m, bn1_v, bn2_g, bn2_b, bn2_m, bn2_v,
        bn3_g, bn3_b, bn3_m, bn3_v, bn4_g, bn4_b, bn4_m, bn4_v,
        s1, bb1, s2, bb2, s3, bb3, s4, bb4,
        conv1_w, wb1, conv2_w, wb2, conv3_w, wb3, conv4_w, wb4,
        attn_w, wattnTP, w_ih, w_hh, wcombP, wihL,
        captions, emb_table, e512P,
        hbuf, cbuf, xinA,
        (unsigned long long*)hal2, n8);

    // ---- decoder precompute GEMM (independent of encoder) ----
    gemm_ldsb<0><<<96, 256, 0, stream>>>(e512P, wihL, b_ih, b_hh, eg, 3072);

    // ---- encoder ----
    im2col1<<<(121856 * 160 + 255) / 256, 256, 0, stream>>>(images, imcol);
    conv1_gemm<<<476, 256, 0, stream>>>(imcol, wb1, s1, bb1, c1out);
    // imcol dead -> convert fc_w (f32->bf16 row-major) into same buffer
    cvt_b16rows<<<(NV * 96 + 255) / 256, 256, 0, stream>>>(fc_w, fcwb, 96, 768, NV * 96);
    pool_kernel<<<(32 * 17 * 56 * 8 + 255) / 256, 256, 0, stream>>>(c1out, hal2);
    conv_mfma<64, 19, 58, 1, 16, 56, 128, 18, 58>
        <<<896, 64, 0, stream>>>(hal2, wb2, s2, bb2, hal3);
    conv_mfma<128, 18, 58, 2, 8, 28, 256, 10, 30>
        <<<448, 64, 0, stream>>>(hal3, wb3, s3, bb3, hal4);
    conv4_lds<<<dim3(98, 3), 256, 0, stream>>>(hal4, wb4, s4, bb4, memv);

    // ---- attention K~ precompute: KT = mem @ attn_w ----
    kmat_lds<<<dim3(98, 3), 256, 0, stream>>>(memv, wattnTP, KT);

    // ---- sequential decoder (xin double-buffered) ----
    ushort_t* xcur = xinA;
    ushort_t* xnxt = xinB;
    for (int t = 0; t < NT; ++t) {
        attn2<<<NB, NH, 0, stream>>>(xcur, KT, memv);
        step_fused<<<48, 256, 0, stream>>>(
            xcur, wcombP, eg + (size_t)t * NB * 3072, cbuf, hbuf, xnxt, HallP, t);
        ushort_t* tmp = xcur; xcur = xnxt; xnxt = tmp;
    }

    // ---- vocab projection for all 16 steps at once ----
    gemm_ldsb<1><<<1000, 256, 0, stream>>>(HallP, fcwb, fc_b, nullptr, out, NV);

    copy_hc<<<(NB * NH + 255) / 256, 256, 0, stream>>>(hbuf, cbuf, out);
}

// Round 19
// 851.648 us; speedup vs baseline: 1.0622x; 1.0073x over previous
//
#include <hip/hip_runtime.h>
#include <math.h>

#define NB 32
#define NT 16
#define NH 768
#define NV 32000

typedef short bf16x8 __attribute__((ext_vector_type(8)));
typedef float floatx4 __attribute__((ext_vector_type(4)));
typedef unsigned short ushort_t;

__device__ __forceinline__ float bf2f(unsigned short h) {
    unsigned u = ((unsigned)h) << 16;
    return __builtin_bit_cast(float, u);
}
__device__ __forceinline__ unsigned short f2bf(float f) {
    unsigned u = __builtin_bit_cast(unsigned, f);
    u += 0x7fffu + ((u >> 16) & 1u);
    return (unsigned short)(u >> 16);
}
__device__ __forceinline__ float sigmoidf_(float x) { return 1.f / (1.f + expf(-x)); }

// XCD-chunk swizzle: grid size N % 8 == 0.
__device__ __forceinline__ int swz8(int bid, int N) {
    return (bid & 7) * (N >> 3) + (bid >> 3);
}

__device__ __forceinline__ bf16x8 cvt8(float4 a, float4 b) {
    bf16x8 t;
    t[0] = (short)f2bf(a.x); t[1] = (short)f2bf(a.y);
    t[2] = (short)f2bf(a.z); t[3] = (short)f2bf(a.w);
    t[4] = (short)f2bf(b.x); t[5] = (short)f2bf(b.y);
    t[6] = (short)f2bf(b.z); t[7] = (short)f2bf(b.w);
    return t;
}

// ---------------- ONE merged prep kernel ----------------
#define SEG0 1216
#define SEG1 (SEG0 + 10240)
#define SEG2 (SEG1 + 73728)
#define SEG3 (SEG2 + 294912)
#define SEG4 (SEG3 + 1769472)
#define SEG5 (SEG4 + 589824)
#define SEG6 (SEG5 + 4718592)
#define SEG7 (SEG6 + 294912)
#define SEG8 (SEG7 + 393216)
#define SEG9 (SEG8 + 49152)
__global__ __launch_bounds__(256) void prep_all(
    const float* __restrict__ g1, const float* __restrict__ b1, const float* __restrict__ m1, const float* __restrict__ v1,
    const float* __restrict__ g2, const float* __restrict__ b2, const float* __restrict__ m2, const float* __restrict__ v2,
    const float* __restrict__ g3, const float* __restrict__ b3, const float* __restrict__ m3, const float* __restrict__ v3,
    const float* __restrict__ g4, const float* __restrict__ b4, const float* __restrict__ m4, const float* __restrict__ v4,
    float* __restrict__ s1, float* __restrict__ o1, float* __restrict__ s2, float* __restrict__ o2,
    float* __restrict__ s3, float* __restrict__ o3, float* __restrict__ s4, float* __restrict__ o4,
    const float* __restrict__ conv1_w, ushort_t* __restrict__ wb1,
    const float* __restrict__ conv2_w, ushort_t* __restrict__ wb2,
    const float* __restrict__ conv3_w, ushort_t* __restrict__ wb3,
    const float* __restrict__ conv4_w, ushort_t* __restrict__ wb4,
    const float* __restrict__ attn_w, ushort_t* __restrict__ wattnTP,
    const float* __restrict__ w_ih, const float* __restrict__ w_hh, ushort_t* __restrict__ wcombP,
    ushort_t* __restrict__ wihL,
    const int* __restrict__ caps, const float* __restrict__ table, ushort_t* __restrict__ e512P,
    float* __restrict__ hbuf, float* __restrict__ cbuf, ushort_t* __restrict__ xinA,
    unsigned long long* __restrict__ halo, long long n8) {
    long long gi = (long long)blockIdx.x * 256 + threadIdx.x;
    if (gi < SEG0) {
        int i = (int)gi;
        const float *g, *b, *m, *v;
        float *s, *o;
        int c;
        if (i < 64)        { g = g1; b = b1; m = m1; v = v1; s = s1; o = o1; c = i; }
        else if (i < 192)  { g = g2; b = b2; m = m2; v = v2; s = s2; o = o2; c = i - 64; }
        else if (i < 448)  { g = g3; b = b3; m = m3; v = v3; s = s3; o = o3; c = i - 192; }
        else               { g = g4; b = b4; m = m4; v = v4; s = s4; o = o4; c = i - 448; }
        float inv = g[c] * rsqrtf(v[c] + 1e-5f);
        s[c] = inv;
        o[c] = b[c] - m[c] * inv;
    } else if (gi < SEG1) {
        int idx = (int)(gi - SEG0);
        int co = idx / 160, k = idx % 160;
        wb1[idx] = (k < 147) ? f2bf(conv1_w[co * 147 + k]) : (ushort_t)0;
    } else if (gi < SEG4) {
        const float* w;
        ushort_t* dst;
        int CIN, idx;
        if (gi < SEG2)      { w = conv2_w; dst = wb2; CIN = 64;  idx = (int)(gi - SEG1); }
        else if (gi < SEG3) { w = conv3_w; dst = wb3; CIN = 128; idx = (int)(gi - SEG2); }
        else                { w = conv4_w; dst = wb4; CIN = 256; idx = (int)(gi - SEG3); }
        int e = idx & 7, lane = (idx >> 3) & 63, j = (idx >> 9) & 3;
        int r = idx >> 11;
        int KQ = CIN >> 5;
        int kq = r % KQ; r /= KQ;
        int tap = r % 9; int nt = r / 9;
        int co = nt * 64 + j * 16 + (lane & 15);
        int ci = kq * 32 + (lane >> 4) * 8 + e;
        dst[idx] = f2bf(w[((size_t)co * CIN + ci) * 9 + tap]);
    } else if (gi < SEG5) {
        int idx = (int)(gi - SEG4);
        int e = idx & 7, lane = (idx >> 3) & 63, j = (idx >> 9) & 3;
        int t = idx >> 11;
        int kq = t % 24, nt = t / 24;
        int n = nt * 64 + 16 * j + (lane & 15);
        int k = kq * 32 + (lane >> 4) * 8 + e;
        wattnTP[idx] = f2bf(attn_w[(size_t)k * 768 + n]);
    } else if (gi < SEG6) {
        int idx = (int)(gi - SEG5);
        int e = idx & 7, lane = (idx >> 3) & 63;
        int t = idx >> 9;
        int kq = t % 48, gg = t / 48;
        int g = gg & 3, bx = gg >> 2;
        int j = g * 768 + bx * 16 + (lane & 15);
        int k = kq * 32 + (lane >> 4) * 8 + e;
        float v = (k < NH) ? w_ih[(size_t)j * (2 * NH) + NH + k] : w_hh[(size_t)j * NH + (k - NH)];
        wcombP[idx] = f2bf(v);
    } else if (gi < SEG7) {
        int idx = (int)(gi - SEG6);
        int r = idx / 96, g = idx % 96;
        const float4* s = (const float4*)(w_ih + (size_t)r * 1536 + g * 8);
        *(bf16x8*)(wihL + (size_t)idx * 8) = cvt8(s[0], s[1]);
    } else if (gi < SEG8) {
        int idx = (int)(gi - SEG7);
        int e = idx & 7, lane = (idx >> 3) & 63, i = (idx >> 9) & 3;
        int t2 = idx >> 11;
        int kq = t2 % 24, mt = t2 / 24;
        int r = mt * 64 + i * 16 + (lane & 15);
        int k = kq * 32 + (lane >> 4) * 8 + e;
        int t = r >> 5, b = r & 31;
        e512P[idx] = f2bf(table[(size_t)caps[b * NT + t] * NH + k]);
    } else if (gi < SEG9) {
        int i = (int)(gi - SEG8);
        xinA[i] = 0;
        if (i < NB * NH) { hbuf[i] = 0.f; cbuf[i] = 0.f; }
    } else {
        long long j = gi - SEG9;
        if (j < n8) halo[j] = 0ULL;
    }
}

// ---------------- conv1 im2col ----------------
__global__ __launch_bounds__(256) void im2col1(const float* __restrict__ img, ushort_t* __restrict__ A) {
    int idx = blockIdx.x * 256 + threadIdx.x;
    const int total = 121856 * 160;
    if (idx >= total) return;
    int k = idx % 160;
    int m = idx / 160;
    ushort_t v = 0;
    if (k < 147) {
        int b = m / 3808;
        int rm = m % 3808;
        int y = rm / 112, x = rm % 112;
        int ci = k / 49;
        int r = k % 49;
        int ky = r / 7, kx = r % 7;
        int iy = 2 * y - 3 + ky;
        int ix = 2 * x - 3 + kx;
        if ((unsigned)iy < 224u && (unsigned)ix < 224u)
            v = f2bf(img[((size_t)(b * 3 + ci) * 224 + iy) * 224 + ix]);
    }
    A[idx] = v;
}

// rows of f32 -> bf16 (fc weights)
__global__ __launch_bounds__(256) void cvt_b16rows(const float* __restrict__ src, ushort_t* __restrict__ dst,
                                                   int cols8, int ldsrc, int total8) {
    int i = blockIdx.x * 256 + threadIdx.x;
    if (i >= total8) return;
    int r = i / cols8, g = i % cols8;
    const float4* s = (const float4*)(src + (size_t)r * ldsrc + g * 8);
    *(bf16x8*)(dst + (size_t)i * 8) = cvt8(s[0], s[1]);
}

// ---------------- conv1 GEMM ----------------
__global__ __launch_bounds__(256) void conv1_gemm(
    const ushort_t* __restrict__ A, const ushort_t* __restrict__ Bw,
    const float* __restrict__ scale, const float* __restrict__ bias,
    ushort_t* __restrict__ out) {
    int lane = threadIdx.x & 63, w = threadIdx.x >> 6;
    int m0 = (blockIdx.x * 4 + w) * 64;
    int lr = lane & 15, kl = (lane >> 4) * 8;
    floatx4 acc[4][4];
    #pragma unroll
    for (int i = 0; i < 4; ++i)
        #pragma unroll
        for (int j = 0; j < 4; ++j) acc[i][j] = 0.f;
    #pragma unroll
    for (int k0 = 0; k0 < 160; k0 += 32) {
        bf16x8 a[4], bb[4];
        #pragma unroll
        for (int i = 0; i < 4; ++i) a[i] = *(const bf16x8*)(A + (size_t)(m0 + 16 * i + lr) * 160 + kl + k0);
        #pragma unroll
        for (int j = 0; j < 4; ++j) bb[j] = *(const bf16x8*)(Bw + (size_t)(16 * j + lr) * 160 + kl + k0);
        #pragma unroll
        for (int i = 0; i < 4; ++i)
            #pragma unroll
            for (int j = 0; j < 4; ++j)
                acc[i][j] = __builtin_amdgcn_mfma_f32_16x16x32_bf16(a[i], bb[j], acc[i][j], 0, 0, 0);
    }
    #pragma unroll
    for (int i = 0; i < 4; ++i) {
        #pragma unroll
        for (int r = 0; r < 4; ++r) {
            int m = m0 + 16 * i + (lane >> 4) * 4 + r;
            int b = m / 3808;
            int rm = m % 3808;
            int y = rm / 112, x = rm % 112;
            #pragma unroll
            for (int j = 0; j < 4; ++j) {
                int n = 16 * j + lr;
                float v = fmaxf(acc[i][j][r] * scale[n] + bias[n], 0.f);
                out[((size_t)(b * 34 + y) * 112 + x) * 64 + n] = f2bf(v);
            }
        }
    }
}

// ---------------- maxpool 3x3 s2 p1 ----------------
__global__ __launch_bounds__(256) void pool_kernel(const ushort_t* __restrict__ in,
                                                   ushort_t* __restrict__ hal2) {
    int idx = blockIdx.x * 256 + threadIdx.x;
    const int total = 32 * 17 * 56 * 8;
    if (idx >= total) return;
    int c8 = idx & 7;
    int rest = idx >> 3;
    int x = rest % 56; rest /= 56;
    int y = rest % 17; int b = rest / 17;
    float mx[8];
    #pragma unroll
    for (int j = 0; j < 8; ++j) mx[j] = -INFINITY;
    for (int dy = -1; dy <= 1; ++dy) {
        int iy = 2 * y + dy;
        if ((unsigned)iy >= 34u) continue;
        for (int dx = -1; dx <= 1; ++dx) {
            int ix = 2 * x + dx;
            if ((unsigned)ix >= 112u) continue;
            bf16x8 v = *(const bf16x8*)(in + (((size_t)(b * 34 + iy)) * 112 + ix) * 64 + c8 * 8);
            #pragma unroll
            for (int j = 0; j < 8; ++j) mx[j] = fmaxf(mx[j], bf2f((unsigned short)v[j]));
        }
    }
    bf16x8 o;
    #pragma unroll
    for (int j = 0; j < 8; ++j) o[j] = (short)f2bf(mx[j]);
    *(bf16x8*)(hal2 + (((size_t)(b * 19 + y + 1)) * 58 + (x + 1)) * 64 + c8 * 8) = o;
}

// ---------------- implicit-GEMM 3x3 conv via MFMA (conv2/conv3), prefetch + swizzle ----------------
template <int CIN, int HH, int WH, int STRIDE, int HOUT, int WOUT, int COUT, int OH, int OW>
__global__ __launch_bounds__(64) void conv_mfma(
    const ushort_t* __restrict__ in, const ushort_t* __restrict__ wtP,
    const float* __restrict__ scale, const float* __restrict__ bias,
    ushort_t* __restrict__ out) {
    const int KQ = CIN / 32;
    const int NK = 9 * KQ;
    const int MT = (32 * HOUT * WOUT) / 64;
    const int NTL = COUT / 64;
    int id = swz8(blockIdx.x, MT * NTL);
    int mt = id % MT, nt = id / MT;
    int lane = threadIdx.x;
    int lr = lane & 15, kl = (lane >> 4) * 8;
    int rowoff[4];
    #pragma unroll
    for (int i = 0; i < 4; ++i) {
        int m = mt * 64 + 16 * i + lr;
        int b = m / (HOUT * WOUT);
        int rm = m % (HOUT * WOUT);
        int y = rm / WOUT, x = rm % WOUT;
        rowoff[i] = ((b * HH + y * STRIDE) * WH + x * STRIDE) * CIN + kl;
    }
    floatx4 acc[4][4];
    #pragma unroll
    for (int i = 0; i < 4; ++i)
        #pragma unroll
        for (int j = 0; j < 4; ++j) acc[i][j] = 0.f;

    auto ioffOf = [&](int ks) {
        int tap = ks / KQ;
        int k0 = (ks & (KQ - 1)) * 32;
        int ky = tap / 3, kx = tap - ky * 3;
        return (ky * WH + kx) * CIN + k0;
    };
    const ushort_t* bbase = wtP + ((size_t)nt * 9 * KQ * 4 * 64 + lane) * 8;

    bf16x8 aC[4], bC[4], aN[4], bN[4];
    {
        int io = ioffOf(0);
        #pragma unroll
        for (int i = 0; i < 4; ++i) aC[i] = *(const bf16x8*)(in + rowoff[i] + io);
        #pragma unroll
        for (int j = 0; j < 4; ++j) bC[j] = *(const bf16x8*)(bbase + ((size_t)j * 64) * 8);
    }
    for (int ks = 0; ks < NK; ks += 2) {
        {
            int io = ioffOf(ks + 1);
            #pragma unroll
            for (int i = 0; i < 4; ++i) aN[i] = *(const bf16x8*)(in + rowoff[i] + io);
            #pragma unroll
            for (int j = 0; j < 4; ++j) bN[j] = *(const bf16x8*)(bbase + ((size_t)((ks + 1) * 4 + j) * 64) * 8);
        }
        #pragma unroll
        for (int i = 0; i < 4; ++i)
            #pragma unroll
            for (int j = 0; j < 4; ++j)
                acc[i][j] = __builtin_amdgcn_mfma_f32_16x16x32_bf16(aC[i], bC[j], acc[i][j], 0, 0, 0);
        if (ks + 2 < NK) {
            int io = ioffOf(ks + 2);
            #pragma unroll
            for (int i = 0; i < 4; ++i) aC[i] = *(const bf16x8*)(in + rowoff[i] + io);
            #pragma unroll
            for (int j = 0; j < 4; ++j) bC[j] = *(const bf16x8*)(bbase + ((size_t)((ks + 2) * 4 + j) * 64) * 8);
        }
        #pragma unroll
        for (int i = 0; i < 4; ++i)
            #pragma unroll
            for (int j = 0; j < 4; ++j)
                acc[i][j] = __builtin_amdgcn_mfma_f32_16x16x32_bf16(aN[i], bN[j], acc[i][j], 0, 0, 0);
    }
    #pragma unroll
    for (int i = 0; i < 4; ++i) {
        #pragma unroll
        for (int r = 0; r < 4; ++r) {
            int m = mt * 64 + 16 * i + (lane >> 4) * 4 + r;
            int b = m / (HOUT * WOUT);
            int rm = m % (HOUT * WOUT);
            int y = rm / WOUT, x = rm % WOUT;
            #pragma unroll
            for (int j = 0; j < 4; ++j) {
                int n = nt * 64 + 16 * j + lr;
                float v = fmaxf(acc[i][j][r] * scale[n] + bias[n], 0.f);
                out[((size_t)(b * OH + y + 1) * OW + (x + 1)) * COUT + n] = f2bf(v);
            }
        }
    }
}

// ---------------- conv4: 4-wave LDS-staged-A, PHASE=4 k-steps per barrier pair ----------------
__global__ __launch_bounds__(256) void conv4_lds(
    const ushort_t* __restrict__ in, const ushort_t* __restrict__ wtP,
    const float* __restrict__ scale, const float* __restrict__ bias,
    ushort_t* __restrict__ memv) {
    const int CIN = 256, WH = 30;
    __shared__ ushort_t at[2][4 * 64 * 40];
    int tid = threadIdx.x;
    int lane = tid & 63, w = tid >> 6;
    int mt = blockIdx.x;
    int nt = blockIdx.y * 4 + w;
    int lr = lane & 15, kl = (lane >> 4) * 8;
    int srow = tid >> 2, sc = tid & 3;
    int m_s = mt * 64 + srow;
    int b_s = m_s / 196, rm_s = m_s % 196;
    int y_s = rm_s / 28, x_s = rm_s % 28;
    const ushort_t* arow = in + ((size_t)(b_s * 10 + y_s) * 30 + x_s) * CIN + sc * 8;
    int woff = srow * 40 + sc * 8;

    floatx4 acc[4][4];
    #pragma unroll
    for (int i = 0; i < 4; ++i)
        #pragma unroll
        for (int j = 0; j < 4; ++j) acc[i][j] = 0.f;

    auto ioffOf = [&](int ks) {
        int tap = ks >> 3;
        int k0 = (ks & 7) * 32;
        int ky = tap / 3, kx = tap - ky * 3;
        return (ky * WH + kx) * CIN + k0;
    };
    const ushort_t* bbase = wtP + ((size_t)nt * 72 * 4 * 64 + lane) * 8;

    bf16x8 st[4];
    #pragma unroll
    for (int j = 0; j < 4; ++j) st[j] = *(const bf16x8*)(arow + ioffOf(j));
    for (int p = 0; p < 18; ++p) {
        ushort_t* buf = &at[p & 1][0];
        #pragma unroll
        for (int j = 0; j < 4; ++j)
            *(bf16x8*)(buf + j * 2560 + woff) = st[j];
        if (p < 17) {
            #pragma unroll
            for (int j = 0; j < 4; ++j)
                st[j] = *(const bf16x8*)(arow + ioffOf((p + 1) * 4 + j));
        }
        __syncthreads();
        #pragma unroll
        for (int kk = 0; kk < 4; ++kk) {
            int ks = p * 4 + kk;
            bf16x8 a[4], bb[4];
            #pragma unroll
            for (int j = 0; j < 4; ++j)
                bb[j] = *(const bf16x8*)(bbase + ((size_t)(ks * 4 + j) * 64) * 8);
            #pragma unroll
            for (int i = 0; i < 4; ++i)
                a[i] = *(const bf16x8*)(buf + kk * 2560 + (16 * i + lr) * 40 + kl);
            #pragma unroll
            for (int i = 0; i < 4; ++i)
                #pragma unroll
                for (int j = 0; j < 4; ++j)
                    acc[i][j] = __builtin_amdgcn_mfma_f32_16x16x32_bf16(a[i], bb[j], acc[i][j], 0, 0, 0);
        }
        __syncthreads();
    }
    #pragma unroll
    for (int i = 0; i < 4; ++i) {
        #pragma unroll
        for (int r = 0; r < 4; ++r) {
            int m = mt * 64 + 16 * i + (lane >> 4) * 4 + r;
            #pragma unroll
            for (int j = 0; j < 4; ++j) {
                int n = nt * 64 + 16 * j + lr;
                float v = fmaxf(acc[i][j][r] * scale[n] + bias[n], 0.f);
                memv[(size_t)m * 768 + n] = f2bf(v);
            }
        }
    }
}

// ---------------- kmat: 4-wave LDS-staged-A; KT [b][96][196][8] ----------------
__global__ __launch_bounds__(256) void kmat_lds(
    const ushort_t* __restrict__ memv, const ushort_t* __restrict__ Bp,
    ushort_t* __restrict__ KT) {
    __shared__ ushort_t at[2][4 * 64 * 40];
    int tid = threadIdx.x;
    int lane = tid & 63, w = tid >> 6;
    int mt = blockIdx.x;
    int nt = blockIdx.y * 4 + w;
    int lr = lane & 15, kl = (lane >> 4) * 8;
    int srow = tid >> 2, sc = tid & 3;
    const ushort_t* arow = memv + (size_t)(mt * 64 + srow) * 768 + sc * 8;
    int woff = srow * 40 + sc * 8;
    const ushort_t* bbase = Bp + ((size_t)nt * 24 * 4 * 64 + lane) * 8;

    floatx4 acc[4][4];
    #pragma unroll
    for (int i = 0; i < 4; ++i)
        #pragma unroll
        for (int j = 0; j < 4; ++j) acc[i][j] = 0.f;

    bf16x8 st[4];
    #pragma unroll
    for (int j = 0; j < 4; ++j) st[j] = *(const bf16x8*)(arow + j * 32);
    for (int p = 0; p < 6; ++p) {
        ushort_t* buf = &at[p & 1][0];
        #pragma unroll
        for (int j = 0; j < 4; ++j)
            *(bf16x8*)(buf + j * 2560 + woff) = st[j];
        if (p < 5) {
            #pragma unroll
            for (int j = 0; j < 4; ++j)
                st[j] = *(const bf16x8*)(arow + ((p + 1) * 4 + j) * 32);
        }
        __syncthreads();
        #pragma unroll
        for (int kk = 0; kk < 4; ++kk) {
            int ks = p * 4 + kk;
            bf16x8 a[4], bb[4];
            #pragma unroll
            for (int j = 0; j < 4; ++j)
                bb[j] = *(const bf16x8*)(bbase + ((size_t)(ks * 4 + j) * 64) * 8);
            #pragma unroll
            for (int i = 0; i < 4; ++i)
                a[i] = *(const bf16x8*)(buf + kk * 2560 + (16 * i + lr) * 40 + kl);
            #pragma unroll
            for (int i = 0; i < 4; ++i)
                #pragma unroll
                for (int j = 0; j < 4; ++j)
                    acc[i][j] = __builtin_amdgcn_mfma_f32_16x16x32_bf16(a[i], bb[j], acc[i][j], 0, 0, 0);
        }
        __syncthreads();
    }
    #pragma unroll
    for (int i = 0; i < 4; ++i) {
        #pragma unroll
        for (int r = 0; r < 4; ++r) {
            int mg = mt * 64 + 16 * i + (lane >> 4) * 4 + r;
            int b = mg / 196, m = mg % 196;
            #pragma unroll
            for (int j = 0; j < 4; ++j) {
                int n = nt * 64 + 16 * j + lr;
                KT[(((size_t)b * 96 + (n >> 3)) * 196 + m) * 8 + (n & 7)] = f2bf(acc[i][j][r]);
            }
        }
    }
}

// ---------------- occupancy-first GEMM: C[512][N] = Ap . Bb^T + bias; swizzled 1D grid ----------------
template <int REMAP>
__global__ __launch_bounds__(256, 4) void gemm_ldsb(
    const ushort_t* __restrict__ Ap, const ushort_t* __restrict__ Bb,
    const float* __restrict__ bias1, const float* __restrict__ bias2,
    float* __restrict__ C, int N) {
    __shared__ ushort_t bt[2][64 * 72];
    int tid = threadIdx.x;
    int lane = tid & 63, w = tid >> 6;
    int nblk = (N >> 6) * 2;
    int id = swz8(blockIdx.x, nblk);
    int nt = id >> 1, mh = id & 1;
    int n0 = nt * 64;
    int mt = mh * 4 + w;
    int lr = lane & 15, hi = lane >> 4;
    int srow = tid >> 2, sc = tid & 3;
    const ushort_t* gsrc = Bb + (size_t)(n0 + srow) * 768 + sc * 8;
    int woff = srow * 72 + sc * 8;
    floatx4 acc[4][4];
    #pragma unroll
    for (int i = 0; i < 4; ++i)
        #pragma unroll
        for (int j = 0; j < 4; ++j) acc[i][j] = 0.f;
    bf16x8 s0 = *(const bf16x8*)(gsrc);
    bf16x8 s1 = *(const bf16x8*)(gsrc + 32);
    for (int kc = 0; kc < 12; ++kc) {
        ushort_t* bufw = &bt[kc & 1][0];
        *(bf16x8*)(bufw + woff) = s0;
        *(bf16x8*)(bufw + woff + 32) = s1;
        if (kc < 11) {
            const ushort_t* p = gsrc + (size_t)(kc + 1) * 64;
            s0 = *(const bf16x8*)(p);
            s1 = *(const bf16x8*)(p + 32);
        }
        __syncthreads();
        const ushort_t* bufr = &bt[kc & 1][0];
        #pragma unroll
        for (int kk = 0; kk < 2; ++kk) {
            int kq = kc * 2 + kk;
            bf16x8 bfr[4], a[4];
            #pragma unroll
            for (int j = 0; j < 4; ++j)
                bfr[j] = *(const bf16x8*)(bufr + (j * 16 + lr) * 72 + kk * 32 + hi * 8);
            #pragma unroll
            for (int i = 0; i < 4; ++i)
                a[i] = *(const bf16x8*)(Ap + ((((size_t)mt * 24 + kq) * 4 + i) * 64 + lane) * 8);
            #pragma unroll
            for (int i = 0; i < 4; ++i)
                #pragma unroll
                for (int j = 0; j < 4; ++j)
                    acc[i][j] = __builtin_amdgcn_mfma_f32_16x16x32_bf16(a[i], bfr[j], acc[i][j], 0, 0, 0);
        }
    }
    #pragma unroll
    for (int i = 0; i < 4; ++i) {
        #pragma unroll
        for (int rr = 0; rr < 4; ++rr) {
            int m = mt * 64 + 16 * i + hi * 4 + rr;   // m = t*32+b
            #pragma unroll
            for (int j = 0; j < 4; ++j) {
                int n = n0 + 16 * j + lr;
                float vv = acc[i][j][rr];
                if (bias1) vv += bias1[n];
                if (bias2) vv += bias2[n];
                if (REMAP) {
                    int t = m >> 5, b = m & 31;
                    C[(size_t)((b << 4) + t) * NV + n] = vv;
                } else {
                    C[(size_t)m * N + n] = vv;
                }
            }
        }
    }
}

// ---------------- attention step, 2-way split: grid (32, 2) ----------------
// Both half-blocks compute scores+softmax (redundant, cheap); ctx phase is split:
// half h covers dims [h*384, h*384+384). Disjoint xin writes.
__global__ __launch_bounds__(768) void attn2(
    ushort_t* __restrict__ xin, const ushort_t* __restrict__ KT,
    const ushort_t* __restrict__ mem) {
    __shared__ float hq[NH];
    __shared__ float sl[196];
    __shared__ float red[16];
    int b = blockIdx.x, halfb = blockIdx.y, tid = threadIdx.x;
    hq[tid] = bf2f(xin[(size_t)b * 1536 + NH + tid]);
    __syncthreads();
    if (tid < 392) {
        int m = tid >> 1, half = tid & 1;
        const ushort_t* basep = KT + (((size_t)b * 96 + half * 48) * 196 + m) * 8;
        float acc = 0.f;
        #pragma unroll 4
        for (int k8 = 0; k8 < 48; ++k8) {
            bf16x8 v = *(const bf16x8*)(basep + (size_t)k8 * 196 * 8);
            const float* qp = hq + (half * 48 + k8) * 8;
            #pragma unroll
            for (int j = 0; j < 8; ++j)
                acc = fmaf(bf2f((unsigned short)v[j]), qp[j], acc);
        }
        acc += __shfl_xor(acc, 1);
        if (!half) sl[m] = acc;
    }
    __syncthreads();
    float sc = (tid < 196) ? sl[tid] : -INFINITY;
    float v = sc;
    #pragma unroll
    for (int off = 32; off; off >>= 1) v = fmaxf(v, __shfl_down(v, off));
    if ((tid & 63) == 0) red[tid >> 6] = v;
    __syncthreads();
    if (tid == 0) {
        float m = red[0];
        for (int i = 1; i < 12; ++i) m = fmaxf(m, red[i]);
        red[12] = m;
    }
    __syncthreads();
    float mx = red[12];
    float e = (tid < 196) ? expf(sc - mx) : 0.f;
    __syncthreads();
    v = e;
    #pragma unroll
    for (int off = 32; off; off >>= 1) v += __shfl_down(v, off);
    if ((tid & 63) == 0) red[tid >> 6] = v;
    __syncthreads();
    if (tid == 0) {
        float s = red[0];
        for (int i = 1; i < 12; ++i) s += red[i];
        red[12] = 1.f / s;
    }
    __syncthreads();
    if (tid < 196) sl[tid] = e * red[12];
    __syncthreads();
    if (tid < 384) {
        int d = halfb * 384 + tid;
        float acc = 0.f;
        const ushort_t* mb = mem + (size_t)b * 196 * NH + d;
        #pragma unroll 4
        for (int m = 0; m < 196; ++m) acc = fmaf(sl[m], bf2f(mb[(size_t)m * NH]), acc);
        xin[(size_t)b * 1536 + d] = f2bf(acc);
    }
}

// ---------------- fused gates GEMM + LSTM cell; writes Hall PACKED ----------------
__global__ __launch_bounds__(256) void step_fused(
    const ushort_t* __restrict__ xin_r, const ushort_t* __restrict__ wcombP,
    const float* __restrict__ eg_t,
    float* __restrict__ cbuf, float* __restrict__ hbuf,
    ushort_t* __restrict__ xin_w, ushort_t* __restrict__ hallP, int tstep) {
    __shared__ float pbuf[4][64][33];
    int lane = threadIdx.x & 63, w = threadIdx.x >> 6;
    int bx = blockIdx.x;
    int lr = lane & 15, kl = (lane >> 4) * 8;
    floatx4 acc[2][4];
    #pragma unroll
    for (int i = 0; i < 2; ++i)
        #pragma unroll
        for (int g = 0; g < 4; ++g) acc[i][g] = 0.f;
    for (int kq = 0; kq < 12; ++kq) {
        int k = w * 384 + kq * 32;
        bf16x8 a[2], bb[4];
        #pragma unroll
        for (int i = 0; i < 2; ++i)
            a[i] = *(const bf16x8*)(xin_r + (size_t)(16 * i + lr) * 1536 + k + kl);
        #pragma unroll
        for (int g = 0; g < 4; ++g)
            bb[g] = *(const bf16x8*)(wcombP + (((size_t)(bx * 4 + g) * 48 + (w * 12 + kq)) * 64 + lane) * 8);
        #pragma unroll
        for (int i = 0; i < 2; ++i)
            #pragma unroll
            for (int g = 0; g < 4; ++g)
                acc[i][g] = __builtin_amdgcn_mfma_f32_16x16x32_bf16(a[i], bb[g], acc[i][g], 0, 0, 0);
    }
    #pragma unroll
    for (int i = 0; i < 2; ++i)
        #pragma unroll
        for (int g = 0; g < 4; ++g)
            #pragma unroll
            for (int r = 0; r < 4; ++r) {
                int m = 16 * i + (lane >> 4) * 4 + r;
                pbuf[w][g * 16 + lr][m] = acc[i][g][r];
            }
    __syncthreads();
    int tid = threadIdx.x;
    #pragma unroll
    for (int o = 0; o < 2; ++o) {
        int pid = tid * 2 + o;
        int m = pid & 31, c = pid >> 5;
        int kcol = bx * 16 + c;
        float gi = 0.f, gf = 0.f, gg = 0.f, go = 0.f;
        #pragma unroll
        for (int ww = 0; ww < 4; ++ww) {
            gi += pbuf[ww][c][m];
            gf += pbuf[ww][16 + c][m];
            gg += pbuf[ww][32 + c][m];
            go += pbuf[ww][48 + c][m];
        }
        const float* eg = eg_t + (size_t)m * 3072;
        gi += eg[kcol];
        gf += eg[768 + kcol];
        gg += eg[1536 + kcol];
        go += eg[2304 + kcol];
        float cst = cbuf[m * 768 + kcol];
        float cn = sigmoidf_(gf) * cst + sigmoidf_(gi) * tanhf(gg);
        float hn = sigmoidf_(go) * tanhf(cn);
        cbuf[m * 768 + kcol] = cn;
        hbuf[m * 768 + kcol] = hn;
        ushort_t hb = f2bf(hn);
        xin_w[(size_t)m * 1536 + NH + kcol] = hb;
        int rrow = tstep * 32 + m;
        int mtp = rrow >> 6, ip = (rrow >> 4) & 3, lrp = rrow & 15;
        int kqp = kcol >> 5, hip = (kcol >> 3) & 3, ep = kcol & 7;
        hallP[((((size_t)mtp * 24 + kqp) * 4 + ip) * 64 + (lrp | (hip << 4))) * 8 + ep] = hb;
    }
}

__global__ __launch_bounds__(256) void copy_hc(const float* __restrict__ h, const float* __restrict__ c,
                                               float* __restrict__ out) {
    int i = blockIdx.x * 256 + threadIdx.x;
    if (i < NB * NH) {
        out[(size_t)NB * NT * NV + i] = h[i];
        out[(size_t)NB * NT * NV + NB * NH + i] = c[i];
    }
}

extern "C" void kernel_launch(void* const* d_in, const int* in_sizes, int n_in,
                              void* d_out, int out_size, void* d_ws, size_t ws_size,
                              hipStream_t stream) {
    const float* images   = (const float*)d_in[0];
    const int*   captions = (const int*)d_in[1];
    const float* conv1_w  = (const float*)d_in[2];
    const float* bn1_g = (const float*)d_in[3], *bn1_b = (const float*)d_in[4];
    const float* bn1_m = (const float*)d_in[5], *bn1_v = (const float*)d_in[6];
    const float* conv2_w  = (const float*)d_in[7];
    const float* bn2_g = (const float*)d_in[8], *bn2_b = (const float*)d_in[9];
    const float* bn2_m = (const float*)d_in[10], *bn2_v = (const float*)d_in[11];
    const float* conv3_w  = (const float*)d_in[12];
    const float* bn3_g = (const float*)d_in[13], *bn3_b = (const float*)d_in[14];
    const float* bn3_m = (const float*)d_in[15], *bn3_v = (const float*)d_in[16];
    const float* conv4_w  = (const float*)d_in[17];
    const float* bn4_g = (const float*)d_in[18], *bn4_b = (const float*)d_in[19];
    const float* bn4_m = (const float*)d_in[20], *bn4_v = (const float*)d_in[21];
    const float* emb_table = (const float*)d_in[22];
    const float* attn_w   = (const float*)d_in[23];
    const float* w_ih     = (const float*)d_in[24];
    const float* w_hh     = (const float*)d_in[25];
    const float* b_ih     = (const float*)d_in[26];
    const float* b_hh     = (const float*)d_in[27];
    const float* fc_w     = (const float*)d_in[28];
    const float* fc_b     = (const float*)d_in[29];
    float* out = (float*)d_out;

    // ---- workspace layout ----
    char* base = (char*)d_ws;
    size_t off = 0;
    auto alloc = [&](size_t bytes) { char* p = base + off; off += (bytes + 255) & ~(size_t)255; return p; };
    float* s1 = (float*)alloc(64 * 4);   float* bb1 = (float*)alloc(64 * 4);
    float* s2 = (float*)alloc(128 * 4);  float* bb2 = (float*)alloc(128 * 4);
    float* s3 = (float*)alloc(256 * 4);  float* bb3 = (float*)alloc(256 * 4);
    float* s4 = (float*)alloc(768 * 4);  float* bb4 = (float*)alloc(768 * 4);
    ushort_t* c1out = (ushort_t*)alloc((size_t)32 * 34 * 112 * 64 * 2);
    size_t halo_start = off;
    ushort_t* hal2 = (ushort_t*)alloc((size_t)32 * 19 * 58 * 64 * 2);
    ushort_t* hal3 = (ushort_t*)alloc((size_t)32 * 18 * 58 * 128 * 2);
    ushort_t* hal4 = (ushort_t*)alloc((size_t)32 * 10 * 30 * 256 * 2);
    size_t halo_bytes = off - halo_start;
    ushort_t* memv = (ushort_t*)alloc((size_t)32 * 196 * 768 * 2);
    ushort_t* KT   = (ushort_t*)alloc((size_t)32 * 96 * 196 * 8 * 2);
    ushort_t* wb1 = (ushort_t*)alloc((size_t)64 * 160 * 2);
    ushort_t* wb2 = (ushort_t*)alloc((size_t)128 * 9 * 64 * 2);
    ushort_t* wb3 = (ushort_t*)alloc((size_t)256 * 9 * 128 * 2);
    ushort_t* wb4 = (ushort_t*)alloc((size_t)768 * 9 * 256 * 2);
    ushort_t* wattnTP = (ushort_t*)alloc((size_t)768 * 768 * 2);
    ushort_t* wcombP = (ushort_t*)alloc((size_t)3072 * 1536 * 2);
    ushort_t* wihL = (ushort_t*)alloc((size_t)3072 * 768 * 2);
    ushort_t* e512P = (ushort_t*)alloc((size_t)512 * 768 * 2);
    float* eg   = (float*)alloc((size_t)512 * 3072 * 4);
    ushort_t* HallP = (ushort_t*)alloc((size_t)512 * 768 * 2);
    float* hbuf = (float*)alloc(NB * NH * 4);
    float* cbuf = (float*)alloc(NB * NH * 4);
    ushort_t* xinA = (ushort_t*)alloc((size_t)NB * 1536 * 2);
    ushort_t* xinB = (ushort_t*)alloc((size_t)NB * 1536 * 2);
    // union: im2col (39 MB, dead after conv1_gemm) then fc_w bf16 (49.2 MB)
    char* ubig = alloc((size_t)NV * NH * 2);
    ushort_t* imcol = (ushort_t*)ubig;
    ushort_t* fcwb  = (ushort_t*)ubig;

    // ---- merged one-time transforms (1 launch) ----
    long long n8 = (long long)(halo_bytes / 8);
    long long prep_total = (long long)SEG9 + n8;
    prep_all<<<(unsigned)((prep_total + 255) / 256), 256, 0, stream>>>(
        bn1_g, bn1_b, bn1_m, bn1_v, bn2_g, bn2_b, bn2_m, bn2_v,
        bn3_g, bn3_b, bn3_m, bn3_v, bn4_g, bn4_b, bn4_m, bn4_v,
        s1, bb1, s2, bb2, s3, bb3, s4, bb4,
        conv1_w, wb1, conv2_w, wb2, conv3_w, wb3, conv4_w, wb4,
        attn_w, wattnTP, w_ih, w_hh, wcombP, wihL,
        captions, emb_table, e512P,
        hbuf, cbuf, xinA,
        (unsigned long long*)hal2, n8);

    // ---- decoder precompute GEMM (independent of encoder) ----
    gemm_ldsb<0><<<96, 256, 0, stream>>>(e512P, wihL, b_ih, b_hh, eg, 3072);

    // ---- encoder ----
    im2col1<<<(121856 * 160 + 255) / 256, 256, 0, stream>>>(images, imcol);
    conv1_gemm<<<476, 256, 0, stream>>>(imcol, wb1, s1, bb1, c1out);
    // imcol dead -> convert fc_w (f32->bf16 row-major) into same buffer
    cvt_b16rows<<<(NV * 96 + 255) / 256, 256, 0, stream>>>(fc_w, fcwb, 96, 768, NV * 96);
    pool_kernel<<<(32 * 17 * 56 * 8 + 255) / 256, 256, 0, stream>>>(c1out, hal2);
    conv_mfma<64, 19, 58, 1, 16, 56, 128, 18, 58>
        <<<896, 64, 0, stream>>>(hal2, wb2, s2, bb2, hal3);
    conv_mfma<128, 18, 58, 2, 8, 28, 256, 10, 30>
        <<<448, 64, 0, stream>>>(hal3, wb3, s3, bb3, hal4);
    conv4_lds<<<dim3(98, 3), 256, 0, stream>>>(hal4, wb4, s4, bb4, memv);

    // ---- attention K~ precompute: KT = mem @ attn_w ----
    kmat_lds<<<dim3(98, 3), 256, 0, stream>>>(memv, wattnTP, KT);

    // ---- sequential decoder (xin double-buffered) ----
    ushort_t* xcur = xinA;
    ushort_t* xnxt = xinB;
    for (int t = 0; t < NT; ++t) {
        attn2<<<dim3(NB, 2), NH, 0, stream>>>(xcur, KT, memv);
        step_fused<<<48, 256, 0, stream>>>(
            xcur, wcombP, eg + (size_t)t * NB * 3072, cbuf, hbuf, xnxt, HallP, t);
        ushort_t* tmp = xcur; xcur = xnxt; xnxt = tmp;
    }

    // ---- vocab projection for all 16 steps at once ----
    gemm_ldsb<1><<<1000, 256, 0, stream>>>(HallP, fcwb, fc_b, nullptr, out, NV);

    copy_hc<<<(NB * NH + 255) / 256, 256, 0, stream>>>(hbuf, cbuf, out);
}